// Round 1
// baseline (549.477 us; speedup 1.0000x reference)
//
#include <hip/hip_runtime.h>
#include <math.h>

#define B_  2
#define N_  6
#define D_  128
#define Q_  2500
#define HK  420
#define NK  2520      // N_*HK
#define M_  4
#define DH  32
#define SPLIT 8
#define KPS 315       // NK/SPLIT

#define F4C(v, dd) ((dd)==0?(v).x:(dd)==1?(v).y:(dd)==2?(v).z:(v).w)

// block of 128 threads (2 waves): reduce (s, s2) across the block
__device__ __forceinline__ void block_reduce_pair(float& s, float& s2, float* scr, int t) {
  #pragma unroll
  for (int off = 1; off < 64; off <<= 1) {
    s  += __shfl_xor(s,  off);
    s2 += __shfl_xor(s2, off);
  }
  __syncthreads();                       // protect scr from previous use
  if ((t & 63) == 0) { scr[(t >> 6) * 2] = s; scr[(t >> 6) * 2 + 1] = s2; }
  __syncthreads();
  s  = scr[0] + scr[2];
  s2 = scr[1] + scr[3];
}

// ---------------- Kernel A: LN + project K and V ----------------
__global__ __launch_bounds__(128)
void proj_kv_kernel(const float* __restrict__ kin, const float* __restrict__ vin,
                    const float* __restrict__ lnk_g, const float* __restrict__ lnk_b,
                    const float* __restrict__ wk, const float* __restrict__ bk,
                    const float* __restrict__ lnv_g, const float* __restrict__ lnv_b,
                    const float* __restrict__ wv, const float* __restrict__ bv,
                    float* __restrict__ kp, float* __restrict__ vp)
{
  const int TR = 8;
  __shared__ float xln[TR][D_];
  __shared__ float scr[4];
  const int t = threadIdx.x;
  const int row0 = blockIdx.x * TR;      // rows in [0, 5040)

  for (int ph = 0; ph < 2; ++ph) {
    const float* in = ph ? vin : kin;
    const float* g  = ph ? lnv_g : lnk_g;
    const float* bb = ph ? lnv_b : lnk_b;
    const float* w  = ph ? wv : wk;
    const float* bs = ph ? bv : bk;
    float* out      = ph ? vp : kp;

    const float gv = g[t], blv = bb[t];
    #pragma unroll
    for (int r = 0; r < TR; ++r) {
      const int row = row0 + r;
      const int cam = row / HK;
      const int kk  = row - cam * HK;
      const float x = in[((size_t)(cam * D_ + t)) * HK + kk];
      float s = x, s2 = x * x;
      block_reduce_pair(s, s2, scr, t);
      const float mean = s * (1.f / D_);
      const float var  = s2 * (1.f / D_) - mean * mean;
      xln[r][t] = (x - mean) * rsqrtf(var + 1e-5f) * gv + blv;
    }
    __syncthreads();

    float acc[TR];
    #pragma unroll
    for (int r = 0; r < TR; ++r) acc[r] = 0.f;
    #pragma unroll 4
    for (int d0 = 0; d0 < D_; d0 += 4) {
      float4 xr[TR];
      #pragma unroll
      for (int r = 0; r < TR; ++r) xr[r] = *(const float4*)&xln[r][d0];
      #pragma unroll
      for (int dd = 0; dd < 4; ++dd) {
        const float wvv = w[(size_t)(d0 + dd) * 128 + t];
        #pragma unroll
        for (int r = 0; r < TR; ++r) acc[r] += F4C(xr[r], dd) * wvv;
      }
    }
    const float bsv = bs[t];
    #pragma unroll
    for (int r = 0; r < TR; ++r) out[((size_t)(row0 + r)) * 128 + t] = acc[r] + bsv;
    __syncthreads();
  }
}

// ---------------- Kernel B: LN(q0)+LN(q1), project, qsum ----------------
__global__ __launch_bounds__(128)
void proj_q_kernel(const float* __restrict__ qin,
                   const float* __restrict__ lnq_g, const float* __restrict__ lnq_b,
                   const float* __restrict__ wq, const float* __restrict__ bq,
                   float* __restrict__ qs)
{
  const int TR = 8;
  __shared__ float xln[TR][D_];
  __shared__ float scr[4];
  const int t = threadIdx.x;
  const int row0 = blockIdx.x * TR;      // rows in [0, 5000)
  const float gv = lnq_g[t], blv = lnq_b[t];

  #pragma unroll
  for (int r = 0; r < TR; ++r) {
    const int row = row0 + r;
    const int b = row / Q_;
    const int qpos = row - b * Q_;
    float xs = 0.f;
    #pragma unroll
    for (int n = 0; n < 2; ++n) {
      const float x = qin[((size_t)((b * N_ + n) * D_ + t)) * Q_ + qpos];
      float s = x, s2 = x * x;
      block_reduce_pair(s, s2, scr, t);
      const float mean = s * (1.f / D_);
      const float var  = s2 * (1.f / D_) - mean * mean;
      xs += (x - mean) * rsqrtf(var + 1e-5f);
    }
    xln[r][t] = xs * gv + 2.f * blv;
  }
  __syncthreads();

  float acc[TR];
  #pragma unroll
  for (int r = 0; r < TR; ++r) acc[r] = 0.f;
  #pragma unroll 4
  for (int d0 = 0; d0 < D_; d0 += 4) {
    float4 xr[TR];
    #pragma unroll
    for (int r = 0; r < TR; ++r) xr[r] = *(const float4*)&xln[r][d0];
    #pragma unroll
    for (int dd = 0; dd < 4; ++dd) {
      const float wvv = wq[(size_t)(d0 + dd) * 128 + t];
      #pragma unroll
      for (int r = 0; r < TR; ++r) acc[r] += F4C(xr[r], dd) * wvv;
    }
  }
  const float bsv = 2.f * bq[t];
  #pragma unroll
  for (int r = 0; r < TR; ++r) qs[((size_t)(row0 + r)) * 128 + t] = acc[r] + bsv;
}

// ---------------- Kernel C: flash attention, split-K partials ----------------
__global__ __launch_bounds__(256)
void attn_kernel(const float* __restrict__ qs, const float* __restrict__ kp,
                 const float* __restrict__ vp,
                 float* __restrict__ pl, float* __restrict__ pacc)
{
  const int bi = blockIdx.x;
  const int qt = bi % 10;
  const int sp = (bi / 10) % SPLIT;
  const int m  = (bi / (10 * SPLIT)) % M_;
  const int b  = bi / (10 * SPLIT * M_);
  const int q  = qt * 256 + threadIdx.x;
  const bool act = (q < Q_);
  const float scale = 0.17677669529663687f;   // 32^-0.5

  float qreg[DH];
  if (act) {
    const float* qrow = qs + ((size_t)(b * Q_ + q)) * 128 + m * DH;
    #pragma unroll
    for (int j = 0; j < DH; ++j) qreg[j] = qrow[j] * scale;
  } else {
    #pragma unroll
    for (int j = 0; j < DH; ++j) qreg[j] = 0.f;
  }

  float acc[DH];
  #pragma unroll
  for (int j = 0; j < DH; ++j) acc[j] = 0.f;
  float l = 0.f;

  const size_t kb = ((size_t)b * NK + sp * KPS) * 128 + m * DH;
  const float* kbase = kp + kb;
  const float* vbase = vp + kb;

  for (int kk = 0; kk < KPS; ++kk) {
    const float4* kr4 = (const float4*)(kbase + (size_t)kk * 128);
    const float4* vr4 = (const float4*)(vbase + (size_t)kk * 128);
    float s = 0.f;
    #pragma unroll
    for (int jj = 0; jj < 8; ++jj) {
      const float4 kf = kr4[jj];
      s += qreg[4*jj+0]*kf.x + qreg[4*jj+1]*kf.y + qreg[4*jj+2]*kf.z + qreg[4*jj+3]*kf.w;
    }
    const float p = __expf(s);
    l += p;
    #pragma unroll
    for (int jj = 0; jj < 8; ++jj) {
      const float4 vf = vr4[jj];
      acc[4*jj+0] += p * vf.x;
      acc[4*jj+1] += p * vf.y;
      acc[4*jj+2] += p * vf.z;
      acc[4*jj+3] += p * vf.w;
    }
  }

  if (act) {
    const size_t base = (((size_t)(b * M_ + m)) * Q_ + q) * SPLIT + sp;
    pl[base] = l;
    float* pa = pacc + base * DH;
    #pragma unroll
    for (int j = 0; j < DH; ++j) pa[j] = acc[j];
  }
}

// ---------------- Kernel C2: combine split-K partials ----------------
__global__ __launch_bounds__(256)
void combine_kernel(const float* __restrict__ pl, const float* __restrict__ pacc,
                    float* __restrict__ a)
{
  const int o = blockIdx.x * 256 + threadIdx.x;   // < B*M*Q*DH = 640000
  const int j = o & 31;
  const int bmq = o >> 5;
  const int q = bmq % Q_;
  const int bm = bmq / Q_;
  const int m = bm & 3, b = bm >> 2;
  float ls = 0.f, as = 0.f;
  #pragma unroll
  for (int sp = 0; sp < SPLIT; ++sp) {
    ls += pl[(size_t)bmq * SPLIT + sp];
    as += pacc[((size_t)bmq * SPLIT + sp) * DH + j];
  }
  a[((size_t)(b * Q_ + q)) * 128 + m * DH + j] = as / ls;
}

// ---------------- Kernel D: proj + skip + LN1 + MLP(GELU) + LN2 + transpose ----------------
__global__ __launch_bounds__(128)
void tail_kernel(const float* __restrict__ a, const float* __restrict__ skip,
                 const float* __restrict__ wp, const float* __restrict__ bp,
                 const float* __restrict__ ln1_g, const float* __restrict__ ln1_b,
                 const float* __restrict__ w1, const float* __restrict__ b1,
                 const float* __restrict__ w2, const float* __restrict__ b2,
                 const float* __restrict__ ln2_g, const float* __restrict__ ln2_b,
                 float* __restrict__ out)
{
  const int TR = 8;
  __shared__ float zl[TR][128];
  __shared__ float hl[TR][256];
  __shared__ float scr[4];
  const int t = threadIdx.x;
  const int row0 = blockIdx.x * TR;      // rows (b*Q+q) in [0, 5000)

  #pragma unroll
  for (int r = 0; r < TR; ++r) zl[r][t] = a[((size_t)(row0 + r)) * 128 + t];
  __syncthreads();

  // z = a @ wp
  float z[TR];
  #pragma unroll
  for (int r = 0; r < TR; ++r) z[r] = 0.f;
  #pragma unroll 4
  for (int d0 = 0; d0 < 128; d0 += 4) {
    float4 xr[TR];
    #pragma unroll
    for (int r = 0; r < TR; ++r) xr[r] = *(const float4*)&zl[r][d0];
    #pragma unroll
    for (int dd = 0; dd < 4; ++dd) {
      const float wvv = wp[(size_t)(d0 + dd) * 128 + t];
      #pragma unroll
      for (int r = 0; r < TR; ++r) z[r] += F4C(xr[r], dd) * wvv;
    }
  }
  // + bp + skip
  const float bpv = bp[t];
  #pragma unroll
  for (int r = 0; r < TR; ++r) {
    const int row = row0 + r;
    const int b = row / Q_;
    const int qpos = row - b * Q_;
    z[r] += bpv + skip[((size_t)(b * 128 + t)) * Q_ + qpos];
  }
  __syncthreads();   // done reading a from zl

  // LN1 (store normalized z back into zl and keep in regs for residual)
  const float g1 = ln1_g[t], bb1 = ln1_b[t];
  #pragma unroll
  for (int r = 0; r < TR; ++r) {
    float s = z[r], s2 = z[r] * z[r];
    block_reduce_pair(s, s2, scr, t);
    const float mean = s * (1.f / 128.f);
    const float var  = s2 * (1.f / 128.f) - mean * mean;
    z[r] = (z[r] - mean) * rsqrtf(var + 1e-5f) * g1 + bb1;
    zl[r][t] = z[r];
  }
  __syncthreads();

  // h = gelu(z @ w1 + b1), exact erf gelu
  float h0[TR], h1[TR];
  #pragma unroll
  for (int r = 0; r < TR; ++r) { h0[r] = 0.f; h1[r] = 0.f; }
  #pragma unroll 4
  for (int d0 = 0; d0 < 128; d0 += 4) {
    float4 xr[TR];
    #pragma unroll
    for (int r = 0; r < TR; ++r) xr[r] = *(const float4*)&zl[r][d0];
    #pragma unroll
    for (int dd = 0; dd < 4; ++dd) {
      const float wa = w1[(size_t)(d0 + dd) * 256 + t];
      const float wb = w1[(size_t)(d0 + dd) * 256 + t + 128];
      #pragma unroll
      for (int r = 0; r < TR; ++r) {
        const float xv = F4C(xr[r], dd);
        h0[r] += xv * wa;
        h1[r] += xv * wb;
      }
    }
  }
  const float b1a = b1[t], b1b = b1[t + 128];
  #pragma unroll
  for (int r = 0; r < TR; ++r) {
    const float x0 = h0[r] + b1a;
    const float x1 = h1[r] + b1b;
    hl[r][t]       = 0.5f * x0 * (1.f + erff(x0 * 0.70710678118f));
    hl[r][t + 128] = 0.5f * x1 * (1.f + erff(x1 * 0.70710678118f));
  }
  __syncthreads();

  // y = h @ w2 + b2 ; z2 = z + y
  float y[TR];
  #pragma unroll
  for (int r = 0; r < TR; ++r) y[r] = 0.f;
  #pragma unroll 4
  for (int c0 = 0; c0 < 256; c0 += 4) {
    float4 hr[TR];
    #pragma unroll
    for (int r = 0; r < TR; ++r) hr[r] = *(const float4*)&hl[r][c0];
    #pragma unroll
    for (int dd = 0; dd < 4; ++dd) {
      const float wvv = w2[(size_t)(c0 + dd) * 128 + t];
      #pragma unroll
      for (int r = 0; r < TR; ++r) y[r] += F4C(hr[r], dd) * wvv;
    }
  }
  const float b2v = b2[t];
  const float g2 = ln2_g[t], bb2 = ln2_b[t];
  #pragma unroll
  for (int r = 0; r < TR; ++r) {
    float zf = z[r] + y[r] + b2v;
    float s = zf, s2 = zf * zf;
    block_reduce_pair(s, s2, scr, t);
    const float mean = s * (1.f / 128.f);
    const float var  = s2 * (1.f / 128.f) - mean * mean;
    const float res  = (zf - mean) * rsqrtf(var + 1e-5f) * g2 + bb2;
    const int row = row0 + r;
    const int b = row / Q_;
    const int qpos = row - b * Q_;
    out[((size_t)(b * 128 + t)) * Q_ + qpos] = res;
  }
}

extern "C" void kernel_launch(void* const* d_in, const int* in_sizes, int n_in,
                              void* d_out, int out_size, void* d_ws, size_t ws_size,
                              hipStream_t stream)
{
  const float* q     = (const float*)d_in[0];
  const float* k     = (const float*)d_in[1];
  const float* v     = (const float*)d_in[2];
  const float* skip  = (const float*)d_in[3];
  const float* lnq_g = (const float*)d_in[4];
  const float* lnq_b = (const float*)d_in[5];
  const float* wq    = (const float*)d_in[6];
  const float* bq    = (const float*)d_in[7];
  const float* lnk_g = (const float*)d_in[8];
  const float* lnk_b = (const float*)d_in[9];
  const float* wk    = (const float*)d_in[10];
  const float* bk    = (const float*)d_in[11];
  const float* lnv_g = (const float*)d_in[12];
  const float* lnv_b = (const float*)d_in[13];
  const float* wv    = (const float*)d_in[14];
  const float* bv    = (const float*)d_in[15];
  const float* wp    = (const float*)d_in[16];
  const float* bp    = (const float*)d_in[17];
  const float* ln1_g = (const float*)d_in[18];
  const float* ln1_b = (const float*)d_in[19];
  const float* w1    = (const float*)d_in[20];
  const float* b1    = (const float*)d_in[21];
  const float* w2    = (const float*)d_in[22];
  const float* b2    = (const float*)d_in[23];
  const float* ln2_g = (const float*)d_in[24];
  const float* ln2_b = (const float*)d_in[25];

  float* ws   = (float*)d_ws;
  float* kp   = ws;                    // B*NK*128   = 645120
  float* vp   = kp + 645120;           // 645120
  float* qs   = vp + 645120;           // B*Q*128    = 640000
  float* pl   = qs + 640000;           // B*M*Q*SPLIT= 160000
  float* pacc = pl + 160000;           // *DH        = 5120000
  float* a    = pacc + 5120000;        // B*Q*128    = 640000

  proj_kv_kernel<<<dim3(630), dim3(128), 0, stream>>>(
      k, v, lnk_g, lnk_b, wk, bk, lnv_g, lnv_b, wv, bv, kp, vp);
  proj_q_kernel<<<dim3(625), dim3(128), 0, stream>>>(
      q, lnq_g, lnq_b, wq, bq, qs);
  attn_kernel<<<dim3(640), dim3(256), 0, stream>>>(qs, kp, vp, pl, pacc);
  combine_kernel<<<dim3(2500), dim3(256), 0, stream>>>(pl, pacc, a);
  tail_kernel<<<dim3(625), dim3(128), 0, stream>>>(
      a, skip, wp, bp, ln1_g, ln1_b, w1, b1, w2, b2, ln2_g, ln2_b, (float*)d_out);
}

// Round 3
// 133.493 us; speedup vs baseline: 4.1161x; 4.1161x over previous
//
#include <hip/hip_runtime.h>
#include <hip/hip_bf16.h>
#include <math.h>
#include <string.h>

#define B_  2
#define N_  6
#define D_  128
#define Q_  2500
#define HK  420
#define NK  2520
#define NKP 2560      // padded keys (40 zero-pads, all in split 3)
#define M_  4
#define DH  32
#define SPLIT 4
#define KPSP 640      // NKP/SPLIT
#define CHUNKS 20     // KPSP/32
#define QT_TILES 157  // ceil(2500/16)
#define SCALE 0.17677669529663687f

typedef __attribute__((ext_vector_type(8))) short short8v;
typedef __attribute__((ext_vector_type(4))) float f32x4;

#define F4C(v, dd) ((dd)==0?(v).x:(dd)==1?(v).y:(dd)==2?(v).z:(v).w)

__device__ __forceinline__ unsigned short f2b(float x) {
  unsigned u = __float_as_uint(x);
  return (unsigned short)((u + 0x7FFFu + ((u >> 16) & 1u)) >> 16);
}

__device__ __forceinline__ unsigned pk2(float lo, float hi) {
  return (unsigned)f2b(lo) | ((unsigned)f2b(hi) << 16);
}

// block of 128 threads (2 waves): reduce (s, s2) across the block
__device__ __forceinline__ void block_reduce_pair(float& s, float& s2, float* scr, int t) {
  #pragma unroll
  for (int off = 1; off < 64; off <<= 1) {
    s  += __shfl_xor(s,  off);
    s2 += __shfl_xor(s2, off);
  }
  __syncthreads();
  if ((t & 63) == 0) { scr[(t >> 6) * 2] = s; scr[(t >> 6) * 2 + 1] = s2; }
  __syncthreads();
  s  = scr[0] + scr[2];
  s2 = scr[1] + scr[3];
}

// ---------------- Kernel A: LN + project K and V -> bf16 (K: [bm][key][dh], V^T: [bm*32+dh][key]) ----------------
__global__ __launch_bounds__(128)
void proj_kv_kernel(const float* __restrict__ kin, const float* __restrict__ vin,
                    const float* __restrict__ lnk_g, const float* __restrict__ lnk_b,
                    const float* __restrict__ wk, const float* __restrict__ bk,
                    const float* __restrict__ lnv_g, const float* __restrict__ lnv_b,
                    const float* __restrict__ wv, const float* __restrict__ bv,
                    unsigned short* __restrict__ kpb, unsigned short* __restrict__ vtb)
{
  const int TR = 4;
  __shared__ float xln[TR][D_];
  __shared__ float scr[4];
  const int t = threadIdx.x;
  const int row0 = blockIdx.x * TR;       // rows in [0, 5040), never straddles b (2520%4==0)
  const int b = row0 / NK;
  const int key0 = row0 - b * NK;

  for (int ph = 0; ph < 2; ++ph) {
    const float* in = ph ? vin : kin;
    const float* g  = ph ? lnv_g : lnk_g;
    const float* bb = ph ? lnv_b : lnk_b;
    const float* w  = ph ? wv : wk;
    const float* bs = ph ? bv : bk;

    const float gv = g[t], blv = bb[t];
    #pragma unroll
    for (int r = 0; r < TR; ++r) {
      const int row = row0 + r;
      const int cam = row / HK;
      const int kk  = row - cam * HK;
      const float x = in[((size_t)(cam * D_ + t)) * HK + kk];
      float s = x, s2 = x * x;
      block_reduce_pair(s, s2, scr, t);
      const float mean = s * (1.f / D_);
      const float var  = s2 * (1.f / D_) - mean * mean;
      xln[r][t] = (x - mean) * rsqrtf(var + 1e-5f) * gv + blv;
    }
    __syncthreads();

    float acc[TR];
    #pragma unroll
    for (int r = 0; r < TR; ++r) acc[r] = 0.f;
    #pragma unroll 4
    for (int d0 = 0; d0 < D_; d0 += 4) {
      float4 xr[TR];
      #pragma unroll
      for (int r = 0; r < TR; ++r) xr[r] = *(const float4*)&xln[r][d0];
      #pragma unroll
      for (int dd = 0; dd < 4; ++dd) {
        const float wvv = w[(size_t)(d0 + dd) * 128 + t];
        #pragma unroll
        for (int r = 0; r < TR; ++r) acc[r] += F4C(xr[r], dd) * wvv;
      }
    }
    const float bsv = bs[t];
    if (ph == 0) {
      const int m = t >> 5, dh = t & 31;
      #pragma unroll
      for (int r = 0; r < TR; ++r)
        kpb[((size_t)(b * M_ + m) * NKP + key0 + r) * DH + dh] = f2b(acc[r] + bsv);
    } else {
      // V^T row index = (b*4+m)*32+dh = b*128 + t; pack this thread's 4 keys
      unsigned lo = pk2(acc[0] + bsv, acc[1] + bsv);
      unsigned hi = pk2(acc[2] + bsv, acc[3] + bsv);
      *(uint2*)&vtb[((size_t)(b * 128 + t)) * NKP + key0] = make_uint2(lo, hi);
    }
    __syncthreads();
  }
}

// ---------------- Kernel B: LN(q0)+LN(q1), project, pre-scale -> bf16 [b*Q+q][128] ----------------
__global__ __launch_bounds__(128)
void proj_q_kernel(const float* __restrict__ qin,
                   const float* __restrict__ lnq_g, const float* __restrict__ lnq_b,
                   const float* __restrict__ wq, const float* __restrict__ bq,
                   unsigned short* __restrict__ qsb)
{
  const int TR = 4;
  __shared__ float xln[TR][D_];
  __shared__ float scr[4];
  const int t = threadIdx.x;
  const int row0 = blockIdx.x * TR;      // [0, 5000), never straddles b
  const float gv = lnq_g[t], blv = lnq_b[t];

  #pragma unroll
  for (int r = 0; r < TR; ++r) {
    const int row = row0 + r;
    const int b = row / Q_;
    const int qpos = row - b * Q_;
    float xs = 0.f;
    #pragma unroll
    for (int n = 0; n < 2; ++n) {
      const float x = qin[((size_t)((b * N_ + n) * D_ + t)) * Q_ + qpos];
      float s = x, s2 = x * x;
      block_reduce_pair(s, s2, scr, t);
      const float mean = s * (1.f / D_);
      const float var  = s2 * (1.f / D_) - mean * mean;
      xs += (x - mean) * rsqrtf(var + 1e-5f);
    }
    xln[r][t] = xs * gv + 2.f * blv;
  }
  __syncthreads();

  float acc[TR];
  #pragma unroll
  for (int r = 0; r < TR; ++r) acc[r] = 0.f;
  #pragma unroll 4
  for (int d0 = 0; d0 < D_; d0 += 4) {
    float4 xr[TR];
    #pragma unroll
    for (int r = 0; r < TR; ++r) xr[r] = *(const float4*)&xln[r][d0];
    #pragma unroll
    for (int dd = 0; dd < 4; ++dd) {
      const float wvv = wq[(size_t)(d0 + dd) * 128 + t];
      #pragma unroll
      for (int r = 0; r < TR; ++r) acc[r] += F4C(xr[r], dd) * wvv;
    }
  }
  const float bsv = 2.f * bq[t];
  #pragma unroll
  for (int r = 0; r < TR; ++r)
    qsb[((size_t)(row0 + r)) * 128 + t] = f2b((acc[r] + bsv) * SCALE);
}

// ---------------- Kernel C: MFMA flash attention (split-K partials) ----------------
// block = 4 waves, each wave owns one 16-query tile; S^T = K.Q^T, O^T = V^T.P^T
__global__ __launch_bounds__(256)
void attn_kernel(const unsigned short* __restrict__ qsb,
                 const unsigned short* __restrict__ kpb,
                 const unsigned short* __restrict__ vtb,
                 float* __restrict__ pl, float* __restrict__ pacc)
{
  __shared__ __align__(16) char plds_all[4][16 * 80];   // per-wave P^T bounce, 80B row stride
  const int wid  = threadIdx.x >> 6;
  const int lane = threadIdx.x & 63;
  const int bi = blockIdx.x;
  const int sp = bi & 3;
  const int tmp = bi >> 2;
  const int qt4 = tmp % 40;
  const int bm = tmp / 40;               // b*4+m
  const int qt = qt4 * 4 + wid;
  if (qt >= QT_TILES) return;

  const int q16 = lane & 15, g = lane >> 4;
  const int q = qt * 16 + q16;
  const int qc = q < Q_ ? q : Q_ - 1;
  const int b = bm >> 2;
  char* plds = plds_all[wid];

  // Q fragment (B operand: col=q, k=dh), held for the whole key loop
  const short8v qf = *(const short8v*)(qsb + ((size_t)(b * Q_ + qc)) * 128 + (bm & 3) * DH + g * 8);

  const unsigned short* kp1 = kpb + ((size_t)bm * NKP + sp * KPSP) * DH + q16 * DH + g * 8;
  const unsigned short* kp2 = kp1 + 16 * DH;
  const unsigned short* vp1 = vtb + ((size_t)(bm * DH + q16)) * NKP + sp * KPSP + g * 8;
  const unsigned short* vp2 = vp1 + (size_t)16 * NKP;

  f32x4 o0 = {0.f, 0.f, 0.f, 0.f}, o1 = {0.f, 0.f, 0.f, 0.f};
  float l = 0.f;

  short8v k1 = *(const short8v*)kp1, k2 = *(const short8v*)kp2;
  short8v v1 = *(const short8v*)vp1, v2 = *(const short8v*)vp2;

  for (int c = 0; c < CHUNKS; ++c) {
    const short8v ck1 = k1, ck2 = k2, cv1 = v1, cv2 = v2;
    if (c < CHUNKS - 1) {                 // prefetch next chunk
      kp1 += 32 * DH; kp2 += 32 * DH; vp1 += 32; vp2 += 32;
      k1 = *(const short8v*)kp1; k2 = *(const short8v*)kp2;
      v1 = *(const short8v*)vp1; v2 = *(const short8v*)vp2;
    }
    // S^T tiles: keys (4g+r) x q, and keys (16+4g+r) x q   [C/D layout: col=lane&15, row=4*(lane>>4)+r]
    f32x4 s0 = __builtin_amdgcn_mfma_f32_16x16x32_bf16(ck1, qf, (f32x4){0.f,0.f,0.f,0.f}, 0, 0, 0);
    f32x4 s1 = __builtin_amdgcn_mfma_f32_16x16x32_bf16(ck2, qf, (f32x4){0.f,0.f,0.f,0.f}, 0, 0, 0);

    float p[8];
    #pragma unroll
    for (int r = 0; r < 4; ++r) { p[r] = __expf(s0[r]); p[4 + r] = __expf(s1[r]); }
    #pragma unroll
    for (int i = 0; i < 8; ++i) l += p[i];

    // P^T -> LDS as bf16: row q (stride 80B), keys 4g..4g+3 at byte 8g, keys 16+4g.. at byte 32+8g
    uint2 w1, w2;
    w1.x = pk2(p[0], p[1]); w1.y = pk2(p[2], p[3]);
    w2.x = pk2(p[4], p[5]); w2.y = pk2(p[6], p[7]);
    *(uint2*)(plds + q16 * 80 + g * 8)      = w1;
    *(uint2*)(plds + q16 * 80 + 32 + g * 8) = w2;
    // B fragment of P^T: col=q, k=keys 8g..8g+7
    const short8v pb = *(const short8v*)(plds + q16 * 80 + g * 16);

    o0 = __builtin_amdgcn_mfma_f32_16x16x32_bf16(cv1, pb, o0, 0, 0, 0);
    o1 = __builtin_amdgcn_mfma_f32_16x16x32_bf16(cv2, pb, o1, 0, 0, 0);
  }

  l += __shfl_xor(l, 16);
  l += __shfl_xor(l, 32);

  if (q < Q_) {
    const size_t row = (size_t)(bm * SPLIT + sp) * Q_ + q;
    if (lane < 16) pl[row] = l;
    *(f32x4*)(pacc + row * DH + 4 * g)      = o0;   // dh = 4g+r
    *(f32x4*)(pacc + row * DH + 16 + 4 * g) = o1;   // dh = 16+4g+r
  }
}

// ---------------- Kernel C2: combine split-K partials ----------------
__global__ __launch_bounds__(256)
void combine_kernel(const float* __restrict__ pl, const float* __restrict__ pacc,
                    float* __restrict__ a)
{
  const int o = blockIdx.x * 256 + threadIdx.x;   // < B*M*Q*DH = 640000
  const int j = o & 31;
  const int bmq = o >> 5;
  const int q = bmq % Q_;
  const int bm = bmq / Q_;
  const int m = bm & 3, b = bm >> 2;
  float ls = -40.0f;                               // exact correction for 40 zero-pad keys
  float as = 0.f;
  #pragma unroll
  for (int sp = 0; sp < SPLIT; ++sp) {
    const size_t row = (size_t)(bm * SPLIT + sp) * Q_ + q;
    ls += pl[row];
    as += pacc[row * DH + j];
  }
  a[((size_t)(b * Q_ + q)) * 128 + m * DH + j] = as / ls;
}

// ---------------- Kernel D: proj + skip + LN1 + MLP(GELU) + LN2 + transpose ----------------
__global__ __launch_bounds__(128)
void tail_kernel(const float* __restrict__ a, const float* __restrict__ skip,
                 const float* __restrict__ wp, const float* __restrict__ bp,
                 const float* __restrict__ ln1_g, const float* __restrict__ ln1_b,
                 const float* __restrict__ w1, const float* __restrict__ b1,
                 const float* __restrict__ w2, const float* __restrict__ b2,
                 const float* __restrict__ ln2_g, const float* __restrict__ ln2_b,
                 float* __restrict__ out)
{
  const int TR = 4;
  __shared__ float zl[TR][128];
  __shared__ float hl[TR][256];
  __shared__ float scr[4];
  const int t = threadIdx.x;
  const int row0 = blockIdx.x * TR;      // [0, 5000)

  #pragma unroll
  for (int r = 0; r < TR; ++r) zl[r][t] = a[((size_t)(row0 + r)) * 128 + t];
  __syncthreads();

  float z[TR];
  #pragma unroll
  for (int r = 0; r < TR; ++r) z[r] = 0.f;
  #pragma unroll 4
  for (int d0 = 0; d0 < 128; d0 += 4) {
    float4 xr[TR];
    #pragma unroll
    for (int r = 0; r < TR; ++r) xr[r] = *(const float4*)&zl[r][d0];
    #pragma unroll
    for (int dd = 0; dd < 4; ++dd) {
      const float wvv = wp[(size_t)(d0 + dd) * 128 + t];
      #pragma unroll
      for (int r = 0; r < TR; ++r) z[r] += F4C(xr[r], dd) * wvv;
    }
  }
  const float bpv = bp[t];
  #pragma unroll
  for (int r = 0; r < TR; ++r) {
    const int row = row0 + r;
    const int b = row / Q_;
    const int qpos = row - b * Q_;
    z[r] += bpv + skip[((size_t)(b * 128 + t)) * Q_ + qpos];
  }
  __syncthreads();

  const float g1 = ln1_g[t], bb1 = ln1_b[t];
  #pragma unroll
  for (int r = 0; r < TR; ++r) {
    float s = z[r], s2 = z[r] * z[r];
    block_reduce_pair(s, s2, scr, t);
    const float mean = s * (1.f / 128.f);
    const float var  = s2 * (1.f / 128.f) - mean * mean;
    z[r] = (z[r] - mean) * rsqrtf(var + 1e-5f) * g1 + bb1;
    zl[r][t] = z[r];
  }
  __syncthreads();

  float h0[TR], h1[TR];
  #pragma unroll
  for (int r = 0; r < TR; ++r) { h0[r] = 0.f; h1[r] = 0.f; }
  #pragma unroll 4
  for (int d0 = 0; d0 < 128; d0 += 4) {
    float4 xr[TR];
    #pragma unroll
    for (int r = 0; r < TR; ++r) xr[r] = *(const float4*)&zl[r][d0];
    #pragma unroll
    for (int dd = 0; dd < 4; ++dd) {
      const float wa = w1[(size_t)(d0 + dd) * 256 + t];
      const float wb = w1[(size_t)(d0 + dd) * 256 + t + 128];
      #pragma unroll
      for (int r = 0; r < TR; ++r) {
        const float xv = F4C(xr[r], dd);
        h0[r] += xv * wa;
        h1[r] += xv * wb;
      }
    }
  }
  const float b1a = b1[t], b1b = b1[t + 128];
  #pragma unroll
  for (int r = 0; r < TR; ++r) {
    const float x0 = h0[r] + b1a;
    const float x1 = h1[r] + b1b;
    hl[r][t]       = 0.5f * x0 * (1.f + erff(x0 * 0.70710678118f));
    hl[r][t + 128] = 0.5f * x1 * (1.f + erff(x1 * 0.70710678118f));
  }
  __syncthreads();

  float y[TR];
  #pragma unroll
  for (int r = 0; r < TR; ++r) y[r] = 0.f;
  #pragma unroll 4
  for (int c0 = 0; c0 < 256; c0 += 4) {
    float4 hr[TR];
    #pragma unroll
    for (int r = 0; r < TR; ++r) hr[r] = *(const float4*)&hl[r][c0];
    #pragma unroll
    for (int dd = 0; dd < 4; ++dd) {
      const float wvv = w2[(size_t)(c0 + dd) * 128 + t];
      #pragma unroll
      for (int r = 0; r < TR; ++r) y[r] += F4C(hr[r], dd) * wvv;
    }
  }
  const float b2v = b2[t];
  const float g2 = ln2_g[t], bb2 = ln2_b[t];
  #pragma unroll
  for (int r = 0; r < TR; ++r) {
    float zf = z[r] + y[r] + b2v;
    float s = zf, s2 = zf * zf;
    block_reduce_pair(s, s2, scr, t);
    const float mean = s * (1.f / 128.f);
    const float var  = s2 * (1.f / 128.f) - mean * mean;
    const float res  = (zf - mean) * rsqrtf(var + 1e-5f) * g2 + bb2;
    const int row = row0 + r;
    const int b = row / Q_;
    const int qpos = row - b * Q_;
    out[((size_t)(b * 128 + t)) * Q_ + qpos] = res;
  }
}

extern "C" void kernel_launch(void* const* d_in, const int* in_sizes, int n_in,
                              void* d_out, int out_size, void* d_ws, size_t ws_size,
                              hipStream_t stream)
{
  const float* q     = (const float*)d_in[0];
  const float* k     = (const float*)d_in[1];
  const float* v     = (const float*)d_in[2];
  const float* skip  = (const float*)d_in[3];
  const float* lnq_g = (const float*)d_in[4];
  const float* lnq_b = (const float*)d_in[5];
  const float* wq    = (const float*)d_in[6];
  const float* bq    = (const float*)d_in[7];
  const float* lnk_g = (const float*)d_in[8];
  const float* lnk_b = (const float*)d_in[9];
  const float* wk    = (const float*)d_in[10];
  const float* bk    = (const float*)d_in[11];
  const float* lnv_g = (const float*)d_in[12];
  const float* lnv_b = (const float*)d_in[13];
  const float* wv    = (const float*)d_in[14];
  const float* bv    = (const float*)d_in[15];
  const float* wp    = (const float*)d_in[16];
  const float* bp    = (const float*)d_in[17];
  const float* ln1_g = (const float*)d_in[18];
  const float* ln1_b = (const float*)d_in[19];
  const float* w1    = (const float*)d_in[20];
  const float* b1    = (const float*)d_in[21];
  const float* w2    = (const float*)d_in[22];
  const float* b2    = (const float*)d_in[23];
  const float* ln2_g = (const float*)d_in[24];
  const float* ln2_b = (const float*)d_in[25];

  unsigned short* kpb = (unsigned short*)d_ws;         // 8*2560*32 = 655360
  unsigned short* vtb = kpb + 655360;                  // 655360
  unsigned short* qsb = vtb + 655360;                  // 640000
  float* pl   = (float*)(qsb + 640000);                // 8*4*2500 = 80000
  float* pacc = pl + 80000;                            // *32 = 2560000
  float* a    = pacc + 2560000;                        // 640000

  // zero K/V bf16 buffers so the 40 pad keys contribute exp(0)=1 (corrected) and V=0
  (void)hipMemsetAsync(kpb, 0, (size_t)(655360 + 655360) * sizeof(unsigned short), stream);

  proj_kv_kernel<<<dim3(1260), dim3(128), 0, stream>>>(
      k, v, lnk_g, lnk_b, wk, bk, lnv_g, lnv_b, wv, bv, kpb, vtb);
  proj_q_kernel<<<dim3(1250), dim3(128), 0, stream>>>(
      q, lnq_g, lnq_b, wq, bq, qsb);
  attn_kernel<<<dim3(1280), dim3(256), 0, stream>>>(qsb, kpb, vtb, pl, pacc);
  combine_kernel<<<dim3(2500), dim3(256), 0, stream>>>(pl, pacc, a);
  tail_kernel<<<dim3(1250), dim3(128), 0, stream>>>(
      a, skip, wp, bp, ln1_g, ln1_b, w1, b1, w2, b2, ln2_g, ln2_b, (float*)d_out);
}

// Round 4
// 130.420 us; speedup vs baseline: 4.2131x; 1.0236x over previous
//
#include <hip/hip_runtime.h>
#include <hip/hip_bf16.h>
#include <math.h>

#define B_  2
#define N_  6
#define D_  128
#define Q_  2500
#define HK  420
#define NK  2520
#define NKP 2560      // padded keys (40 zero-pads)
#define M_  4
#define DH  32
#define SPLIT 4
#define KPSP 640      // NKP/SPLIT
#define CHUNKS 20     // KPSP/32
#define QT_TILES 157  // ceil(2500/16)
#define SCALE 0.17677669529663687f

typedef __attribute__((ext_vector_type(8))) short short8v;
typedef __attribute__((ext_vector_type(4))) float f32x4;

#define F4C(v, dd) ((dd)==0?(v).x:(dd)==1?(v).y:(dd)==2?(v).z:(v).w)

__device__ __forceinline__ unsigned short f2b(float x) {
  unsigned u = __float_as_uint(x);
  return (unsigned short)((u + 0x7FFFu + ((u >> 16) & 1u)) >> 16);
}

__device__ __forceinline__ unsigned pk2(float lo, float hi) {
  return (unsigned)f2b(lo) | ((unsigned)f2b(hi) << 16);
}

__device__ __forceinline__ short8v pack8(float4 f0, float4 f1) {
  short8v t;
  t[0] = (short)f2b(f0.x); t[1] = (short)f2b(f0.y);
  t[2] = (short)f2b(f0.z); t[3] = (short)f2b(f0.w);
  t[4] = (short)f2b(f1.x); t[5] = (short)f2b(f1.y);
  t[6] = (short)f2b(f1.z); t[7] = (short)f2b(f1.w);
  return t;
}

// block of 128 threads (2 waves): reduce (s, s2) across the block
__device__ __forceinline__ void block_reduce_pair(float& s, float& s2, float* scr, int t) {
  #pragma unroll
  for (int off = 1; off < 64; off <<= 1) {
    s  += __shfl_xor(s,  off);
    s2 += __shfl_xor(s2, off);
  }
  __syncthreads();
  if ((t & 63) == 0) { scr[(t >> 6) * 2] = s; scr[(t >> 6) * 2 + 1] = s2; }
  __syncthreads();
  s  = scr[0] + scr[2];
  s2 = scr[1] + scr[3];
}

// ---------------- Kernel P: pre-pack tail weights into bf16 MFMA fragment order ----------------
// frag layout: idx = ((c*JT + j)*64 + lane)*8 + e ; element = W[32c + 8*(lane>>4) + e][16j + (lane&15)]
__global__ __launch_bounds__(256)
void prepack_kernel(const float* __restrict__ wp, const float* __restrict__ w1,
                    const float* __restrict__ w2,
                    unsigned short* __restrict__ wpk, unsigned short* __restrict__ w1k,
                    unsigned short* __restrict__ w2k)
{
  const int tid = blockIdx.x * 256 + threadIdx.x;   // < 81920
  if (tid < 16384) {                                // wp: 4 chunks x 8 jtiles
    const int e = tid & 7, l = (tid >> 3) & 63, j = (tid >> 9) & 7, c = tid >> 12;
    wpk[tid] = f2b(wp[(32*c + 8*(l>>4) + e) * 128 + 16*j + (l & 15)]);
  } else if (tid < 16384 + 32768) {                 // w1: 4 chunks x 16 jtiles
    const int t2 = tid - 16384;
    const int e = t2 & 7, l = (t2 >> 3) & 63, j = (t2 >> 9) & 15, c = t2 >> 13;
    w1k[t2] = f2b(w1[(32*c + 8*(l>>4) + e) * 256 + 16*j + (l & 15)]);
  } else {                                          // w2: 8 chunks x 8 jtiles
    const int t2 = tid - 16384 - 32768;
    const int e = t2 & 7, l = (t2 >> 3) & 63, j = (t2 >> 9) & 7, c = t2 >> 12;
    w2k[t2] = f2b(w2[(32*c + 8*(l>>4) + e) * 128 + 16*j + (l & 15)]);
  }
}

// ---------------- Kernel A: LN + project K and V -> bf16 (K: [bm][key][dh], V^T: [bm*32+dh][key]) ----------------
__global__ __launch_bounds__(128)
void proj_kv_kernel(const float* __restrict__ kin, const float* __restrict__ vin,
                    const float* __restrict__ lnk_g, const float* __restrict__ lnk_b,
                    const float* __restrict__ wk, const float* __restrict__ bk,
                    const float* __restrict__ lnv_g, const float* __restrict__ lnv_b,
                    const float* __restrict__ wv, const float* __restrict__ bv,
                    unsigned short* __restrict__ kpb, unsigned short* __restrict__ vtb)
{
  const int t = threadIdx.x;
  if (blockIdx.x >= 1260) {            // zero the 40 pad keys of kpb and vtb
    const int base = (blockIdx.x - 1260) * 128 + t;      // 0..511
    for (int i = base; i < 10240; i += 512) {
      const int bm = i / 1280, rem = i % 1280;
      kpb[((size_t)bm * NKP + 2520 + rem / 32) * DH + (rem & 31)] = 0;
      vtb[((size_t)(i / 40)) * NKP + 2520 + (i % 40)] = 0;
    }
    return;
  }
  const int TR = 4;
  __shared__ float xln[TR][D_];
  __shared__ float scr[4];
  const int row0 = blockIdx.x * TR;       // rows in [0, 5040), never straddles b
  const int b = row0 / NK;
  const int key0 = row0 - b * NK;

  for (int ph = 0; ph < 2; ++ph) {
    const float* in = ph ? vin : kin;
    const float* g  = ph ? lnv_g : lnk_g;
    const float* bb = ph ? lnv_b : lnk_b;
    const float* w  = ph ? wv : wk;
    const float* bs = ph ? bv : bk;

    const float gv = g[t], blv = bb[t];
    #pragma unroll
    for (int r = 0; r < TR; ++r) {
      const int row = row0 + r;
      const int cam = row / HK;
      const int kk  = row - cam * HK;
      const float x = in[((size_t)(cam * D_ + t)) * HK + kk];
      float s = x, s2 = x * x;
      block_reduce_pair(s, s2, scr, t);
      const float mean = s * (1.f / D_);
      const float var  = s2 * (1.f / D_) - mean * mean;
      xln[r][t] = (x - mean) * rsqrtf(var + 1e-5f) * gv + blv;
    }
    __syncthreads();

    float acc[TR];
    #pragma unroll
    for (int r = 0; r < TR; ++r) acc[r] = 0.f;
    #pragma unroll 4
    for (int d0 = 0; d0 < D_; d0 += 4) {
      float4 xr[TR];
      #pragma unroll
      for (int r = 0; r < TR; ++r) xr[r] = *(const float4*)&xln[r][d0];
      #pragma unroll
      for (int dd = 0; dd < 4; ++dd) {
        const float wvv = w[(size_t)(d0 + dd) * 128 + t];
        #pragma unroll
        for (int r = 0; r < TR; ++r) acc[r] += F4C(xr[r], dd) * wvv;
      }
    }
    const float bsv = bs[t];
    if (ph == 0) {
      const int m = t >> 5, dh = t & 31;
      #pragma unroll
      for (int r = 0; r < TR; ++r)
        kpb[((size_t)(b * M_ + m) * NKP + key0 + r) * DH + dh] = f2b(acc[r] + bsv);
    } else {
      unsigned lo = pk2(acc[0] + bsv, acc[1] + bsv);
      unsigned hi = pk2(acc[2] + bsv, acc[3] + bsv);
      *(uint2*)&vtb[((size_t)(b * 128 + t)) * NKP + key0] = make_uint2(lo, hi);
    }
    __syncthreads();
  }
}

// ---------------- Kernel B: LN(q0)+LN(q1), project, pre-scale -> bf16 [b*Q+q][128] ----------------
__global__ __launch_bounds__(128)
void proj_q_kernel(const float* __restrict__ qin,
                   const float* __restrict__ lnq_g, const float* __restrict__ lnq_b,
                   const float* __restrict__ wq, const float* __restrict__ bq,
                   unsigned short* __restrict__ qsb)
{
  const int TR = 4;
  __shared__ float xln[TR][D_];
  __shared__ float scr[4];
  const int t = threadIdx.x;
  const int row0 = blockIdx.x * TR;      // [0, 5000)
  const float gv = lnq_g[t], blv = lnq_b[t];

  #pragma unroll
  for (int r = 0; r < TR; ++r) {
    const int row = row0 + r;
    const int b = row / Q_;
    const int qpos = row - b * Q_;
    float xs = 0.f;
    #pragma unroll
    for (int n = 0; n < 2; ++n) {
      const float x = qin[((size_t)((b * N_ + n) * D_ + t)) * Q_ + qpos];
      float s = x, s2 = x * x;
      block_reduce_pair(s, s2, scr, t);
      const float mean = s * (1.f / D_);
      const float var  = s2 * (1.f / D_) - mean * mean;
      xs += (x - mean) * rsqrtf(var + 1e-5f);
    }
    xln[r][t] = xs * gv + 2.f * blv;
  }
  __syncthreads();

  float acc[TR];
  #pragma unroll
  for (int r = 0; r < TR; ++r) acc[r] = 0.f;
  #pragma unroll 4
  for (int d0 = 0; d0 < D_; d0 += 4) {
    float4 xr[TR];
    #pragma unroll
    for (int r = 0; r < TR; ++r) xr[r] = *(const float4*)&xln[r][d0];
    #pragma unroll
    for (int dd = 0; dd < 4; ++dd) {
      const float wvv = wq[(size_t)(d0 + dd) * 128 + t];
      #pragma unroll
      for (int r = 0; r < TR; ++r) acc[r] += F4C(xr[r], dd) * wvv;
    }
  }
  const float bsv = 2.f * bq[t];
  #pragma unroll
  for (int r = 0; r < TR; ++r)
    qsb[((size_t)(row0 + r)) * 128 + t] = f2b((acc[r] + bsv) * SCALE);
}

// ---------------- Kernel C: MFMA flash attention (split-K partials) ----------------
__global__ __launch_bounds__(256)
void attn_kernel(const unsigned short* __restrict__ qsb,
                 const unsigned short* __restrict__ kpb,
                 const unsigned short* __restrict__ vtb,
                 float* __restrict__ pl, float* __restrict__ pacc)
{
  __shared__ __align__(16) char plds_all[4][16 * 80];
  const int wid  = threadIdx.x >> 6;
  const int lane = threadIdx.x & 63;
  const int bi = blockIdx.x;
  const int sp = bi & 3;
  const int tmp = bi >> 2;
  const int qt4 = tmp % 40;
  const int bm = tmp / 40;               // b*4+m
  const int qt = qt4 * 4 + wid;
  if (qt >= QT_TILES) return;

  const int q16 = lane & 15, g = lane >> 4;
  const int q = qt * 16 + q16;
  const int qc = q < Q_ ? q : Q_ - 1;
  const int b = bm >> 2;
  char* plds = plds_all[wid];

  const short8v qf = *(const short8v*)(qsb + ((size_t)(b * Q_ + qc)) * 128 + (bm & 3) * DH + g * 8);

  const unsigned short* kp1 = kpb + ((size_t)bm * NKP + sp * KPSP) * DH + q16 * DH + g * 8;
  const unsigned short* kp2 = kp1 + 16 * DH;
  const unsigned short* vp1 = vtb + ((size_t)(bm * DH + q16)) * NKP + sp * KPSP + g * 8;
  const unsigned short* vp2 = vp1 + (size_t)16 * NKP;

  f32x4 o0 = {0.f, 0.f, 0.f, 0.f}, o1 = {0.f, 0.f, 0.f, 0.f};
  float l = 0.f;

  short8v k1 = *(const short8v*)kp1, k2 = *(const short8v*)kp2;
  short8v v1 = *(const short8v*)vp1, v2 = *(const short8v*)vp2;

  for (int c = 0; c < CHUNKS; ++c) {
    const short8v ck1 = k1, ck2 = k2, cv1 = v1, cv2 = v2;
    if (c < CHUNKS - 1) {
      kp1 += 32 * DH; kp2 += 32 * DH; vp1 += 32; vp2 += 32;
      k1 = *(const short8v*)kp1; k2 = *(const short8v*)kp2;
      v1 = *(const short8v*)vp1; v2 = *(const short8v*)vp2;
    }
    f32x4 s0 = __builtin_amdgcn_mfma_f32_16x16x32_bf16(ck1, qf, (f32x4){0.f,0.f,0.f,0.f}, 0, 0, 0);
    f32x4 s1 = __builtin_amdgcn_mfma_f32_16x16x32_bf16(ck2, qf, (f32x4){0.f,0.f,0.f,0.f}, 0, 0, 0);

    float p[8];
    #pragma unroll
    for (int r = 0; r < 4; ++r) { p[r] = __expf(s0[r]); p[4 + r] = __expf(s1[r]); }
    #pragma unroll
    for (int i = 0; i < 8; ++i) l += p[i];

    uint2 w1v, w2v;
    w1v.x = pk2(p[0], p[1]); w1v.y = pk2(p[2], p[3]);
    w2v.x = pk2(p[4], p[5]); w2v.y = pk2(p[6], p[7]);
    *(uint2*)(plds + q16 * 80 + g * 8)      = w1v;
    *(uint2*)(plds + q16 * 80 + 32 + g * 8) = w2v;
    const short8v pb = *(const short8v*)(plds + q16 * 80 + g * 16);

    o0 = __builtin_amdgcn_mfma_f32_16x16x32_bf16(cv1, pb, o0, 0, 0, 0);
    o1 = __builtin_amdgcn_mfma_f32_16x16x32_bf16(cv2, pb, o1, 0, 0, 0);
  }

  l += __shfl_xor(l, 16);
  l += __shfl_xor(l, 32);

  if (q < Q_) {
    const size_t row = (size_t)(bm * SPLIT + sp) * Q_ + q;
    if (lane < 16) pl[row] = l;
    *(f32x4*)(pacc + row * DH + 4 * g)      = o0;
    *(f32x4*)(pacc + row * DH + 16 + 4 * g) = o1;
  }
}

// ---------------- Kernel C2: combine split-K partials ----------------
__global__ __launch_bounds__(256)
void combine_kernel(const float* __restrict__ pl, const float* __restrict__ pacc,
                    float* __restrict__ a)
{
  const int o = blockIdx.x * 256 + threadIdx.x;   // < 640000
  const int j = o & 31;
  const int bmq = o >> 5;
  const int q = bmq % Q_;
  const int bm = bmq / Q_;
  const int m = bm & 3, b = bm >> 2;
  float ls = -40.0f;                               // correction for 40 zero-pad keys
  float as = 0.f;
  #pragma unroll
  for (int sp = 0; sp < SPLIT; ++sp) {
    const size_t row = (size_t)(bm * SPLIT + sp) * Q_ + q;
    ls += pl[row];
    as += pacc[row * DH + j];
  }
  a[((size_t)(b * Q_ + q)) * 128 + m * DH + j] = as / ls;
}

// ---------------- Kernel D: MFMA tail — proj + skip + LN1 + MLP(GELU) + LN2 + transpose ----------------
// 4 waves/block, each wave owns a 16-row tile. Wave-private LDS slices (no __syncthreads).
__global__ __launch_bounds__(256)
void tail_mfma_kernel(const float* __restrict__ a, const float* __restrict__ skip,
                      const unsigned short* __restrict__ wpk, const float* __restrict__ bp,
                      const float* __restrict__ ln1_g, const float* __restrict__ ln1_b,
                      const unsigned short* __restrict__ w1k, const float* __restrict__ b1,
                      const unsigned short* __restrict__ w2k, const float* __restrict__ b2,
                      const float* __restrict__ ln2_g, const float* __restrict__ ln2_b,
                      float* __restrict__ out)
{
  __shared__ __align__(16) unsigned short zlds[4][16][136];
  __shared__ __align__(16) unsigned short hlds[4][16][264];
  const int wid = threadIdx.x >> 6, lane = threadIdx.x & 63;
  const int tile = blockIdx.x * 4 + wid;
  if (tile >= 313) return;
  const int row0 = tile * 16;
  const int l15 = lane & 15, g = lane >> 4;

  // ---- A-frags of attention output (rows row0..row0+15)
  short8v aA[4];
  {
    int arow = row0 + l15; if (arow > 4999) arow = 4999;
    const float* ap = a + (size_t)arow * 128 + 8 * g;
    #pragma unroll
    for (int c = 0; c < 4; ++c)
      aA[c] = pack8(*(const float4*)(ap + 32 * c), *(const float4*)(ap + 32 * c + 4));
  }

  // ---- GEMM1: z = a @ wp   (D layout: col=16j+l15, rows 4g+r)
  f32x4 z[8];
  #pragma unroll
  for (int j = 0; j < 8; ++j) {
    f32x4 d = {0.f, 0.f, 0.f, 0.f};
    #pragma unroll
    for (int c = 0; c < 4; ++c) {
      const short8v wf = *(const short8v*)(wpk + (((c * 8 + j) * 64 + lane) << 3));
      d = __builtin_amdgcn_mfma_f32_16x16x32_bf16(aA[c], wf, d, 0, 0, 0);
    }
    z[j] = d;
  }

  const int grow0 = row0 + 4 * g;
  // ---- + bp + skip, LN1 stats
  float sum[4] = {0,0,0,0}, sq[4] = {0,0,0,0};
  #pragma unroll
  for (int j = 0; j < 8; ++j) {
    const int col = 16 * j + l15;
    const float bpv = bp[col];
    #pragma unroll
    for (int r = 0; r < 4; ++r) {
      int rr = grow0 + r; if (rr > 4999) rr = 4999;
      const int bb = rr / 2500, q = rr - bb * 2500;
      const float val = z[j][r] + bpv + skip[((size_t)(bb * 128 + col)) * 2500 + q];
      z[j][r] = val;
      sum[r] += val; sq[r] += val * val;
    }
  }
  #pragma unroll
  for (int r = 0; r < 4; ++r) {
    #pragma unroll
    for (int off = 1; off < 16; off <<= 1) {
      sum[r] += __shfl_xor(sum[r], off);
      sq[r]  += __shfl_xor(sq[r], off);
    }
  }
  float mean[4], rstd[4];
  #pragma unroll
  for (int r = 0; r < 4; ++r) {
    mean[r] = sum[r] * (1.f / 128.f);
    const float var = sq[r] * (1.f / 128.f) - mean[r] * mean[r];
    rstd[r] = rsqrtf(var + 1e-5f);
  }
  unsigned short (*zw)[136] = zlds[wid];
  #pragma unroll
  for (int j = 0; j < 8; ++j) {
    const int col = 16 * j + l15;
    const float g1 = ln1_g[col], bv1 = ln1_b[col];
    #pragma unroll
    for (int r = 0; r < 4; ++r) {
      const float vv = (z[j][r] - mean[r]) * rstd[r] * g1 + bv1;
      z[j][r] = vv;                       // keep for residual
      zw[4 * g + r][col] = f2b(vv);
    }
  }

  // ---- GEMM2: h = gelu(z_ln @ w1 + b1) -> hlds (bf16)
  short8v zA[4];
  #pragma unroll
  for (int c = 0; c < 4; ++c)
    zA[c] = *(const short8v*)&zw[l15][32 * c + 8 * g];
  unsigned short (*hw)[264] = hlds[wid];
  #pragma unroll
  for (int j = 0; j < 16; ++j) {
    f32x4 d = {0.f, 0.f, 0.f, 0.f};
    #pragma unroll
    for (int c = 0; c < 4; ++c) {
      const short8v wf = *(const short8v*)(w1k + (((c * 16 + j) * 64 + lane) << 3));
      d = __builtin_amdgcn_mfma_f32_16x16x32_bf16(zA[c], wf, d, 0, 0, 0);
    }
    const int col = 16 * j + l15;
    const float bv = b1[col];
    #pragma unroll
    for (int r = 0; r < 4; ++r) {
      const float x = d[r] + bv;
      hw[4 * g + r][col] = f2b(0.5f * x * (1.f + erff(x * 0.70710678118654752f)));
    }
  }

  // ---- GEMM3: y = h @ w2 ; residual + LN2
  short8v hA[8];
  #pragma unroll
  for (int c = 0; c < 8; ++c)
    hA[c] = *(const short8v*)&hw[l15][32 * c + 8 * g];
  float sum2[4] = {0,0,0,0}, sq2[4] = {0,0,0,0};
  #pragma unroll
  for (int j = 0; j < 8; ++j) {
    f32x4 d = {0.f, 0.f, 0.f, 0.f};
    #pragma unroll
    for (int c = 0; c < 8; ++c) {
      const short8v wf = *(const short8v*)(w2k + (((c * 8 + j) * 64 + lane) << 3));
      d = __builtin_amdgcn_mfma_f32_16x16x32_bf16(hA[c], wf, d, 0, 0, 0);
    }
    const int col = 16 * j + l15;
    const float bv = b2[col];
    #pragma unroll
    for (int r = 0; r < 4; ++r) {
      const float vv = z[j][r] + d[r] + bv;
      z[j][r] = vv;
      sum2[r] += vv; sq2[r] += vv * vv;
    }
  }
  #pragma unroll
  for (int r = 0; r < 4; ++r) {
    #pragma unroll
    for (int off = 1; off < 16; off <<= 1) {
      sum2[r] += __shfl_xor(sum2[r], off);
      sq2[r]  += __shfl_xor(sq2[r], off);
    }
  }
  float mean2[4], rstd2[4];
  #pragma unroll
  for (int r = 0; r < 4; ++r) {
    mean2[r] = sum2[r] * (1.f / 128.f);
    const float var = sq2[r] * (1.f / 128.f) - mean2[r] * mean2[r];
    rstd2[r] = rsqrtf(var + 1e-5f);
  }

  // ---- store (4-row groups are 4-aligned; 2500%4==0 so a group never straddles b)
  if (grow0 + 3 <= 4999) {
    const int bb = grow0 / 2500, q0 = grow0 - bb * 2500;
    #pragma unroll
    for (int j = 0; j < 8; ++j) {
      const int col = 16 * j + l15;
      const float g2 = ln2_g[col], bv2 = ln2_b[col];
      float4 o;
      o.x = (z[j][0] - mean2[0]) * rstd2[0] * g2 + bv2;
      o.y = (z[j][1] - mean2[1]) * rstd2[1] * g2 + bv2;
      o.z = (z[j][2] - mean2[2]) * rstd2[2] * g2 + bv2;
      o.w = (z[j][3] - mean2[3]) * rstd2[3] * g2 + bv2;
      *(float4*)(out + ((size_t)(bb * 128 + col)) * 2500 + q0) = o;
    }
  }
}

extern "C" void kernel_launch(void* const* d_in, const int* in_sizes, int n_in,
                              void* d_out, int out_size, void* d_ws, size_t ws_size,
                              hipStream_t stream)
{
  const float* q     = (const float*)d_in[0];
  const float* k     = (const float*)d_in[1];
  const float* v     = (const float*)d_in[2];
  const float* skip  = (const float*)d_in[3];
  const float* lnq_g = (const float*)d_in[4];
  const float* lnq_b = (const float*)d_in[5];
  const float* wq    = (const float*)d_in[6];
  const float* bq    = (const float*)d_in[7];
  const float* lnk_g = (const float*)d_in[8];
  const float* lnk_b = (const float*)d_in[9];
  const float* wk    = (const float*)d_in[10];
  const float* bk    = (const float*)d_in[11];
  const float* lnv_g = (const float*)d_in[12];
  const float* lnv_b = (const float*)d_in[13];
  const float* wv    = (const float*)d_in[14];
  const float* bv    = (const float*)d_in[15];
  const float* wp    = (const float*)d_in[16];
  const float* bp    = (const float*)d_in[17];
  const float* ln1_g = (const float*)d_in[18];
  const float* ln1_b = (const float*)d_in[19];
  const float* w1    = (const float*)d_in[20];
  const float* b1    = (const float*)d_in[21];
  const float* w2    = (const float*)d_in[22];
  const float* b2    = (const float*)d_in[23];
  const float* ln2_g = (const float*)d_in[24];
  const float* ln2_b = (const float*)d_in[25];

  unsigned short* kpb = (unsigned short*)d_ws;         // 8*2560*32 = 655360
  unsigned short* vtb = kpb + 655360;                  // 655360
  unsigned short* qsb = vtb + 655360;                  // 640000
  unsigned short* wpk = qsb + 640000;                  // 16384
  unsigned short* w1k = wpk + 16384;                   // 32768
  unsigned short* w2k = w1k + 32768;                   // 32768
  float* pl   = (float*)(w2k + 32768);                 // 8*4*2500 = 80000
  float* pacc = pl + 80000;                            // *32 = 2560000
  float* a    = pacc + 2560000;                        // 640000

  prepack_kernel<<<dim3(320), dim3(256), 0, stream>>>(wp, w1, w2, wpk, w1k, w2k);
  proj_kv_kernel<<<dim3(1264), dim3(128), 0, stream>>>(
      k, v, lnk_g, lnk_b, wk, bk, lnv_g, lnv_b, wv, bv, kpb, vtb);
  proj_q_kernel<<<dim3(1250), dim3(128), 0, stream>>>(
      q, lnq_g, lnq_b, wq, bq, qsb);
  attn_kernel<<<dim3(1280), dim3(256), 0, stream>>>(qsb, kpb, vtb, pl, pacc);
  combine_kernel<<<dim3(2500), dim3(256), 0, stream>>>(pl, pacc, a);
  tail_mfma_kernel<<<dim3(79), dim3(256), 0, stream>>>(
      a, skip, wpk, bp, ln1_g, ln1_b, w1k, b1, w2k, b2, ln2_g, ln2_b, (float*)d_out);
}

// Round 5
// 113.130 us; speedup vs baseline: 4.8570x; 1.1528x over previous
//
#include <hip/hip_runtime.h>
#include <hip/hip_bf16.h>
#include <math.h>

#define B_  2
#define N_  6
#define D_  128
#define Q_  2500
#define HK  420
#define NK  2520
#define NKP 2560      // padded keys (40 zero-pads)
#define M_  4
#define DH  32
#define SPLIT 8
#define KPSP 320      // NKP/SPLIT
#define CHUNKS 10     // KPSP/32
#define QT_TILES 157  // ceil(2500/16)
#define SCALE 0.17677669529663687f

typedef __attribute__((ext_vector_type(8))) short short8v;
typedef __attribute__((ext_vector_type(4))) float f32x4;

__device__ __forceinline__ unsigned short f2b(float x) {
  unsigned u = __float_as_uint(x);
  return (unsigned short)((u + 0x7FFFu + ((u >> 16) & 1u)) >> 16);
}

__device__ __forceinline__ unsigned pk2(float lo, float hi) {
  return (unsigned)f2b(lo) | ((unsigned)f2b(hi) << 16);
}

__device__ __forceinline__ short8v pack8(float4 f0, float4 f1) {
  short8v t;
  t[0] = (short)f2b(f0.x); t[1] = (short)f2b(f0.y);
  t[2] = (short)f2b(f0.z); t[3] = (short)f2b(f0.w);
  t[4] = (short)f2b(f1.x); t[5] = (short)f2b(f1.y);
  t[6] = (short)f2b(f1.z); t[7] = (short)f2b(f1.w);
  return t;
}

// ---------------- Kernel P: pre-pack all weights into bf16 MFMA B-fragment order ----------------
// frag idx = ((c*JT + j)*64 + lane)*8 + e ; element = W[32c + 8*(lane>>4) + e][16j + (lane&15)]
__global__ __launch_bounds__(256)
void prepack_kernel(const float* __restrict__ wp, const float* __restrict__ w1,
                    const float* __restrict__ w2, const float* __restrict__ wq,
                    const float* __restrict__ wk, const float* __restrict__ wv,
                    unsigned short* __restrict__ wpk, unsigned short* __restrict__ w1k,
                    unsigned short* __restrict__ w2k, unsigned short* __restrict__ wqk,
                    unsigned short* __restrict__ wkk, unsigned short* __restrict__ wvk)
{
  const int tid = blockIdx.x * 256 + threadIdx.x;   // < 131072
  if (tid < 16384) {                                // wp: [128][128]
    const int e = tid & 7, l = (tid >> 3) & 63, j = (tid >> 9) & 7, c = tid >> 12;
    wpk[tid] = f2b(wp[(32*c + 8*(l>>4) + e) * 128 + 16*j + (l & 15)]);
  } else if (tid < 49152) {                         // w1: [128][256]
    const int t2 = tid - 16384;
    const int e = t2 & 7, l = (t2 >> 3) & 63, j = (t2 >> 9) & 15, c = t2 >> 13;
    w1k[t2] = f2b(w1[(32*c + 8*(l>>4) + e) * 256 + 16*j + (l & 15)]);
  } else if (tid < 81920) {                         // w2: [256][128]
    const int t2 = tid - 49152;
    const int e = t2 & 7, l = (t2 >> 3) & 63, j = (t2 >> 9) & 7, c = t2 >> 12;
    w2k[t2] = f2b(w2[(32*c + 8*(l>>4) + e) * 128 + 16*j + (l & 15)]);
  } else {                                          // wq/wk/wv: [128][128]
    const int t2 = (tid - 81920) & 16383;
    const int which = (tid - 81920) >> 14;
    const float* src = which == 0 ? wq : which == 1 ? wk : wv;
    unsigned short* dst = which == 0 ? wqk : which == 1 ? wkk : wvk;
    const int e = t2 & 7, l = (t2 >> 3) & 63, j = (t2 >> 9) & 7, c = t2 >> 12;
    dst[t2] = f2b(src[(32*c + 8*(l>>4) + e) * 128 + 16*j + (l & 15)]);
  }
}

// ---------------- Kernel A: MFMA LN+project K and V ----------------
// One wave per 16-key tile per phase (K or V). No LDS, no __syncthreads.
__global__ __launch_bounds__(256)
void proj_kv_mfma(const float* __restrict__ kin, const float* __restrict__ vin,
                  const float* __restrict__ lnk_g, const float* __restrict__ lnk_b,
                  const unsigned short* __restrict__ wkk, const float* __restrict__ bk,
                  const float* __restrict__ lnv_g, const float* __restrict__ lnv_b,
                  const unsigned short* __restrict__ wvk, const float* __restrict__ bv,
                  unsigned short* __restrict__ kpb, unsigned short* __restrict__ vtb)
{
  if (blockIdx.x >= 158) {             // zero 40 pad keys of kpb and vtb
    const int base = (blockIdx.x - 158) * 256 + threadIdx.x;   // 0..511
    for (int i = base; i < 10240; i += 512) {
      const int bm = i / 1280, rem = i % 1280;
      kpb[((size_t)bm * NKP + 2520 + rem / 32) * DH + (rem & 31)] = 0;
      vtb[((size_t)(i / 40)) * NKP + 2520 + (i % 40)] = 0;
    }
    return;
  }
  const int wid = threadIdx.x >> 6, lane = threadIdx.x & 63;
  const int T = blockIdx.x * 4 + wid;
  if (T >= 630) return;
  const int ph = T >= 315 ? 1 : 0;
  const int t = ph ? T - 315 : T;

  const float* in = ph ? vin : kin;
  const float* gg = ph ? lnv_g : lnk_g;
  const float* bb = ph ? lnv_b : lnk_b;
  const unsigned short* wf = ph ? wvk : wkk;
  const float* bs = ph ? bv : bk;

  const int l15 = lane & 15, g = lane >> 4;
  const int myrow = 16 * t + l15;                 // global key idx 0..5039
  const int cam = myrow / HK, kk = myrow - cam * HK;

  float x[4][8];
  float s = 0.f, s2 = 0.f;
  #pragma unroll
  for (int c = 0; c < 4; ++c)
    #pragma unroll
    for (int e = 0; e < 8; ++e) {
      const float xv = in[((size_t)(cam * D_ + 32 * c + 8 * g + e)) * HK + kk];
      x[c][e] = xv; s += xv; s2 += xv * xv;
    }
  s  += __shfl_xor(s, 16);  s2 += __shfl_xor(s2, 16);
  s  += __shfl_xor(s, 32);  s2 += __shfl_xor(s2, 32);
  const float mean = s * (1.f / 128.f);
  const float rstd = rsqrtf(s2 * (1.f / 128.f) - mean * mean + 1e-5f);

  short8v aA[4];
  #pragma unroll
  for (int c = 0; c < 4; ++c) {
    #pragma unroll
    for (int e = 0; e < 8; ++e) {
      const int col = 32 * c + 8 * g + e;
      aA[c][e] = (short)f2b((x[c][e] - mean) * rstd * gg[col] + bb[col]);
    }
  }

  f32x4 z[8];
  #pragma unroll
  for (int j = 0; j < 8; ++j) {
    f32x4 d = {0.f, 0.f, 0.f, 0.f};
    #pragma unroll
    for (int c = 0; c < 4; ++c) {
      const short8v w8 = *(const short8v*)(wf + (((c * 8 + j) * 64 + lane) << 3));
      d = __builtin_amdgcn_mfma_f32_16x16x32_bf16(aA[c], w8, d, 0, 0, 0);
    }
    z[j] = d;
  }

  const int key0 = 16 * t + 4 * g;                // D rows: key0 + r
  #pragma unroll
  for (int j = 0; j < 8; ++j) {
    const int col = 16 * j + l15;
    const float bsv = bs[col];
    if (ph == 0) {
      const int m = col >> 5, dh = col & 31;
      #pragma unroll
      for (int r = 0; r < 4; ++r) {
        const int key = key0 + r;
        const int bbx = key / NK, kb = key - bbx * NK;
        kpb[((size_t)(bbx * M_ + m) * NKP + kb) * DH + dh] = f2b(z[j][r] + bsv);
      }
    } else {
      #pragma unroll
      for (int r = 0; r < 4; ++r) {
        const int key = key0 + r;
        const int bbx = key / NK, kb = key - bbx * NK;
        vtb[((size_t)(bbx * 128 + col)) * NKP + kb] = f2b(z[j][r] + bsv);
      }
    }
  }
}

// ---------------- Kernel B: MFMA LN(q0)+LN(q1) + project + pre-scale ----------------
__global__ __launch_bounds__(256)
void proj_q_mfma(const float* __restrict__ qin,
                 const float* __restrict__ lnq_g, const float* __restrict__ lnq_b,
                 const unsigned short* __restrict__ wqk, const float* __restrict__ bq,
                 unsigned short* __restrict__ qsb)
{
  const int wid = threadIdx.x >> 6, lane = threadIdx.x & 63;
  const int t = blockIdx.x * 4 + wid;
  if (t >= 313) return;
  const int l15 = lane & 15, g = lane >> 4;
  int myrow = 16 * t + l15; if (myrow > 4999) myrow = 4999;
  const int b = myrow / Q_, qpos = myrow - b * Q_;

  float xs[4][8];
  #pragma unroll
  for (int c = 0; c < 4; ++c)
    #pragma unroll
    for (int e = 0; e < 8; ++e) xs[c][e] = 0.f;

  #pragma unroll
  for (int n = 0; n < 2; ++n) {
    float x[4][8];
    float s = 0.f, s2 = 0.f;
    #pragma unroll
    for (int c = 0; c < 4; ++c)
      #pragma unroll
      for (int e = 0; e < 8; ++e) {
        const float xv = qin[((size_t)((b * N_ + n) * D_ + 32 * c + 8 * g + e)) * Q_ + qpos];
        x[c][e] = xv; s += xv; s2 += xv * xv;
      }
    s  += __shfl_xor(s, 16);  s2 += __shfl_xor(s2, 16);
    s  += __shfl_xor(s, 32);  s2 += __shfl_xor(s2, 32);
    const float mean = s * (1.f / 128.f);
    const float rstd = rsqrtf(s2 * (1.f / 128.f) - mean * mean + 1e-5f);
    #pragma unroll
    for (int c = 0; c < 4; ++c)
      #pragma unroll
      for (int e = 0; e < 8; ++e) xs[c][e] += (x[c][e] - mean) * rstd;
  }

  short8v aA[4];
  #pragma unroll
  for (int c = 0; c < 4; ++c) {
    #pragma unroll
    for (int e = 0; e < 8; ++e) {
      const int col = 32 * c + 8 * g + e;
      aA[c][e] = (short)f2b(SCALE * (xs[c][e] * lnq_g[col] + 2.f * lnq_b[col]));
    }
  }

  f32x4 z[8];
  #pragma unroll
  for (int j = 0; j < 8; ++j) {
    f32x4 d = {0.f, 0.f, 0.f, 0.f};
    #pragma unroll
    for (int c = 0; c < 4; ++c) {
      const short8v w8 = *(const short8v*)(wqk + (((c * 8 + j) * 64 + lane) << 3));
      d = __builtin_amdgcn_mfma_f32_16x16x32_bf16(aA[c], w8, d, 0, 0, 0);
    }
    z[j] = d;
  }

  const int row0 = 16 * t + 4 * g;
  #pragma unroll
  for (int j = 0; j < 8; ++j) {
    const int col = 16 * j + l15;
    const float bsv = 2.f * SCALE * bq[col];
    #pragma unroll
    for (int r = 0; r < 4; ++r) {
      const int row = row0 + r;
      if (row < 5000) qsb[((size_t)row) * 128 + col] = f2b(z[j][r] + bsv);
    }
  }
}

// ---------------- Kernel C: MFMA flash attention (split-K partials) ----------------
__global__ __launch_bounds__(256)
void attn_kernel(const unsigned short* __restrict__ qsb,
                 const unsigned short* __restrict__ kpb,
                 const unsigned short* __restrict__ vtb,
                 float* __restrict__ pl, float* __restrict__ pacc)
{
  __shared__ __align__(16) char plds_all[4][16 * 80];
  const int wid  = threadIdx.x >> 6;
  const int lane = threadIdx.x & 63;
  const int bi = blockIdx.x;
  const int sp = bi & 7;
  const int tmp = bi >> 3;
  const int qt4 = tmp % 40;
  const int bm = tmp / 40;               // b*4+m
  const int qt = qt4 * 4 + wid;
  if (qt >= QT_TILES) return;

  const int q16 = lane & 15, g = lane >> 4;
  const int q = qt * 16 + q16;
  const int qc = q < Q_ ? q : Q_ - 1;
  const int b = bm >> 2;
  char* plds = plds_all[wid];

  const short8v qf = *(const short8v*)(qsb + ((size_t)(b * Q_ + qc)) * 128 + (bm & 3) * DH + g * 8);

  const unsigned short* kp1 = kpb + ((size_t)bm * NKP + sp * KPSP) * DH + q16 * DH + g * 8;
  const unsigned short* kp2 = kp1 + 16 * DH;
  const unsigned short* vp1 = vtb + ((size_t)(bm * DH + q16)) * NKP + sp * KPSP + g * 8;
  const unsigned short* vp2 = vp1 + (size_t)16 * NKP;

  f32x4 o0 = {0.f, 0.f, 0.f, 0.f}, o1 = {0.f, 0.f, 0.f, 0.f};
  float l = 0.f;

  short8v k1 = *(const short8v*)kp1, k2 = *(const short8v*)kp2;
  short8v v1 = *(const short8v*)vp1, v2 = *(const short8v*)vp2;

  for (int c = 0; c < CHUNKS; ++c) {
    const short8v ck1 = k1, ck2 = k2, cv1 = v1, cv2 = v2;
    if (c < CHUNKS - 1) {
      kp1 += 32 * DH; kp2 += 32 * DH; vp1 += 32; vp2 += 32;
      k1 = *(const short8v*)kp1; k2 = *(const short8v*)kp2;
      v1 = *(const short8v*)vp1; v2 = *(const short8v*)vp2;
    }
    f32x4 s0 = __builtin_amdgcn_mfma_f32_16x16x32_bf16(ck1, qf, (f32x4){0.f,0.f,0.f,0.f}, 0, 0, 0);
    f32x4 s1 = __builtin_amdgcn_mfma_f32_16x16x32_bf16(ck2, qf, (f32x4){0.f,0.f,0.f,0.f}, 0, 0, 0);

    float p[8];
    #pragma unroll
    for (int r = 0; r < 4; ++r) { p[r] = __expf(s0[r]); p[4 + r] = __expf(s1[r]); }
    #pragma unroll
    for (int i = 0; i < 8; ++i) l += p[i];

    uint2 w1v, w2v;
    w1v.x = pk2(p[0], p[1]); w1v.y = pk2(p[2], p[3]);
    w2v.x = pk2(p[4], p[5]); w2v.y = pk2(p[6], p[7]);
    *(uint2*)(plds + q16 * 80 + g * 8)      = w1v;
    *(uint2*)(plds + q16 * 80 + 32 + g * 8) = w2v;
    const short8v pb = *(const short8v*)(plds + q16 * 80 + g * 16);

    o0 = __builtin_amdgcn_mfma_f32_16x16x32_bf16(cv1, pb, o0, 0, 0, 0);
    o1 = __builtin_amdgcn_mfma_f32_16x16x32_bf16(cv2, pb, o1, 0, 0, 0);
  }

  l += __shfl_xor(l, 16);
  l += __shfl_xor(l, 32);

  if (q < Q_) {
    const size_t row = (size_t)(bm * SPLIT + sp) * Q_ + q;
    if (lane < 16) pl[row] = l;
    *(f32x4*)(pacc + row * DH + 4 * g)      = o0;
    *(f32x4*)(pacc + row * DH + 16 + 4 * g) = o1;
  }
}

// ---------------- Kernel C2: combine split-K partials ----------------
__global__ __launch_bounds__(256)
void combine_kernel(const float* __restrict__ pl, const float* __restrict__ pacc,
                    float* __restrict__ a)
{
  const int o = blockIdx.x * 256 + threadIdx.x;   // < 640000
  const int j = o & 31;
  const int bmq = o >> 5;
  const int q = bmq % Q_;
  const int bm = bmq / Q_;
  const int m = bm & 3, b = bm >> 2;
  float ls = -40.0f;                               // correction for 40 zero-pad keys
  float as = 0.f;
  #pragma unroll
  for (int sp = 0; sp < SPLIT; ++sp) {
    const size_t row = (size_t)(bm * SPLIT + sp) * Q_ + q;
    ls += pl[row];
    as += pacc[row * DH + j];
  }
  a[((size_t)(b * Q_ + q)) * 128 + m * DH + j] = as / ls;
}

// ---------------- Kernel D: MFMA tail — proj + skip + LN1 + MLP(GELU) + LN2 + transpose ----------------
__global__ __launch_bounds__(256)
void tail_mfma_kernel(const float* __restrict__ a, const float* __restrict__ skip,
                      const unsigned short* __restrict__ wpk, const float* __restrict__ bp,
                      const float* __restrict__ ln1_g, const float* __restrict__ ln1_b,
                      const unsigned short* __restrict__ w1k, const float* __restrict__ b1,
                      const unsigned short* __restrict__ w2k, const float* __restrict__ b2,
                      const float* __restrict__ ln2_g, const float* __restrict__ ln2_b,
                      float* __restrict__ out)
{
  __shared__ __align__(16) unsigned short zlds[4][16][136];
  __shared__ __align__(16) unsigned short hlds[4][16][264];
  const int wid = threadIdx.x >> 6, lane = threadIdx.x & 63;
  const int tile = blockIdx.x * 4 + wid;
  if (tile >= 313) return;
  const int row0 = tile * 16;
  const int l15 = lane & 15, g = lane >> 4;

  short8v aA[4];
  {
    int arow = row0 + l15; if (arow > 4999) arow = 4999;
    const float* ap = a + (size_t)arow * 128 + 8 * g;
    #pragma unroll
    for (int c = 0; c < 4; ++c)
      aA[c] = pack8(*(const float4*)(ap + 32 * c), *(const float4*)(ap + 32 * c + 4));
  }

  f32x4 z[8];
  #pragma unroll
  for (int j = 0; j < 8; ++j) {
    f32x4 d = {0.f, 0.f, 0.f, 0.f};
    #pragma unroll
    for (int c = 0; c < 4; ++c) {
      const short8v wf = *(const short8v*)(wpk + (((c * 8 + j) * 64 + lane) << 3));
      d = __builtin_amdgcn_mfma_f32_16x16x32_bf16(aA[c], wf, d, 0, 0, 0);
    }
    z[j] = d;
  }

  const int grow0 = row0 + 4 * g;
  float sum[4] = {0,0,0,0}, sq[4] = {0,0,0,0};
  #pragma unroll
  for (int j = 0; j < 8; ++j) {
    const int col = 16 * j + l15;
    const float bpv = bp[col];
    #pragma unroll
    for (int r = 0; r < 4; ++r) {
      int rr = grow0 + r; if (rr > 4999) rr = 4999;
      const int bb = rr / 2500, q = rr - bb * 2500;
      const float val = z[j][r] + bpv + skip[((size_t)(bb * 128 + col)) * 2500 + q];
      z[j][r] = val;
      sum[r] += val; sq[r] += val * val;
    }
  }
  #pragma unroll
  for (int r = 0; r < 4; ++r) {
    #pragma unroll
    for (int off = 1; off < 16; off <<= 1) {
      sum[r] += __shfl_xor(sum[r], off);
      sq[r]  += __shfl_xor(sq[r], off);
    }
  }
  float mean[4], rstd[4];
  #pragma unroll
  for (int r = 0; r < 4; ++r) {
    mean[r] = sum[r] * (1.f / 128.f);
    const float var = sq[r] * (1.f / 128.f) - mean[r] * mean[r];
    rstd[r] = rsqrtf(var + 1e-5f);
  }
  unsigned short (*zw)[136] = zlds[wid];
  #pragma unroll
  for (int j = 0; j < 8; ++j) {
    const int col = 16 * j + l15;
    const float g1 = ln1_g[col], bv1 = ln1_b[col];
    #pragma unroll
    for (int r = 0; r < 4; ++r) {
      const float vv = (z[j][r] - mean[r]) * rstd[r] * g1 + bv1;
      z[j][r] = vv;
      zw[4 * g + r][col] = f2b(vv);
    }
  }

  short8v zA[4];
  #pragma unroll
  for (int c = 0; c < 4; ++c)
    zA[c] = *(const short8v*)&zw[l15][32 * c + 8 * g];
  unsigned short (*hw)[264] = hlds[wid];
  #pragma unroll
  for (int j = 0; j < 16; ++j) {
    f32x4 d = {0.f, 0.f, 0.f, 0.f};
    #pragma unroll
    for (int c = 0; c < 4; ++c) {
      const short8v wf = *(const short8v*)(w1k + (((c * 16 + j) * 64 + lane) << 3));
      d = __builtin_amdgcn_mfma_f32_16x16x32_bf16(zA[c], wf, d, 0, 0, 0);
    }
    const int col = 16 * j + l15;
    const float bv = b1[col];
    #pragma unroll
    for (int r = 0; r < 4; ++r) {
      const float x = d[r] + bv;
      hw[4 * g + r][col] = f2b(0.5f * x * (1.f + erff(x * 0.70710678118654752f)));
    }
  }

  short8v hA[8];
  #pragma unroll
  for (int c = 0; c < 8; ++c)
    hA[c] = *(const short8v*)&hw[l15][32 * c + 8 * g];
  float sum2[4] = {0,0,0,0}, sq2[4] = {0,0,0,0};
  #pragma unroll
  for (int j = 0; j < 8; ++j) {
    f32x4 d = {0.f, 0.f, 0.f, 0.f};
    #pragma unroll
    for (int c = 0; c < 8; ++c) {
      const short8v wf = *(const short8v*)(w2k + (((c * 8 + j) * 64 + lane) << 3));
      d = __builtin_amdgcn_mfma_f32_16x16x32_bf16(hA[c], wf, d, 0, 0, 0);
    }
    const int col = 16 * j + l15;
    const float bv = b2[col];
    #pragma unroll
    for (int r = 0; r < 4; ++r) {
      const float vv = z[j][r] + d[r] + bv;
      z[j][r] = vv;
      sum2[r] += vv; sq2[r] += vv * vv;
    }
  }
  #pragma unroll
  for (int r = 0; r < 4; ++r) {
    #pragma unroll
    for (int off = 1; off < 16; off <<= 1) {
      sum2[r] += __shfl_xor(sum2[r], off);
      sq2[r]  += __shfl_xor(sq2[r], off);
    }
  }
  float mean2[4], rstd2[4];
  #pragma unroll
  for (int r = 0; r < 4; ++r) {
    mean2[r] = sum2[r] * (1.f / 128.f);
    const float var = sq2[r] * (1.f / 128.f) - mean2[r] * mean2[r];
    rstd2[r] = rsqrtf(var + 1e-5f);
  }

  if (grow0 + 3 <= 4999) {
    const int bb = grow0 / 2500, q0 = grow0 - bb * 2500;
    #pragma unroll
    for (int j = 0; j < 8; ++j) {
      const int col = 16 * j + l15;
      const float g2 = ln2_g[col], bv2 = ln2_b[col];
      float4 o;
      o.x = (z[j][0] - mean2[0]) * rstd2[0] * g2 + bv2;
      o.y = (z[j][1] - mean2[1]) * rstd2[1] * g2 + bv2;
      o.z = (z[j][2] - mean2[2]) * rstd2[2] * g2 + bv2;
      o.w = (z[j][3] - mean2[3]) * rstd2[3] * g2 + bv2;
      *(float4*)(out + ((size_t)(bb * 128 + col)) * 2500 + q0) = o;
    }
  }
}

extern "C" void kernel_launch(void* const* d_in, const int* in_sizes, int n_in,
                              void* d_out, int out_size, void* d_ws, size_t ws_size,
                              hipStream_t stream)
{
  const float* q     = (const float*)d_in[0];
  const float* k     = (const float*)d_in[1];
  const float* v     = (const float*)d_in[2];
  const float* skip  = (const float*)d_in[3];
  const float* lnq_g = (const float*)d_in[4];
  const float* lnq_b = (const float*)d_in[5];
  const float* wq    = (const float*)d_in[6];
  const float* bq    = (const float*)d_in[7];
  const float* lnk_g = (const float*)d_in[8];
  const float* lnk_b = (const float*)d_in[9];
  const float* wk    = (const float*)d_in[10];
  const float* bk    = (const float*)d_in[11];
  const float* lnv_g = (const float*)d_in[12];
  const float* lnv_b = (const float*)d_in[13];
  const float* wv    = (const float*)d_in[14];
  const float* bv    = (const float*)d_in[15];
  const float* wp    = (const float*)d_in[16];
  const float* bp    = (const float*)d_in[17];
  const float* ln1_g = (const float*)d_in[18];
  const float* ln1_b = (const float*)d_in[19];
  const float* w1    = (const float*)d_in[20];
  const float* b1    = (const float*)d_in[21];
  const float* w2    = (const float*)d_in[22];
  const float* b2    = (const float*)d_in[23];
  const float* ln2_g = (const float*)d_in[24];
  const float* ln2_b = (const float*)d_in[25];

  unsigned short* kpb = (unsigned short*)d_ws;         // 655360
  unsigned short* vtb = kpb + 655360;                  // 655360
  unsigned short* qsb = vtb + 655360;                  // 640000
  unsigned short* wpk = qsb + 640000;                  // 16384
  unsigned short* w1k = wpk + 16384;                   // 32768
  unsigned short* w2k = w1k + 32768;                   // 32768
  unsigned short* wqk = w2k + 32768;                   // 16384
  unsigned short* wkk = wqk + 16384;                   // 16384
  unsigned short* wvk = wkk + 16384;                   // 16384
  float* pl   = (float*)(wvk + 16384);                 // 2*4*8*2500 = 160000
  float* pacc = pl + 160000;                           // *32 = 5120000
  float* a    = pacc + 5120000;                        // 640000

  prepack_kernel<<<dim3(512), dim3(256), 0, stream>>>(wp, w1, w2, wq, wk, wv,
                                                      wpk, w1k, w2k, wqk, wkk, wvk);
  proj_kv_mfma<<<dim3(160), dim3(256), 0, stream>>>(
      k, v, lnk_g, lnk_b, wkk, bk, lnv_g, lnv_b, wvk, bv, kpb, vtb);
  proj_q_mfma<<<dim3(79), dim3(256), 0, stream>>>(q, lnq_g, lnq_b, wqk, bq, qsb);
  attn_kernel<<<dim3(2560), dim3(256), 0, stream>>>(qsb, kpb, vtb, pl, pacc);
  combine_kernel<<<dim3(2500), dim3(256), 0, stream>>>(pl, pacc, a);
  tail_mfma_kernel<<<dim3(79), dim3(256), 0, stream>>>(
      a, skip, wpk, bp, ln1_g, ln1_b, w1k, b1, w2k, b2, ln2_g, ln2_b, (float*)d_out);
}

// Round 6
// 107.413 us; speedup vs baseline: 5.1156x; 1.0532x over previous
//
#include <hip/hip_runtime.h>
#include <hip/hip_bf16.h>
#include <math.h>

#define B_  2
#define N_  6
#define D_  128
#define Q_  2500
#define HK  420
#define NK  2520
#define NKP 2560      // padded keys (40 zero-pads, all in split 3)
#define M_  4
#define DH  32
#define SPLIT 4
#define KPSP 640      // NKP/SPLIT
#define CHUNKS 20     // KPSP/32
#define QT_TILES 157  // ceil(2500/16)
#define SCALE 0.17677669529663687f

typedef __attribute__((ext_vector_type(8))) short short8v;
typedef __attribute__((ext_vector_type(4))) float f32x4;

__device__ __forceinline__ unsigned short f2b(float x) {
  unsigned u = __float_as_uint(x);
  return (unsigned short)((u + 0x7FFFu + ((u >> 16) & 1u)) >> 16);
}

__device__ __forceinline__ unsigned pk2(float lo, float hi) {
  return (unsigned)f2b(lo) | ((unsigned)f2b(hi) << 16);
}

// ---------------- Kernel 1: prepack weights to MFMA B-frag order + zero pad keys ----------------
// frag idx = ((c*JT + j)*64 + lane)*8 + e ; element = W[32c + 8*(lane>>4) + e][16j + (lane&15)]
__global__ __launch_bounds__(256)
void setup_kernel(const float* __restrict__ wp, const float* __restrict__ w1,
                  const float* __restrict__ w2, const float* __restrict__ wq,
                  const float* __restrict__ wk, const float* __restrict__ wv,
                  unsigned short* __restrict__ wpk, unsigned short* __restrict__ w1k,
                  unsigned short* __restrict__ w2k, unsigned short* __restrict__ wqk,
                  unsigned short* __restrict__ wkk, unsigned short* __restrict__ wvk,
                  unsigned short* __restrict__ kpb, unsigned short* __restrict__ vtb)
{
  if (blockIdx.x < 128) {
    const int base = blockIdx.x * 1024 + threadIdx.x * 4;
    #pragma unroll
    for (int i = 0; i < 4; ++i) {
      const int tid = base + i;                       // < 131072
      if (tid < 16384) {                              // wp: [128][128]
        const int e = tid & 7, l = (tid >> 3) & 63, j = (tid >> 9) & 7, c = tid >> 12;
        wpk[tid] = f2b(wp[(32*c + 8*(l>>4) + e) * 128 + 16*j + (l & 15)]);
      } else if (tid < 49152) {                       // w1: [128][256]
        const int t2 = tid - 16384;
        const int e = t2 & 7, l = (t2 >> 3) & 63, j = (t2 >> 9) & 15, c = t2 >> 13;
        w1k[t2] = f2b(w1[(32*c + 8*(l>>4) + e) * 256 + 16*j + (l & 15)]);
      } else if (tid < 81920) {                       // w2: [256][128]
        const int t2 = tid - 49152;
        const int e = t2 & 7, l = (t2 >> 3) & 63, j = (t2 >> 9) & 7, c = t2 >> 12;
        w2k[t2] = f2b(w2[(32*c + 8*(l>>4) + e) * 128 + 16*j + (l & 15)]);
      } else {                                        // wq/wk/wv: [128][128]
        const int t2 = (tid - 81920) & 16383;
        const int which = (tid - 81920) >> 14;
        const float* src = which == 0 ? wq : which == 1 ? wk : wv;
        unsigned short* dst = which == 0 ? wqk : which == 1 ? wkk : wvk;
        const int e = t2 & 7, l = (t2 >> 3) & 63, j = (t2 >> 9) & 7, c = t2 >> 12;
        dst[t2] = f2b(src[(32*c + 8*(l>>4) + e) * 128 + 16*j + (l & 15)]);
      }
    }
  } else {                                            // zero 40 pad keys of kpb and vtb
    const int base = (blockIdx.x - 128) * 256 + threadIdx.x;   // 0..511
    for (int i = base; i < 10240; i += 512) {
      const int bm = i / 1280, rem = i % 1280;
      kpb[((size_t)bm * NKP + 2520 + rem / 32) * DH + (rem & 31)] = 0;
      vtb[((size_t)(i / 40)) * NKP + 2520 + (i % 40)] = 0;
    }
  }
}

// ---------------- Kernel 2: fused MFMA LN+project for K, V and Q ----------------
// One wave per 16-row tile. No LDS, no __syncthreads.
__global__ __launch_bounds__(256)
void proj_kernel(const float* __restrict__ kin, const float* __restrict__ vin,
                 const float* __restrict__ lnk_g, const float* __restrict__ lnk_b,
                 const unsigned short* __restrict__ wkk, const float* __restrict__ bk,
                 const float* __restrict__ lnv_g, const float* __restrict__ lnv_b,
                 const unsigned short* __restrict__ wvk, const float* __restrict__ bv,
                 unsigned short* __restrict__ kpb, unsigned short* __restrict__ vtb,
                 const float* __restrict__ qin,
                 const float* __restrict__ lnq_g, const float* __restrict__ lnq_b,
                 const unsigned short* __restrict__ wqk, const float* __restrict__ bq,
                 unsigned short* __restrict__ qsb)
{
  const int wid = threadIdx.x >> 6, lane = threadIdx.x & 63;
  const int l15 = lane & 15, g = lane >> 4;

  if (blockIdx.x < 158) {
    // ---------------- K/V projection ----------------
    const int T = blockIdx.x * 4 + wid;
    if (T >= 630) return;
    const int ph = T >= 315 ? 1 : 0;
    const int t = ph ? T - 315 : T;

    const float* in = ph ? vin : kin;
    const float* gg = ph ? lnv_g : lnk_g;
    const float* bb = ph ? lnv_b : lnk_b;
    const unsigned short* wf = ph ? wvk : wkk;
    const float* bs = ph ? bv : bk;

    const int myrow = 16 * t + l15;                 // global key idx 0..5039
    const int cam = myrow / HK, kk = myrow - cam * HK;

    float x[4][8];
    float s = 0.f, s2 = 0.f;
    #pragma unroll
    for (int c = 0; c < 4; ++c)
      #pragma unroll
      for (int e = 0; e < 8; ++e) {
        const float xv = in[((size_t)(cam * D_ + 32 * c + 8 * g + e)) * HK + kk];
        x[c][e] = xv; s += xv; s2 += xv * xv;
      }
    s  += __shfl_xor(s, 16);  s2 += __shfl_xor(s2, 16);
    s  += __shfl_xor(s, 32);  s2 += __shfl_xor(s2, 32);
    const float mean = s * (1.f / 128.f);
    const float rstd = rsqrtf(s2 * (1.f / 128.f) - mean * mean + 1e-5f);

    short8v aA[4];
    #pragma unroll
    for (int c = 0; c < 4; ++c)
      #pragma unroll
      for (int e = 0; e < 8; ++e) {
        const int col = 32 * c + 8 * g + e;
        aA[c][e] = (short)f2b((x[c][e] - mean) * rstd * gg[col] + bb[col]);
      }

    f32x4 z[8];
    #pragma unroll
    for (int j = 0; j < 8; ++j) {
      f32x4 d = {0.f, 0.f, 0.f, 0.f};
      #pragma unroll
      for (int c = 0; c < 4; ++c) {
        const short8v w8 = *(const short8v*)(wf + (((c * 8 + j) * 64 + lane) << 3));
        d = __builtin_amdgcn_mfma_f32_16x16x32_bf16(aA[c], w8, d, 0, 0, 0);
      }
      z[j] = d;
    }

    const int key0 = 16 * t + 4 * g;                // D rows: key0 + r
    #pragma unroll
    for (int j = 0; j < 8; ++j) {
      const int col = 16 * j + l15;
      const float bsv = bs[col];
      if (ph == 0) {
        const int m = col >> 5, dh = col & 31;
        #pragma unroll
        for (int r = 0; r < 4; ++r) {
          const int key = key0 + r;
          const int bbx = key / NK, kb = key - bbx * NK;
          kpb[((size_t)(bbx * M_ + m) * NKP + kb) * DH + dh] = f2b(z[j][r] + bsv);
        }
      } else {
        #pragma unroll
        for (int r = 0; r < 4; ++r) {
          const int key = key0 + r;
          const int bbx = key / NK, kb = key - bbx * NK;
          vtb[((size_t)(bbx * 128 + col)) * NKP + kb] = f2b(z[j][r] + bsv);
        }
      }
    }
  } else {
    // ---------------- Q projection: LN(q0)+LN(q1), project, pre-scale ----------------
    const int t = (blockIdx.x - 158) * 4 + wid;
    if (t >= 313) return;
    int myrow = 16 * t + l15; if (myrow > 4999) myrow = 4999;
    const int b = myrow / Q_, qpos = myrow - b * Q_;

    float xs[4][8];
    #pragma unroll
    for (int c = 0; c < 4; ++c)
      #pragma unroll
      for (int e = 0; e < 8; ++e) xs[c][e] = 0.f;

    #pragma unroll
    for (int n = 0; n < 2; ++n) {
      float x[4][8];
      float s = 0.f, s2 = 0.f;
      #pragma unroll
      for (int c = 0; c < 4; ++c)
        #pragma unroll
        for (int e = 0; e < 8; ++e) {
          const float xv = qin[((size_t)((b * N_ + n) * D_ + 32 * c + 8 * g + e)) * Q_ + qpos];
          x[c][e] = xv; s += xv; s2 += xv * xv;
        }
      s  += __shfl_xor(s, 16);  s2 += __shfl_xor(s2, 16);
      s  += __shfl_xor(s, 32);  s2 += __shfl_xor(s2, 32);
      const float mean = s * (1.f / 128.f);
      const float rstd = rsqrtf(s2 * (1.f / 128.f) - mean * mean + 1e-5f);
      #pragma unroll
      for (int c = 0; c < 4; ++c)
        #pragma unroll
        for (int e = 0; e < 8; ++e) xs[c][e] += (x[c][e] - mean) * rstd;
    }

    short8v aA[4];
    #pragma unroll
    for (int c = 0; c < 4; ++c) {
      #pragma unroll
      for (int e = 0; e < 8; ++e) {
        const int col = 32 * c + 8 * g + e;
        aA[c][e] = (short)f2b(SCALE * (xs[c][e] * lnq_g[col] + 2.f * lnq_b[col]));
      }
    }

    f32x4 z[8];
    #pragma unroll
    for (int j = 0; j < 8; ++j) {
      f32x4 d = {0.f, 0.f, 0.f, 0.f};
      #pragma unroll
      for (int c = 0; c < 4; ++c) {
        const short8v w8 = *(const short8v*)(wqk + (((c * 8 + j) * 64 + lane) << 3));
        d = __builtin_amdgcn_mfma_f32_16x16x32_bf16(aA[c], w8, d, 0, 0, 0);
      }
      z[j] = d;
    }

    const int row0 = 16 * t + 4 * g;
    #pragma unroll
    for (int j = 0; j < 8; ++j) {
      const int col = 16 * j + l15;
      const float bsv = 2.f * SCALE * bq[col];
      #pragma unroll
      for (int r = 0; r < 4; ++r) {
        const int row = row0 + r;
        if (row < 5000) qsb[((size_t)row) * 128 + col] = f2b(z[j][r] + bsv);
      }
    }
  }
}

// ---------------- Kernel 3: MFMA flash attention (split-K partials) ----------------
// Staggered key-loop start (decorrelate L2 streams) + depth-2 prefetch.
__global__ __launch_bounds__(256)
void attn_kernel(const unsigned short* __restrict__ qsb,
                 const unsigned short* __restrict__ kpb,
                 const unsigned short* __restrict__ vtb,
                 float* __restrict__ pl, float* __restrict__ pacc)
{
  __shared__ __align__(16) char plds_all[4][16 * 80];
  const int wid  = threadIdx.x >> 6;
  const int lane = threadIdx.x & 63;
  const int bi = blockIdx.x;
  const int sp = bi & 3;
  const int tmp = bi >> 2;
  const int qt4 = tmp % 40;
  const int bm = tmp / 40;               // b*4+m
  const int qt = qt4 * 4 + wid;
  if (qt >= QT_TILES) return;

  const int q16 = lane & 15, g = lane >> 4;
  const int q = qt * 16 + q16;
  const int qc = q < Q_ ? q : Q_ - 1;
  const int b = bm >> 2;
  char* plds = plds_all[wid];

  const short8v qf = *(const short8v*)(qsb + ((size_t)(b * Q_ + qc)) * 128 + (bm & 3) * DH + g * 8);

  const unsigned short* kbase = kpb + ((size_t)bm * NKP + sp * KPSP) * DH + q16 * DH + g * 8;
  const unsigned short* vbase = vtb + ((size_t)(bm * DH + q16)) * NKP + sp * KPSP + g * 8;

  f32x4 o0 = {0.f, 0.f, 0.f, 0.f}, o1 = {0.f, 0.f, 0.f, 0.f};
  float l = 0.f;

  const int c0 = qt % CHUNKS;
  int c1 = c0 + 1; if (c1 >= CHUNKS) c1 -= CHUNKS;
  int cn = c0 + 2; if (cn >= CHUNKS) cn -= CHUNKS;

  short8v kA1 = *(const short8v*)(kbase + c0 * 1024);
  short8v kA2 = *(const short8v*)(kbase + c0 * 1024 + 512);
  short8v vA1 = *(const short8v*)(vbase + c0 * 32);
  short8v vA2 = *(const short8v*)(vbase + c0 * 32 + 16 * NKP);
  short8v kB1 = *(const short8v*)(kbase + c1 * 1024);
  short8v kB2 = *(const short8v*)(kbase + c1 * 1024 + 512);
  short8v vB1 = *(const short8v*)(vbase + c1 * 32);
  short8v vB2 = *(const short8v*)(vbase + c1 * 32 + 16 * NKP);

  auto step = [&](short8v& K1r, short8v& K2r, short8v& V1r, short8v& V2r, int cnx) {
    f32x4 s0 = __builtin_amdgcn_mfma_f32_16x16x32_bf16(K1r, qf, (f32x4){0.f,0.f,0.f,0.f}, 0, 0, 0);
    f32x4 s1 = __builtin_amdgcn_mfma_f32_16x16x32_bf16(K2r, qf, (f32x4){0.f,0.f,0.f,0.f}, 0, 0, 0);

    float p[8];
    #pragma unroll
    for (int r = 0; r < 4; ++r) { p[r] = __expf(s0[r]); p[4 + r] = __expf(s1[r]); }
    #pragma unroll
    for (int i = 0; i < 8; ++i) l += p[i];

    uint2 w1v, w2v;
    w1v.x = pk2(p[0], p[1]); w1v.y = pk2(p[2], p[3]);
    w2v.x = pk2(p[4], p[5]); w2v.y = pk2(p[6], p[7]);
    *(uint2*)(plds + q16 * 80 + g * 8)      = w1v;
    *(uint2*)(plds + q16 * 80 + 32 + g * 8) = w2v;
    const short8v pb = *(const short8v*)(plds + q16 * 80 + g * 16);

    o0 = __builtin_amdgcn_mfma_f32_16x16x32_bf16(V1r, pb, o0, 0, 0, 0);
    o1 = __builtin_amdgcn_mfma_f32_16x16x32_bf16(V2r, pb, o1, 0, 0, 0);

    K1r = *(const short8v*)(kbase + cnx * 1024);
    K2r = *(const short8v*)(kbase + cnx * 1024 + 512);
    V1r = *(const short8v*)(vbase + cnx * 32);
    V2r = *(const short8v*)(vbase + cnx * 32 + 16 * NKP);
  };

  #pragma unroll 1
  for (int it = 0; it < CHUNKS / 2; ++it) {
    step(kA1, kA2, vA1, vA2, cn);
    cn = cn + 1 >= CHUNKS ? cn + 1 - CHUNKS : cn + 1;
    step(kB1, kB2, vB1, vB2, cn);
    cn = cn + 1 >= CHUNKS ? cn + 1 - CHUNKS : cn + 1;
  }

  l += __shfl_xor(l, 16);
  l += __shfl_xor(l, 32);

  if (q < Q_) {
    const size_t row = (size_t)(bm * SPLIT + sp) * Q_ + q;
    if (lane < 16) pl[row] = l;
    *(f32x4*)(pacc + row * DH + 4 * g)      = o0;
    *(f32x4*)(pacc + row * DH + 16 + 4 * g) = o1;
  }
}

// ---------------- Kernel 4: fused combine + MFMA tail ----------------
__global__ __launch_bounds__(256)
void tail_kernel(const float* __restrict__ pl, const float* __restrict__ pacc,
                 const float* __restrict__ skip,
                 const unsigned short* __restrict__ wpk, const float* __restrict__ bp,
                 const float* __restrict__ ln1_g, const float* __restrict__ ln1_b,
                 const unsigned short* __restrict__ w1k, const float* __restrict__ b1,
                 const unsigned short* __restrict__ w2k, const float* __restrict__ b2,
                 const float* __restrict__ ln2_g, const float* __restrict__ ln2_b,
                 float* __restrict__ out)
{
  __shared__ __align__(16) unsigned short zlds[4][16][136];
  __shared__ __align__(16) unsigned short hlds[4][16][264];
  const int wid = threadIdx.x >> 6, lane = threadIdx.x & 63;
  const int tile = blockIdx.x * 4 + wid;
  if (tile >= 313) return;
  const int row0 = tile * 16;
  const int l15 = lane & 15, g = lane >> 4;

  // ---- combine split-K partials directly into A-frags
  short8v aA[4];
  {
    int arow = row0 + l15; if (arow > 4999) arow = 4999;
    const int bb = arow / Q_, qq = arow - bb * Q_;
    #pragma unroll
    for (int c = 0; c < 4; ++c) {            // c == head m
      float ls = -40.0f;                     // exact correction for 40 zero-pad keys
      float4 a0 = {0,0,0,0}, a1 = {0,0,0,0};
      #pragma unroll
      for (int sp = 0; sp < SPLIT; ++sp) {
        const size_t row = (size_t)((bb * 4 + c) * SPLIT + sp) * Q_ + qq;
        ls += pl[row];
        const float4 t0 = *(const float4*)(pacc + row * DH + 8 * g);
        const float4 t1 = *(const float4*)(pacc + row * DH + 8 * g + 4);
        a0.x += t0.x; a0.y += t0.y; a0.z += t0.z; a0.w += t0.w;
        a1.x += t1.x; a1.y += t1.y; a1.z += t1.z; a1.w += t1.w;
      }
      const float inv = 1.f / ls;
      aA[c][0] = (short)f2b(a0.x * inv); aA[c][1] = (short)f2b(a0.y * inv);
      aA[c][2] = (short)f2b(a0.z * inv); aA[c][3] = (short)f2b(a0.w * inv);
      aA[c][4] = (short)f2b(a1.x * inv); aA[c][5] = (short)f2b(a1.y * inv);
      aA[c][6] = (short)f2b(a1.z * inv); aA[c][7] = (short)f2b(a1.w * inv);
    }
  }

  // ---- GEMM1: z = a @ wp
  f32x4 z[8];
  #pragma unroll
  for (int j = 0; j < 8; ++j) {
    f32x4 d = {0.f, 0.f, 0.f, 0.f};
    #pragma unroll
    for (int c = 0; c < 4; ++c) {
      const short8v wf = *(const short8v*)(wpk + (((c * 8 + j) * 64 + lane) << 3));
      d = __builtin_amdgcn_mfma_f32_16x16x32_bf16(aA[c], wf, d, 0, 0, 0);
    }
    z[j] = d;
  }

  const int grow0 = row0 + 4 * g;
  float sum[4] = {0,0,0,0}, sq[4] = {0,0,0,0};
  #pragma unroll
  for (int j = 0; j < 8; ++j) {
    const int col = 16 * j + l15;
    const float bpv = bp[col];
    #pragma unroll
    for (int r = 0; r < 4; ++r) {
      int rr = grow0 + r; if (rr > 4999) rr = 4999;
      const int bb = rr / 2500, q = rr - bb * 2500;
      const float val = z[j][r] + bpv + skip[((size_t)(bb * 128 + col)) * 2500 + q];
      z[j][r] = val;
      sum[r] += val; sq[r] += val * val;
    }
  }
  #pragma unroll
  for (int r = 0; r < 4; ++r) {
    #pragma unroll
    for (int off = 1; off < 16; off <<= 1) {
      sum[r] += __shfl_xor(sum[r], off);
      sq[r]  += __shfl_xor(sq[r], off);
    }
  }
  float mean[4], rstd[4];
  #pragma unroll
  for (int r = 0; r < 4; ++r) {
    mean[r] = sum[r] * (1.f / 128.f);
    const float var = sq[r] * (1.f / 128.f) - mean[r] * mean[r];
    rstd[r] = rsqrtf(var + 1e-5f);
  }
  unsigned short (*zw)[136] = zlds[wid];
  #pragma unroll
  for (int j = 0; j < 8; ++j) {
    const int col = 16 * j + l15;
    const float g1 = ln1_g[col], bv1 = ln1_b[col];
    #pragma unroll
    for (int r = 0; r < 4; ++r) {
      const float vv = (z[j][r] - mean[r]) * rstd[r] * g1 + bv1;
      z[j][r] = vv;
      zw[4 * g + r][col] = f2b(vv);
    }
  }

  // ---- GEMM2: h = gelu(z_ln @ w1 + b1)
  short8v zA[4];
  #pragma unroll
  for (int c = 0; c < 4; ++c)
    zA[c] = *(const short8v*)&zw[l15][32 * c + 8 * g];
  unsigned short (*hw)[264] = hlds[wid];
  #pragma unroll
  for (int j = 0; j < 16; ++j) {
    f32x4 d = {0.f, 0.f, 0.f, 0.f};
    #pragma unroll
    for (int c = 0; c < 4; ++c) {
      const short8v wf = *(const short8v*)(w1k + (((c * 16 + j) * 64 + lane) << 3));
      d = __builtin_amdgcn_mfma_f32_16x16x32_bf16(zA[c], wf, d, 0, 0, 0);
    }
    const int col = 16 * j + l15;
    const float bv = b1[col];
    #pragma unroll
    for (int r = 0; r < 4; ++r) {
      const float x = d[r] + bv;
      hw[4 * g + r][col] = f2b(0.5f * x * (1.f + erff(x * 0.70710678118654752f)));
    }
  }

  // ---- GEMM3: y = h @ w2 ; residual + LN2
  short8v hA[8];
  #pragma unroll
  for (int c = 0; c < 8; ++c)
    hA[c] = *(const short8v*)&hw[l15][32 * c + 8 * g];
  float sum2[4] = {0,0,0,0}, sq2[4] = {0,0,0,0};
  #pragma unroll
  for (int j = 0; j < 8; ++j) {
    f32x4 d = {0.f, 0.f, 0.f, 0.f};
    #pragma unroll
    for (int c = 0; c < 8; ++c) {
      const short8v wf = *(const short8v*)(w2k + (((c * 8 + j) * 64 + lane) << 3));
      d = __builtin_amdgcn_mfma_f32_16x16x32_bf16(hA[c], wf, d, 0, 0, 0);
    }
    const int col = 16 * j + l15;
    const float bv = b2[col];
    #pragma unroll
    for (int r = 0; r < 4; ++r) {
      const float vv = z[j][r] + d[r] + bv;
      z[j][r] = vv;
      sum2[r] += vv; sq2[r] += vv * vv;
    }
  }
  #pragma unroll
  for (int r = 0; r < 4; ++r) {
    #pragma unroll
    for (int off = 1; off < 16; off <<= 1) {
      sum2[r] += __shfl_xor(sum2[r], off);
      sq2[r]  += __shfl_xor(sq2[r], off);
    }
  }
  float mean2[4], rstd2[4];
  #pragma unroll
  for (int r = 0; r < 4; ++r) {
    mean2[r] = sum2[r] * (1.f / 128.f);
    const float var = sq2[r] * (1.f / 128.f) - mean2[r] * mean2[r];
    rstd2[r] = rsqrtf(var + 1e-5f);
  }

  if (grow0 + 3 <= 4999) {
    const int bb = grow0 / 2500, q0 = grow0 - bb * 2500;
    #pragma unroll
    for (int j = 0; j < 8; ++j) {
      const int col = 16 * j + l15;
      const float g2 = ln2_g[col], bv2 = ln2_b[col];
      float4 o;
      o.x = (z[j][0] - mean2[0]) * rstd2[0] * g2 + bv2;
      o.y = (z[j][1] - mean2[1]) * rstd2[1] * g2 + bv2;
      o.z = (z[j][2] - mean2[2]) * rstd2[2] * g2 + bv2;
      o.w = (z[j][3] - mean2[3]) * rstd2[3] * g2 + bv2;
      *(float4*)(out + ((size_t)(bb * 128 + col)) * 2500 + q0) = o;
    }
  }
}

extern "C" void kernel_launch(void* const* d_in, const int* in_sizes, int n_in,
                              void* d_out, int out_size, void* d_ws, size_t ws_size,
                              hipStream_t stream)
{
  const float* q     = (const float*)d_in[0];
  const float* k     = (const float*)d_in[1];
  const float* v     = (const float*)d_in[2];
  const float* skip  = (const float*)d_in[3];
  const float* lnq_g = (const float*)d_in[4];
  const float* lnq_b = (const float*)d_in[5];
  const float* wq    = (const float*)d_in[6];
  const float* bq    = (const float*)d_in[7];
  const float* lnk_g = (const float*)d_in[8];
  const float* lnk_b = (const float*)d_in[9];
  const float* wk    = (const float*)d_in[10];
  const float* bk    = (const float*)d_in[11];
  const float* lnv_g = (const float*)d_in[12];
  const float* lnv_b = (const float*)d_in[13];
  const float* wv    = (const float*)d_in[14];
  const float* bv    = (const float*)d_in[15];
  const float* wp    = (const float*)d_in[16];
  const float* bp    = (const float*)d_in[17];
  const float* ln1_g = (const float*)d_in[18];
  const float* ln1_b = (const float*)d_in[19];
  const float* w1    = (const float*)d_in[20];
  const float* b1    = (const float*)d_in[21];
  const float* w2    = (const float*)d_in[22];
  const float* b2    = (const float*)d_in[23];
  const float* ln2_g = (const float*)d_in[24];
  const float* ln2_b = (const float*)d_in[25];

  unsigned short* kpb = (unsigned short*)d_ws;         // 655360
  unsigned short* vtb = kpb + 655360;                  // 655360
  unsigned short* qsb = vtb + 655360;                  // 640000
  unsigned short* wpk = qsb + 640000;                  // 16384
  unsigned short* w1k = wpk + 16384;                   // 32768
  unsigned short* w2k = w1k + 32768;                   // 32768
  unsigned short* wqk = w2k + 32768;                   // 16384
  unsigned short* wkk = wqk + 16384;                   // 16384
  unsigned short* wvk = wkk + 16384;                   // 16384
  float* pl   = (float*)(wvk + 16384);                 // 8*4*2500 = 80000
  float* pacc = pl + 80000;                            // *32 = 2560000

  setup_kernel<<<dim3(130), dim3(256), 0, stream>>>(wp, w1, w2, wq, wk, wv,
                                                    wpk, w1k, w2k, wqk, wkk, wvk,
                                                    kpb, vtb);
  proj_kernel<<<dim3(237), dim3(256), 0, stream>>>(
      k, v, lnk_g, lnk_b, wkk, bk, lnv_g, lnv_b, wvk, bv, kpb, vtb,
      q, lnq_g, lnq_b, wqk, bq, qsb);
  attn_kernel<<<dim3(1280), dim3(256), 0, stream>>>(qsb, kpb, vtb, pl, pacc);
  tail_kernel<<<dim3(79), dim3(256), 0, stream>>>(
      pl, pacc, skip, wpk, bp, ln1_g, ln1_b, w1k, b1, w2k, b2, ln2_g, ln2_b, (float*)d_out);
}

// Round 7
// 75.986 us; speedup vs baseline: 7.2313x; 1.4136x over previous
//
#include <hip/hip_runtime.h>
#include <hip/hip_bf16.h>
#include <math.h>

#define B_  2
#define N_  6
#define D_  128
#define Q_  2500
#define HK  420
#define NK  2520
#define NKP 2560      // padded keys (40 zero-pads, all in split 3)
#define M_  4
#define DH  32
#define SPLIT 4
#define KPSP 640      // NKP/SPLIT
#define CHUNKS 20     // KPSP/32
#define QT_TILES 157  // ceil(2500/16)
#define SCALE 0.17677669529663687f

typedef __attribute__((ext_vector_type(8))) short short8v;
typedef __attribute__((ext_vector_type(4))) float f32x4;

__device__ __forceinline__ unsigned short f2b(float x) {
  unsigned u = __float_as_uint(x);
  return (unsigned short)((u + 0x7FFFu + ((u >> 16) & 1u)) >> 16);
}

__device__ __forceinline__ unsigned pk2(float lo, float hi) {
  return (unsigned)f2b(lo) | ((unsigned)f2b(hi) << 16);
}

// ---------------- Kernel 1: prepack weights to MFMA B-frag order + zero pad keys ----------------
// frag idx = ((c*JT + j)*64 + lane)*8 + e ; element = W[32c + 8*(lane>>4) + e][16j + (lane&15)]
__global__ __launch_bounds__(256)
void setup_kernel(const float* __restrict__ wp, const float* __restrict__ w1,
                  const float* __restrict__ w2, const float* __restrict__ wq,
                  const float* __restrict__ wk, const float* __restrict__ wv,
                  unsigned short* __restrict__ wpk, unsigned short* __restrict__ w1k,
                  unsigned short* __restrict__ w2k, unsigned short* __restrict__ wqk,
                  unsigned short* __restrict__ wkk, unsigned short* __restrict__ wvk,
                  unsigned short* __restrict__ kpb, unsigned short* __restrict__ vtb)
{
  if (blockIdx.x < 128) {
    const int base = blockIdx.x * 1024 + threadIdx.x * 4;
    #pragma unroll
    for (int i = 0; i < 4; ++i) {
      const int tid = base + i;                       // < 131072
      if (tid < 16384) {                              // wp: [128][128]
        const int e = tid & 7, l = (tid >> 3) & 63, j = (tid >> 9) & 7, c = tid >> 12;
        wpk[tid] = f2b(wp[(32*c + 8*(l>>4) + e) * 128 + 16*j + (l & 15)]);
      } else if (tid < 49152) {                       // w1: [128][256]
        const int t2 = tid - 16384;
        const int e = t2 & 7, l = (t2 >> 3) & 63, j = (t2 >> 9) & 15, c = t2 >> 13;
        w1k[t2] = f2b(w1[(32*c + 8*(l>>4) + e) * 256 + 16*j + (l & 15)]);
      } else if (tid < 81920) {                       // w2: [256][128]
        const int t2 = tid - 49152;
        const int e = t2 & 7, l = (t2 >> 3) & 63, j = (t2 >> 9) & 7, c = t2 >> 12;
        w2k[t2] = f2b(w2[(32*c + 8*(l>>4) + e) * 128 + 16*j + (l & 15)]);
      } else {                                        // wq/wk/wv: [128][128]
        const int t2 = (tid - 81920) & 16383;
        const int which = (tid - 81920) >> 14;
        const float* src = which == 0 ? wq : which == 1 ? wk : wv;
        unsigned short* dst = which == 0 ? wqk : which == 1 ? wkk : wvk;
        const int e = t2 & 7, l = (t2 >> 3) & 63, j = (t2 >> 9) & 7, c = t2 >> 12;
        dst[t2] = f2b(src[(32*c + 8*(l>>4) + e) * 128 + 16*j + (l & 15)]);
      }
    }
  } else {                                            // zero 40 pad keys of kpb and vtb
    const int base = (blockIdx.x - 128) * 256 + threadIdx.x;   // 0..511
    for (int i = base; i < 10240; i += 512) {
      const int bm = i / 1280, rem = i % 1280;
      kpb[((size_t)bm * NKP + 2520 + rem / 32) * DH + (rem & 31)] = 0;
      vtb[((size_t)(i / 40)) * NKP + 2520 + (i % 40)] = 0;
    }
  }
}

// ---------------- Kernel 2: fused MFMA LN+project for K, V and Q ----------------
__global__ __launch_bounds__(256)
void proj_kernel(const float* __restrict__ kin, const float* __restrict__ vin,
                 const float* __restrict__ lnk_g, const float* __restrict__ lnk_b,
                 const unsigned short* __restrict__ wkk, const float* __restrict__ bk,
                 const float* __restrict__ lnv_g, const float* __restrict__ lnv_b,
                 const unsigned short* __restrict__ wvk, const float* __restrict__ bv,
                 unsigned short* __restrict__ kpb, unsigned short* __restrict__ vtb,
                 const float* __restrict__ qin,
                 const float* __restrict__ lnq_g, const float* __restrict__ lnq_b,
                 const unsigned short* __restrict__ wqk, const float* __restrict__ bq,
                 unsigned short* __restrict__ qsb)
{
  const int wid = threadIdx.x >> 6, lane = threadIdx.x & 63;
  const int l15 = lane & 15, g = lane >> 4;

  if (blockIdx.x < 158) {
    const int T = blockIdx.x * 4 + wid;
    if (T >= 630) return;
    const int ph = T >= 315 ? 1 : 0;
    const int t = ph ? T - 315 : T;

    const float* in = ph ? vin : kin;
    const float* gg = ph ? lnv_g : lnk_g;
    const float* bb = ph ? lnv_b : lnk_b;
    const unsigned short* wf = ph ? wvk : wkk;
    const float* bs = ph ? bv : bk;

    const int myrow = 16 * t + l15;
    const int cam = myrow / HK, kk = myrow - cam * HK;

    float x[4][8];
    float s = 0.f, s2 = 0.f;
    #pragma unroll
    for (int c = 0; c < 4; ++c)
      #pragma unroll
      for (int e = 0; e < 8; ++e) {
        const float xv = in[((size_t)(cam * D_ + 32 * c + 8 * g + e)) * HK + kk];
        x[c][e] = xv; s += xv; s2 += xv * xv;
      }
    s  += __shfl_xor(s, 16);  s2 += __shfl_xor(s2, 16);
    s  += __shfl_xor(s, 32);  s2 += __shfl_xor(s2, 32);
    const float mean = s * (1.f / 128.f);
    const float rstd = rsqrtf(s2 * (1.f / 128.f) - mean * mean + 1e-5f);

    short8v aA[4];
    #pragma unroll
    for (int c = 0; c < 4; ++c)
      #pragma unroll
      for (int e = 0; e < 8; ++e) {
        const int col = 32 * c + 8 * g + e;
        aA[c][e] = (short)f2b((x[c][e] - mean) * rstd * gg[col] + bb[col]);
      }

    f32x4 z[8];
    #pragma unroll
    for (int j = 0; j < 8; ++j) {
      f32x4 d = {0.f, 0.f, 0.f, 0.f};
      #pragma unroll
      for (int c = 0; c < 4; ++c) {
        const short8v w8 = *(const short8v*)(wf + (((c * 8 + j) * 64 + lane) << 3));
        d = __builtin_amdgcn_mfma_f32_16x16x32_bf16(aA[c], w8, d, 0, 0, 0);
      }
      z[j] = d;
    }

    const int key0 = 16 * t + 4 * g;
    #pragma unroll
    for (int j = 0; j < 8; ++j) {
      const int col = 16 * j + l15;
      const float bsv = bs[col];
      if (ph == 0) {
        const int m = col >> 5, dh = col & 31;
        #pragma unroll
        for (int r = 0; r < 4; ++r) {
          const int key = key0 + r;
          const int bbx = key / NK, kb = key - bbx * NK;
          kpb[((size_t)(bbx * M_ + m) * NKP + kb) * DH + dh] = f2b(z[j][r] + bsv);
        }
      } else {
        #pragma unroll
        for (int r = 0; r < 4; ++r) {
          const int key = key0 + r;
          const int bbx = key / NK, kb = key - bbx * NK;
          vtb[((size_t)(bbx * 128 + col)) * NKP + kb] = f2b(z[j][r] + bsv);
        }
      }
    }
  } else {
    const int t = (blockIdx.x - 158) * 4 + wid;
    if (t >= 313) return;
    int myrow = 16 * t + l15; if (myrow > 4999) myrow = 4999;
    const int b = myrow / Q_, qpos = myrow - b * Q_;

    float xs[4][8];
    #pragma unroll
    for (int c = 0; c < 4; ++c)
      #pragma unroll
      for (int e = 0; e < 8; ++e) xs[c][e] = 0.f;

    #pragma unroll
    for (int n = 0; n < 2; ++n) {
      float x[4][8];
      float s = 0.f, s2 = 0.f;
      #pragma unroll
      for (int c = 0; c < 4; ++c)
        #pragma unroll
        for (int e = 0; e < 8; ++e) {
          const float xv = qin[((size_t)((b * N_ + n) * D_ + 32 * c + 8 * g + e)) * Q_ + qpos];
          x[c][e] = xv; s += xv; s2 += xv * xv;
        }
      s  += __shfl_xor(s, 16);  s2 += __shfl_xor(s2, 16);
      s  += __shfl_xor(s, 32);  s2 += __shfl_xor(s2, 32);
      const float mean = s * (1.f / 128.f);
      const float rstd = rsqrtf(s2 * (1.f / 128.f) - mean * mean + 1e-5f);
      #pragma unroll
      for (int c = 0; c < 4; ++c)
        #pragma unroll
        for (int e = 0; e < 8; ++e) xs[c][e] += (x[c][e] - mean) * rstd;
    }

    short8v aA[4];
    #pragma unroll
    for (int c = 0; c < 4; ++c) {
      #pragma unroll
      for (int e = 0; e < 8; ++e) {
        const int col = 32 * c + 8 * g + e;
        aA[c][e] = (short)f2b(SCALE * (xs[c][e] * lnq_g[col] + 2.f * lnq_b[col]));
      }
    }

    f32x4 z[8];
    #pragma unroll
    for (int j = 0; j < 8; ++j) {
      f32x4 d = {0.f, 0.f, 0.f, 0.f};
      #pragma unroll
      for (int c = 0; c < 4; ++c) {
        const short8v w8 = *(const short8v*)(wqk + (((c * 8 + j) * 64 + lane) << 3));
        d = __builtin_amdgcn_mfma_f32_16x16x32_bf16(aA[c], w8, d, 0, 0, 0);
      }
      z[j] = d;
    }

    const int row0 = 16 * t + 4 * g;
    #pragma unroll
    for (int j = 0; j < 8; ++j) {
      const int col = 16 * j + l15;
      const float bsv = 2.f * SCALE * bq[col];
      #pragma unroll
      for (int r = 0; r < 4; ++r) {
        const int row = row0 + r;
        if (row < 5000) qsb[((size_t)row) * 128 + col] = f2b(z[j][r] + bsv);
      }
    }
  }
}

// ---------------- Kernel 3: MFMA flash attention (split-K partials) ----------------
__global__ __launch_bounds__(256)
void attn_kernel(const unsigned short* __restrict__ qsb,
                 const unsigned short* __restrict__ kpb,
                 const unsigned short* __restrict__ vtb,
                 float* __restrict__ pl, float* __restrict__ pacc)
{
  __shared__ __align__(16) char plds_all[4][16 * 80];
  const int wid  = threadIdx.x >> 6;
  const int lane = threadIdx.x & 63;
  const int bi = blockIdx.x;
  const int sp = bi & 3;
  const int tmp = bi >> 2;
  const int qt4 = tmp % 40;
  const int bm = tmp / 40;               // b*4+m
  const int qt = qt4 * 4 + wid;
  if (qt >= QT_TILES) return;

  const int q16 = lane & 15, g = lane >> 4;
  const int q = qt * 16 + q16;
  const int qc = q < Q_ ? q : Q_ - 1;
  const int b = bm >> 2;
  char* plds = plds_all[wid];

  const short8v qf = *(const short8v*)(qsb + ((size_t)(b * Q_ + qc)) * 128 + (bm & 3) * DH + g * 8);

  const unsigned short* kbase = kpb + ((size_t)bm * NKP + sp * KPSP) * DH + q16 * DH + g * 8;
  const unsigned short* vbase = vtb + ((size_t)(bm * DH + q16)) * NKP + sp * KPSP + g * 8;

  f32x4 o0 = {0.f, 0.f, 0.f, 0.f}, o1 = {0.f, 0.f, 0.f, 0.f};
  float l = 0.f;

  const int c0 = qt % CHUNKS;
  int c1 = c0 + 1; if (c1 >= CHUNKS) c1 -= CHUNKS;
  int cn = c0 + 2; if (cn >= CHUNKS) cn -= CHUNKS;

  short8v kA1 = *(const short8v*)(kbase + c0 * 1024);
  short8v kA2 = *(const short8v*)(kbase + c0 * 1024 + 512);
  short8v vA1 = *(const short8v*)(vbase + c0 * 32);
  short8v vA2 = *(const short8v*)(vbase + c0 * 32 + 16 * NKP);
  short8v kB1 = *(const short8v*)(kbase + c1 * 1024);
  short8v kB2 = *(const short8v*)(kbase + c1 * 1024 + 512);
  short8v vB1 = *(const short8v*)(vbase + c1 * 32);
  short8v vB2 = *(const short8v*)(vbase + c1 * 32 + 16 * NKP);

  auto step = [&](short8v& K1r, short8v& K2r, short8v& V1r, short8v& V2r, int cnx) {
    f32x4 s0 = __builtin_amdgcn_mfma_f32_16x16x32_bf16(K1r, qf, (f32x4){0.f,0.f,0.f,0.f}, 0, 0, 0);
    f32x4 s1 = __builtin_amdgcn_mfma_f32_16x16x32_bf16(K2r, qf, (f32x4){0.f,0.f,0.f,0.f}, 0, 0, 0);

    float p[8];
    #pragma unroll
    for (int r = 0; r < 4; ++r) { p[r] = __expf(s0[r]); p[4 + r] = __expf(s1[r]); }
    #pragma unroll
    for (int i = 0; i < 8; ++i) l += p[i];

    uint2 w1v, w2v;
    w1v.x = pk2(p[0], p[1]); w1v.y = pk2(p[2], p[3]);
    w2v.x = pk2(p[4], p[5]); w2v.y = pk2(p[6], p[7]);
    *(uint2*)(plds + q16 * 80 + g * 8)      = w1v;
    *(uint2*)(plds + q16 * 80 + 32 + g * 8) = w2v;
    const short8v pb = *(const short8v*)(plds + q16 * 80 + g * 16);

    o0 = __builtin_amdgcn_mfma_f32_16x16x32_bf16(V1r, pb, o0, 0, 0, 0);
    o1 = __builtin_amdgcn_mfma_f32_16x16x32_bf16(V2r, pb, o1, 0, 0, 0);

    K1r = *(const short8v*)(kbase + cnx * 1024);
    K2r = *(const short8v*)(kbase + cnx * 1024 + 512);
    V1r = *(const short8v*)(vbase + cnx * 32);
    V2r = *(const short8v*)(vbase + cnx * 32 + 16 * NKP);
  };

  #pragma unroll 1
  for (int it = 0; it < CHUNKS / 2; ++it) {
    step(kA1, kA2, vA1, vA2, cn);
    cn = cn + 1 >= CHUNKS ? cn + 1 - CHUNKS : cn + 1;
    step(kB1, kB2, vB1, vB2, cn);
    cn = cn + 1 >= CHUNKS ? cn + 1 - CHUNKS : cn + 1;
  }

  l += __shfl_xor(l, 16);
  l += __shfl_xor(l, 32);

  if (q < Q_) {
    const size_t row = (size_t)(bm * SPLIT + sp) * Q_ + q;
    if (lane < 16) pl[row] = l;
    *(f32x4*)(pacc + row * DH + 4 * g)      = o0;
    *(f32x4*)(pacc + row * DH + 16 + 4 * g) = o1;
  }
}

// ---------------- Kernel 4: fused combine + MFMA tail, 4 waves cooperate on one 16-row tile ----------------
__global__ __launch_bounds__(256)
void tail_kernel(const float* __restrict__ pl, const float* __restrict__ pacc,
                 const float* __restrict__ skip,
                 const unsigned short* __restrict__ wpk, const float* __restrict__ bp,
                 const float* __restrict__ ln1_g, const float* __restrict__ ln1_b,
                 const unsigned short* __restrict__ w1k, const float* __restrict__ b1,
                 const unsigned short* __restrict__ w2k, const float* __restrict__ b2,
                 const float* __restrict__ ln2_g, const float* __restrict__ ln2_b,
                 float* __restrict__ out)
{
  __shared__ __align__(16) unsigned short aL[16][136];
  __shared__ __align__(16) unsigned short zl[16][136];
  __shared__ __align__(16) unsigned short hl[16][264];
  __shared__ __align__(16) float stat1[4][16][2];
  __shared__ __align__(16) float stat2[4][16][2];

  const int wid = threadIdx.x >> 6, lane = threadIdx.x & 63;
  const int l15 = lane & 15, g = lane >> 4;
  const int row0 = blockIdx.x * 16;
  const int grow0 = row0 + 4 * g;

  // ---- combine: wave `wid` combines head c=wid into shared bf16 tile aL[16][128]
  {
    int arow = row0 + l15; if (arow > 4999) arow = 4999;
    const int bb = arow / Q_, qq = arow - bb * Q_;
    float ls = -40.0f;                   // exact correction for 40 zero-pad keys
    float4 a0 = {0,0,0,0}, a1 = {0,0,0,0};
    #pragma unroll
    for (int sp = 0; sp < SPLIT; ++sp) {
      const size_t row = (size_t)((bb * 4 + wid) * SPLIT + sp) * Q_ + qq;
      ls += pl[row];
      const float4 t0 = *(const float4*)(pacc + row * DH + 8 * g);
      const float4 t1 = *(const float4*)(pacc + row * DH + 8 * g + 4);
      a0.x += t0.x; a0.y += t0.y; a0.z += t0.z; a0.w += t0.w;
      a1.x += t1.x; a1.y += t1.y; a1.z += t1.z; a1.w += t1.w;
    }
    const float inv = 1.f / ls;
    uint4 w;
    w.x = pk2(a0.x * inv, a0.y * inv);
    w.y = pk2(a0.z * inv, a0.w * inv);
    w.z = pk2(a1.x * inv, a1.y * inv);
    w.w = pk2(a1.z * inv, a1.w * inv);
    *(uint4*)&aL[l15][32 * wid + 8 * g] = w;
  }
  __syncthreads();

  short8v aA[4];
  #pragma unroll
  for (int c = 0; c < 4; ++c)
    aA[c] = *(const short8v*)&aL[l15][32 * c + 8 * g];

  // ---- GEMM1: z = a @ wp ; wave handles j in {2wid, 2wid+1}
  f32x4 zres[2];
  #pragma unroll
  for (int jj = 0; jj < 2; ++jj) {
    const int j = 2 * wid + jj;
    f32x4 d = {0.f, 0.f, 0.f, 0.f};
    #pragma unroll
    for (int c = 0; c < 4; ++c) {
      const short8v wf = *(const short8v*)(wpk + (((c * 8 + j) * 64 + lane) << 3));
      d = __builtin_amdgcn_mfma_f32_16x16x32_bf16(aA[c], wf, d, 0, 0, 0);
    }
    zres[jj] = d;
  }

  // ---- + bp + skip
  #pragma unroll
  for (int jj = 0; jj < 2; ++jj) {
    const int col = 16 * (2 * wid + jj) + l15;
    const float bpv = bp[col];
    #pragma unroll
    for (int r = 0; r < 4; ++r) {
      int rr = grow0 + r; if (rr > 4999) rr = 4999;
      const int bb = rr / 2500, q = rr - bb * 2500;
      zres[jj][r] += bpv + skip[((size_t)(bb * 128 + col)) * 2500 + q];
    }
  }

  // ---- LN1 stats: wave partials over its 32 cols, then cross-wave LDS reduce
  {
    float sum[4], sq[4];
    #pragma unroll
    for (int r = 0; r < 4; ++r) {
      sum[r] = zres[0][r] + zres[1][r];
      sq[r]  = zres[0][r] * zres[0][r] + zres[1][r] * zres[1][r];
    }
    #pragma unroll
    for (int r = 0; r < 4; ++r) {
      #pragma unroll
      for (int off = 1; off < 16; off <<= 1) {
        sum[r] += __shfl_xor(sum[r], off);
        sq[r]  += __shfl_xor(sq[r], off);
      }
    }
    if (l15 == 0) {
      float4 s0 = {sum[0], sq[0], sum[1], sq[1]};
      float4 s1 = {sum[2], sq[2], sum[3], sq[3]};
      *(float4*)&stat1[wid][4 * g][0]     = s0;
      *(float4*)&stat1[wid][4 * g + 2][0] = s1;
    }
  }
  __syncthreads();

  float mean[4], rstd[4];
  #pragma unroll
  for (int r = 0; r < 4; ++r) {
    float S = 0.f, S2 = 0.f;
    #pragma unroll
    for (int w2 = 0; w2 < 4; ++w2) {
      S  += stat1[w2][4 * g + r][0];
      S2 += stat1[w2][4 * g + r][1];
    }
    mean[r] = S * (1.f / 128.f);
    rstd[r] = rsqrtf(S2 * (1.f / 128.f) - mean[r] * mean[r] + 1e-5f);
  }

  // ---- LN1 apply; keep normalized z in regs for residual; write shared zl
  #pragma unroll
  for (int jj = 0; jj < 2; ++jj) {
    const int col = 16 * (2 * wid + jj) + l15;
    const float g1 = ln1_g[col], bv1 = ln1_b[col];
    #pragma unroll
    for (int r = 0; r < 4; ++r) {
      const float vv = (zres[jj][r] - mean[r]) * rstd[r] * g1 + bv1;
      zres[jj][r] = vv;
      zl[4 * g + r][col] = f2b(vv);
    }
  }
  __syncthreads();

  // ---- GEMM2: h = gelu(z_ln @ w1 + b1) ; wave handles j in {4wid..4wid+3}
  short8v zA[4];
  #pragma unroll
  for (int c = 0; c < 4; ++c)
    zA[c] = *(const short8v*)&zl[l15][32 * c + 8 * g];
  #pragma unroll
  for (int jj = 0; jj < 4; ++jj) {
    const int j = 4 * wid + jj;
    f32x4 d = {0.f, 0.f, 0.f, 0.f};
    #pragma unroll
    for (int c = 0; c < 4; ++c) {
      const short8v wf = *(const short8v*)(w1k + (((c * 16 + j) * 64 + lane) << 3));
      d = __builtin_amdgcn_mfma_f32_16x16x32_bf16(zA[c], wf, d, 0, 0, 0);
    }
    const int col = 16 * j + l15;
    const float bv = b1[col];
    #pragma unroll
    for (int r = 0; r < 4; ++r) {
      const float x = d[r] + bv;
      hl[4 * g + r][col] = f2b(0.5f * x * (1.f + erff(x * 0.70710678118654752f)));
    }
  }
  __syncthreads();

  // ---- GEMM3: y = h @ w2 ; wave handles j in {2wid, 2wid+1}; residual
  short8v hA[8];
  #pragma unroll
  for (int c = 0; c < 8; ++c)
    hA[c] = *(const short8v*)&hl[l15][32 * c + 8 * g];
  #pragma unroll
  for (int jj = 0; jj < 2; ++jj) {
    const int j = 2 * wid + jj;
    f32x4 d = {0.f, 0.f, 0.f, 0.f};
    #pragma unroll
    for (int c = 0; c < 8; ++c) {
      const short8v wf = *(const short8v*)(w2k + (((c * 8 + j) * 64 + lane) << 3));
      d = __builtin_amdgcn_mfma_f32_16x16x32_bf16(hA[c], wf, d, 0, 0, 0);
    }
    const int col = 16 * j + l15;
    const float bv = b2[col];
    #pragma unroll
    for (int r = 0; r < 4; ++r) zres[jj][r] += d[r] + bv;
  }

  // ---- LN2 stats
  {
    float sum[4], sq[4];
    #pragma unroll
    for (int r = 0; r < 4; ++r) {
      sum[r] = zres[0][r] + zres[1][r];
      sq[r]  = zres[0][r] * zres[0][r] + zres[1][r] * zres[1][r];
    }
    #pragma unroll
    for (int r = 0; r < 4; ++r) {
      #pragma unroll
      for (int off = 1; off < 16; off <<= 1) {
        sum[r] += __shfl_xor(sum[r], off);
        sq[r]  += __shfl_xor(sq[r], off);
      }
    }
    if (l15 == 0) {
      float4 s0 = {sum[0], sq[0], sum[1], sq[1]};
      float4 s1 = {sum[2], sq[2], sum[3], sq[3]};
      *(float4*)&stat2[wid][4 * g][0]     = s0;
      *(float4*)&stat2[wid][4 * g + 2][0] = s1;
    }
  }
  __syncthreads();

  float mean2[4], rstd2[4];
  #pragma unroll
  for (int r = 0; r < 4; ++r) {
    float S = 0.f, S2 = 0.f;
    #pragma unroll
    for (int w2 = 0; w2 < 4; ++w2) {
      S  += stat2[w2][4 * g + r][0];
      S2 += stat2[w2][4 * g + r][1];
    }
    mean2[r] = S * (1.f / 128.f);
    rstd2[r] = rsqrtf(S2 * (1.f / 128.f) - mean2[r] * mean2[r] + 1e-5f);
  }

  // ---- store
  if (grow0 + 3 <= 4999) {
    const int bb = grow0 / 2500, q0 = grow0 - bb * 2500;
    #pragma unroll
    for (int jj = 0; jj < 2; ++jj) {
      const int col = 16 * (2 * wid + jj) + l15;
      const float g2 = ln2_g[col], bv2 = ln2_b[col];
      float4 o;
      o.x = (zres[jj][0] - mean2[0]) * rstd2[0] * g2 + bv2;
      o.y = (zres[jj][1] - mean2[1]) * rstd2[1] * g2 + bv2;
      o.z = (zres[jj][2] - mean2[2]) * rstd2[2] * g2 + bv2;
      o.w = (zres[jj][3] - mean2[3]) * rstd2[3] * g2 + bv2;
      *(float4*)(out + ((size_t)(bb * 128 + col)) * 2500 + q0) = o;
    }
  }
}

extern "C" void kernel_launch(void* const* d_in, const int* in_sizes, int n_in,
                              void* d_out, int out_size, void* d_ws, size_t ws_size,
                              hipStream_t stream)
{
  const float* q     = (const float*)d_in[0];
  const float* k     = (const float*)d_in[1];
  const float* v     = (const float*)d_in[2];
  const float* skip  = (const float*)d_in[3];
  const float* lnq_g = (const float*)d_in[4];
  const float* lnq_b = (const float*)d_in[5];
  const float* wq    = (const float*)d_in[6];
  const float* bq    = (const float*)d_in[7];
  const float* lnk_g = (const float*)d_in[8];
  const float* lnk_b = (const float*)d_in[9];
  const float* wk    = (const float*)d_in[10];
  const float* bk    = (const float*)d_in[11];
  const float* lnv_g = (const float*)d_in[12];
  const float* lnv_b = (const float*)d_in[13];
  const float* wv    = (const float*)d_in[14];
  const float* bv    = (const float*)d_in[15];
  const float* wp    = (const float*)d_in[16];
  const float* bp    = (const float*)d_in[17];
  const float* ln1_g = (const float*)d_in[18];
  const float* ln1_b = (const float*)d_in[19];
  const float* w1    = (const float*)d_in[20];
  const float* b1    = (const float*)d_in[21];
  const float* w2    = (const float*)d_in[22];
  const float* b2    = (const float*)d_in[23];
  const float* ln2_g = (const float*)d_in[24];
  const float* ln2_b = (const float*)d_in[25];

  unsigned short* kpb = (unsigned short*)d_ws;         // 655360
  unsigned short* vtb = kpb + 655360;                  // 655360
  unsigned short* qsb = vtb + 655360;                  // 640000
  unsigned short* wpk = qsb + 640000;                  // 16384
  unsigned short* w1k = wpk + 16384;                   // 32768
  unsigned short* w2k = w1k + 32768;                   // 32768
  unsigned short* wqk = w2k + 32768;                   // 16384
  unsigned short* wkk = wqk + 16384;                   // 16384
  unsigned short* wvk = wkk + 16384;                   // 16384
  float* pl   = (float*)(wvk + 16384);                 // 8*4*2500 = 80000
  float* pacc = pl + 80000;                            // *32 = 2560000

  setup_kernel<<<dim3(130), dim3(256), 0, stream>>>(wp, w1, w2, wq, wk, wv,
                                                    wpk, w1k, w2k, wqk, wkk, wvk,
                                                    kpb, vtb);
  proj_kernel<<<dim3(237), dim3(256), 0, stream>>>(
      k, v, lnk_g, lnk_b, wkk, bk, lnv_g, lnv_b, wvk, bv, kpb, vtb,
      q, lnq_g, lnq_b, wqk, bq, qsb);
  attn_kernel<<<dim3(1280), dim3(256), 0, stream>>>(qsb, kpb, vtb, pl, pacc);
  tail_kernel<<<dim3(313), dim3(256), 0, stream>>>(
      pl, pacc, skip, wpk, bp, ln1_g, ln1_b, w1k, b1, w2k, b2, ln2_g, ln2_b, (float*)d_out);
}

// Round 8
// 74.539 us; speedup vs baseline: 7.3716x; 1.0194x over previous
//
#include <hip/hip_runtime.h>
#include <hip/hip_bf16.h>
#include <math.h>

#define B_  2
#define N_  6
#define D_  128
#define Q_  2500
#define HK  420
#define NK  2520
#define NKP 2560      // padded keys (40 zero-pads, all in split 3)
#define M_  4
#define DH  32
#define SPLIT 4
#define KPSP 640      // NKP/SPLIT
#define CHUNKS 20     // KPSP/32
#define QT_TILES 157  // ceil(2500/16)
#define SCALE 0.17677669529663687f

typedef __attribute__((ext_vector_type(8))) short short8v;
typedef __attribute__((ext_vector_type(4))) float f32x4;

__device__ __forceinline__ unsigned short f2b(float x) {
  unsigned u = __float_as_uint(x);
  return (unsigned short)((u + 0x7FFFu + ((u >> 16) & 1u)) >> 16);
}

__device__ __forceinline__ unsigned pk2(float lo, float hi) {
  return (unsigned)f2b(lo) | ((unsigned)f2b(hi) << 16);
}

// K-chunk storage permutation: actual key a (0..31) -> buffer position p so that
// the QK^T D-layout lands P[8g+e] directly in lane (q16,g)'s PV B-frag slots.
__device__ __forceinline__ int kperm(int a) {
  const int h = a & 7;
  return ((h >= 4) ? 16 : 0) + 4 * (a >> 3) + (h & 3);
}

// ---------------- Kernel 1: prepack weights to MFMA B-frag order + zero pad chunks ----------------
// frag idx = ((c*JT + j)*64 + lane)*8 + e ; element = W[32c + 8*(lane>>4) + e][16j + (lane&15)]
__global__ __launch_bounds__(256)
void setup_kernel(const float* __restrict__ wp, const float* __restrict__ w1,
                  const float* __restrict__ w2, const float* __restrict__ wq,
                  const float* __restrict__ wk, const float* __restrict__ wv,
                  unsigned short* __restrict__ wpk, unsigned short* __restrict__ w1k,
                  unsigned short* __restrict__ w2k, unsigned short* __restrict__ wqk,
                  unsigned short* __restrict__ wkk, unsigned short* __restrict__ wvk,
                  unsigned short* __restrict__ kpb, unsigned short* __restrict__ vtb)
{
  if (blockIdx.x < 128) {
    const int base = blockIdx.x * 1024 + threadIdx.x * 4;
    #pragma unroll
    for (int i = 0; i < 4; ++i) {
      const int tid = base + i;                       // < 131072
      if (tid < 16384) {                              // wp: [128][128]
        const int e = tid & 7, l = (tid >> 3) & 63, j = (tid >> 9) & 7, c = tid >> 12;
        wpk[tid] = f2b(wp[(32*c + 8*(l>>4) + e) * 128 + 16*j + (l & 15)]);
      } else if (tid < 49152) {                       // w1: [128][256]
        const int t2 = tid - 16384;
        const int e = t2 & 7, l = (t2 >> 3) & 63, j = (t2 >> 9) & 15, c = t2 >> 13;
        w1k[t2] = f2b(w1[(32*c + 8*(l>>4) + e) * 256 + 16*j + (l & 15)]);
      } else if (tid < 81920) {                       // w2: [256][128]
        const int t2 = tid - 49152;
        const int e = t2 & 7, l = (t2 >> 3) & 63, j = (t2 >> 9) & 7, c = t2 >> 12;
        w2k[t2] = f2b(w2[(32*c + 8*(l>>4) + e) * 128 + 16*j + (l & 15)]);
      } else {                                        // wq/wk/wv: [128][128]
        const int t2 = (tid - 81920) & 16383;
        const int which = (tid - 81920) >> 14;
        const float* src = which == 0 ? wq : which == 1 ? wk : wv;
        unsigned short* dst = which == 0 ? wqk : which == 1 ? wkk : wvk;
        const int e = t2 & 7, l = (t2 >> 3) & 63, j = (t2 >> 9) & 7, c = t2 >> 12;
        dst[t2] = f2b(src[(32*c + 8*(l>>4) + e) * 128 + 16*j + (l & 15)]);
      }
    }
  } else {
    // zero kpb buffer positions 2496..2559 (chunks 78,79; proj rewrites real keys after)
    // and vtb key columns 2496..2559. 8bm*64*32 + 256*64 = 32768 elements.
    const int base = (blockIdx.x - 128) * 256 + threadIdx.x;   // 0..511
    for (int i = base; i < 16384; i += 512) {
      const int bm = i >> 11, rem = i & 2047;                  // rem = pos64*32+dh
      kpb[((size_t)bm * NKP + 2496 + (rem >> 5)) * DH + (rem & 31)] = 0;
      vtb[((size_t)(i >> 6)) * NKP + 2496 + (i & 63)] = 0;
    }
  }
}

// ---------------- Kernel 2: fused MFMA LN+project for K, V and Q ----------------
__global__ __launch_bounds__(256)
void proj_kernel(const float* __restrict__ kin, const float* __restrict__ vin,
                 const float* __restrict__ lnk_g, const float* __restrict__ lnk_b,
                 const unsigned short* __restrict__ wkk, const float* __restrict__ bk,
                 const float* __restrict__ lnv_g, const float* __restrict__ lnv_b,
                 const unsigned short* __restrict__ wvk, const float* __restrict__ bv,
                 unsigned short* __restrict__ kpb, unsigned short* __restrict__ vtb,
                 const float* __restrict__ qin,
                 const float* __restrict__ lnq_g, const float* __restrict__ lnq_b,
                 const unsigned short* __restrict__ wqk, const float* __restrict__ bq,
                 unsigned short* __restrict__ qsb)
{
  const int wid = threadIdx.x >> 6, lane = threadIdx.x & 63;
  const int l15 = lane & 15, g = lane >> 4;

  if (blockIdx.x < 158) {
    const int T = blockIdx.x * 4 + wid;
    if (T >= 630) return;
    const int ph = T >= 315 ? 1 : 0;
    const int t = ph ? T - 315 : T;

    const float* in = ph ? vin : kin;
    const float* gg = ph ? lnv_g : lnk_g;
    const float* bb = ph ? lnv_b : lnk_b;
    const unsigned short* wf = ph ? wvk : wkk;
    const float* bs = ph ? bv : bk;

    const int myrow = 16 * t + l15;
    const int cam = myrow / HK, kk = myrow - cam * HK;

    float x[4][8];
    float s = 0.f, s2 = 0.f;
    #pragma unroll
    for (int c = 0; c < 4; ++c)
      #pragma unroll
      for (int e = 0; e < 8; ++e) {
        const float xv = in[((size_t)(cam * D_ + 32 * c + 8 * g + e)) * HK + kk];
        x[c][e] = xv; s += xv; s2 += xv * xv;
      }
    s  += __shfl_xor(s, 16);  s2 += __shfl_xor(s2, 16);
    s  += __shfl_xor(s, 32);  s2 += __shfl_xor(s2, 32);
    const float mean = s * (1.f / 128.f);
    const float rstd = rsqrtf(s2 * (1.f / 128.f) - mean * mean + 1e-5f);

    short8v aA[4];
    #pragma unroll
    for (int c = 0; c < 4; ++c)
      #pragma unroll
      for (int e = 0; e < 8; ++e) {
        const int col = 32 * c + 8 * g + e;
        aA[c][e] = (short)f2b((x[c][e] - mean) * rstd * gg[col] + bb[col]);
      }

    f32x4 z[8];
    #pragma unroll
    for (int j = 0; j < 8; ++j) {
      f32x4 d = {0.f, 0.f, 0.f, 0.f};
      #pragma unroll
      for (int c = 0; c < 4; ++c) {
        const short8v w8 = *(const short8v*)(wf + (((c * 8 + j) * 64 + lane) << 3));
        d = __builtin_amdgcn_mfma_f32_16x16x32_bf16(aA[c], w8, d, 0, 0, 0);
      }
      z[j] = d;
    }

    const int key0 = 16 * t + 4 * g;
    #pragma unroll
    for (int j = 0; j < 8; ++j) {
      const int col = 16 * j + l15;
      const float bsv = bs[col];
      if (ph == 0) {
        const int m = col >> 5, dh = col & 31;
        #pragma unroll
        for (int r = 0; r < 4; ++r) {
          const int key = key0 + r;
          const int bbx = key / NK, kb = key - bbx * NK;
          const int kbp = (kb & ~31) | kperm(kb & 31);        // permuted chunk position
          kpb[((size_t)(bbx * M_ + m) * NKP + kbp) * DH + dh] = f2b(z[j][r] + bsv);
        }
      } else {
        #pragma unroll
        for (int r = 0; r < 4; ++r) {
          const int key = key0 + r;
          const int bbx = key / NK, kb = key - bbx * NK;
          vtb[((size_t)(bbx * 128 + col)) * NKP + kb] = f2b(z[j][r] + bsv);
        }
      }
    }
  } else {
    const int t = (blockIdx.x - 158) * 4 + wid;
    if (t >= 313) return;
    int myrow = 16 * t + l15; if (myrow > 4999) myrow = 4999;
    const int b = myrow / Q_, qpos = myrow - b * Q_;

    float xs[4][8];
    #pragma unroll
    for (int c = 0; c < 4; ++c)
      #pragma unroll
      for (int e = 0; e < 8; ++e) xs[c][e] = 0.f;

    #pragma unroll
    for (int n = 0; n < 2; ++n) {
      float x[4][8];
      float s = 0.f, s2 = 0.f;
      #pragma unroll
      for (int c = 0; c < 4; ++c)
        #pragma unroll
        for (int e = 0; e < 8; ++e) {
          const float xv = qin[((size_t)((b * N_ + n) * D_ + 32 * c + 8 * g + e)) * Q_ + qpos];
          x[c][e] = xv; s += xv; s2 += xv * xv;
        }
      s  += __shfl_xor(s, 16);  s2 += __shfl_xor(s2, 16);
      s  += __shfl_xor(s, 32);  s2 += __shfl_xor(s2, 32);
      const float mean = s * (1.f / 128.f);
      const float rstd = rsqrtf(s2 * (1.f / 128.f) - mean * mean + 1e-5f);
      #pragma unroll
      for (int c = 0; c < 4; ++c)
        #pragma unroll
        for (int e = 0; e < 8; ++e) xs[c][e] += (x[c][e] - mean) * rstd;
    }

    short8v aA[4];
    #pragma unroll
    for (int c = 0; c < 4; ++c) {
      #pragma unroll
      for (int e = 0; e < 8; ++e) {
        const int col = 32 * c + 8 * g + e;
        aA[c][e] = (short)f2b(SCALE * (xs[c][e] * lnq_g[col] + 2.f * lnq_b[col]));
      }
    }

    f32x4 z[8];
    #pragma unroll
    for (int j = 0; j < 8; ++j) {
      f32x4 d = {0.f, 0.f, 0.f, 0.f};
      #pragma unroll
      for (int c = 0; c < 4; ++c) {
        const short8v w8 = *(const short8v*)(wqk + (((c * 8 + j) * 64 + lane) << 3));
        d = __builtin_amdgcn_mfma_f32_16x16x32_bf16(aA[c], w8, d, 0, 0, 0);
      }
      z[j] = d;
    }

    const int row0 = 16 * t + 4 * g;
    #pragma unroll
    for (int j = 0; j < 8; ++j) {
      const int col = 16 * j + l15;
      const float bsv = 2.f * SCALE * bq[col];
      #pragma unroll
      for (int r = 0; r < 4; ++r) {
        const int row = row0 + r;
        if (row < 5000) qsb[((size_t)row) * 128 + col] = f2b(z[j][r] + bsv);
      }
    }
  }
}

// ---------------- Kernel 3: MFMA flash attention, zero-LDS (permuted-K in-register P path) ----------------
__global__ __launch_bounds__(256)
void attn_kernel(const unsigned short* __restrict__ qsb,
                 const unsigned short* __restrict__ kpb,
                 const unsigned short* __restrict__ vtb,
                 float* __restrict__ pl, float* __restrict__ pacc)
{
  const int wid  = threadIdx.x >> 6;
  const int lane = threadIdx.x & 63;
  const int bi = blockIdx.x;
  const int sp = bi & 3;
  const int tmp = bi >> 2;
  const int qt4 = tmp % 40;
  const int bm = tmp / 40;               // b*4+m
  const int qt = qt4 * 4 + wid;
  if (qt >= QT_TILES) return;

  const int q16 = lane & 15, g = lane >> 4;
  const int q = qt * 16 + q16;
  const int qc = q < Q_ ? q : Q_ - 1;
  const int b = bm >> 2;

  const short8v qf = *(const short8v*)(qsb + ((size_t)(b * Q_ + qc)) * 128 + (bm & 3) * DH + g * 8);

  const unsigned short* kbase = kpb + ((size_t)bm * NKP + sp * KPSP) * DH + q16 * DH + g * 8;
  const unsigned short* vbase = vtb + ((size_t)(bm * DH + q16)) * NKP + sp * KPSP + g * 8;

  f32x4 o0 = {0.f, 0.f, 0.f, 0.f}, o1 = {0.f, 0.f, 0.f, 0.f};
  float l = 0.f;

  const int c0 = qt % CHUNKS;
  int c1 = c0 + 1; if (c1 >= CHUNKS) c1 -= CHUNKS;
  int cn = c0 + 2; if (cn >= CHUNKS) cn -= CHUNKS;

  short8v kA1 = *(const short8v*)(kbase + c0 * 1024);
  short8v kA2 = *(const short8v*)(kbase + c0 * 1024 + 512);
  short8v vA1 = *(const short8v*)(vbase + c0 * 32);
  short8v vA2 = *(const short8v*)(vbase + c0 * 32 + 16 * NKP);
  short8v kB1 = *(const short8v*)(kbase + c1 * 1024);
  short8v kB2 = *(const short8v*)(kbase + c1 * 1024 + 512);
  short8v vB1 = *(const short8v*)(vbase + c1 * 32);
  short8v vB2 = *(const short8v*)(vbase + c1 * 32 + 16 * NKP);

  auto step = [&](short8v& K1r, short8v& K2r, short8v& V1r, short8v& V2r, int cnx) {
    // Permuted K: lane (q16,g) gets S for keys 8g+r (s0) and 8g+4+r (s1)
    f32x4 s0 = __builtin_amdgcn_mfma_f32_16x16x32_bf16(K1r, qf, (f32x4){0.f,0.f,0.f,0.f}, 0, 0, 0);
    f32x4 s1 = __builtin_amdgcn_mfma_f32_16x16x32_bf16(K2r, qf, (f32x4){0.f,0.f,0.f,0.f}, 0, 0, 0);

    float p[8];
    #pragma unroll
    for (int r = 0; r < 4; ++r) { p[r] = __expf(s0[r]); p[4 + r] = __expf(s1[r]); }
    #pragma unroll
    for (int i = 0; i < 8; ++i) l += p[i];

    short8v pb;                          // B-frag of P^T directly in-register
    #pragma unroll
    for (int i = 0; i < 8; ++i) pb[i] = (short)f2b(p[i]);

    o0 = __builtin_amdgcn_mfma_f32_16x16x32_bf16(V1r, pb, o0, 0, 0, 0);
    o1 = __builtin_amdgcn_mfma_f32_16x16x32_bf16(V2r, pb, o1, 0, 0, 0);

    K1r = *(const short8v*)(kbase + cnx * 1024);
    K2r = *(const short8v*)(kbase + cnx * 1024 + 512);
    V1r = *(const short8v*)(vbase + cnx * 32);
    V2r = *(const short8v*)(vbase + cnx * 32 + 16 * NKP);
  };

  #pragma unroll 1
  for (int it = 0; it < CHUNKS / 2; ++it) {
    step(kA1, kA2, vA1, vA2, cn);
    cn = cn + 1 >= CHUNKS ? cn + 1 - CHUNKS : cn + 1;
    step(kB1, kB2, vB1, vB2, cn);
    cn = cn + 1 >= CHUNKS ? cn + 1 - CHUNKS : cn + 1;
  }

  l += __shfl_xor(l, 16);
  l += __shfl_xor(l, 32);

  if (q < Q_) {
    const size_t row = (size_t)(bm * SPLIT + sp) * Q_ + q;
    if (lane < 16) pl[row] = l;
    *(f32x4*)(pacc + row * DH + 4 * g)      = o0;
    *(f32x4*)(pacc + row * DH + 16 + 4 * g) = o1;
  }
}

// ---------------- Kernel 4: fused combine + MFMA tail, 4 waves cooperate on one 16-row tile ----------------
__global__ __launch_bounds__(256)
void tail_kernel(const float* __restrict__ pl, const float* __restrict__ pacc,
                 const float* __restrict__ skip,
                 const unsigned short* __restrict__ wpk, const float* __restrict__ bp,
                 const float* __restrict__ ln1_g, const float* __restrict__ ln1_b,
                 const unsigned short* __restrict__ w1k, const float* __restrict__ b1,
                 const unsigned short* __restrict__ w2k, const float* __restrict__ b2,
                 const float* __restrict__ ln2_g, const float* __restrict__ ln2_b,
                 float* __restrict__ out)
{
  __shared__ __align__(16) unsigned short aL[16][136];
  __shared__ __align__(16) unsigned short zl[16][136];
  __shared__ __align__(16) unsigned short hl[16][264];
  __shared__ __align__(16) float stat1[4][16][2];
  __shared__ __align__(16) float stat2[4][16][2];

  const int wid = threadIdx.x >> 6, lane = threadIdx.x & 63;
  const int l15 = lane & 15, g = lane >> 4;
  const int row0 = blockIdx.x * 16;
  const int grow0 = row0 + 4 * g;

  {
    int arow = row0 + l15; if (arow > 4999) arow = 4999;
    const int bb = arow / Q_, qq = arow - bb * Q_;
    float ls = -40.0f;                   // exact correction for 40 zero-pad keys
    float4 a0 = {0,0,0,0}, a1 = {0,0,0,0};
    #pragma unroll
    for (int sp = 0; sp < SPLIT; ++sp) {
      const size_t row = (size_t)((bb * 4 + wid) * SPLIT + sp) * Q_ + qq;
      ls += pl[row];
      const float4 t0 = *(const float4*)(pacc + row * DH + 8 * g);
      const float4 t1 = *(const float4*)(pacc + row * DH + 8 * g + 4);
      a0.x += t0.x; a0.y += t0.y; a0.z += t0.z; a0.w += t0.w;
      a1.x += t1.x; a1.y += t1.y; a1.z += t1.z; a1.w += t1.w;
    }
    const float inv = 1.f / ls;
    uint4 w;
    w.x = pk2(a0.x * inv, a0.y * inv);
    w.y = pk2(a0.z * inv, a0.w * inv);
    w.z = pk2(a1.x * inv, a1.y * inv);
    w.w = pk2(a1.z * inv, a1.w * inv);
    *(uint4*)&aL[l15][32 * wid + 8 * g] = w;
  }
  __syncthreads();

  short8v aA[4];
  #pragma unroll
  for (int c = 0; c < 4; ++c)
    aA[c] = *(const short8v*)&aL[l15][32 * c + 8 * g];

  f32x4 zres[2];
  #pragma unroll
  for (int jj = 0; jj < 2; ++jj) {
    const int j = 2 * wid + jj;
    f32x4 d = {0.f, 0.f, 0.f, 0.f};
    #pragma unroll
    for (int c = 0; c < 4; ++c) {
      const short8v wf = *(const short8v*)(wpk + (((c * 8 + j) * 64 + lane) << 3));
      d = __builtin_amdgcn_mfma_f32_16x16x32_bf16(aA[c], wf, d, 0, 0, 0);
    }
    zres[jj] = d;
  }

  #pragma unroll
  for (int jj = 0; jj < 2; ++jj) {
    const int col = 16 * (2 * wid + jj) + l15;
    const float bpv = bp[col];
    #pragma unroll
    for (int r = 0; r < 4; ++r) {
      int rr = grow0 + r; if (rr > 4999) rr = 4999;
      const int bb = rr / 2500, q = rr - bb * 2500;
      zres[jj][r] += bpv + skip[((size_t)(bb * 128 + col)) * 2500 + q];
    }
  }

  {
    float sum[4], sq[4];
    #pragma unroll
    for (int r = 0; r < 4; ++r) {
      sum[r] = zres[0][r] + zres[1][r];
      sq[r]  = zres[0][r] * zres[0][r] + zres[1][r] * zres[1][r];
    }
    #pragma unroll
    for (int r = 0; r < 4; ++r) {
      #pragma unroll
      for (int off = 1; off < 16; off <<= 1) {
        sum[r] += __shfl_xor(sum[r], off);
        sq[r]  += __shfl_xor(sq[r], off);
      }
    }
    if (l15 == 0) {
      float4 s0 = {sum[0], sq[0], sum[1], sq[1]};
      float4 s1 = {sum[2], sq[2], sum[3], sq[3]};
      *(float4*)&stat1[wid][4 * g][0]     = s0;
      *(float4*)&stat1[wid][4 * g + 2][0] = s1;
    }
  }
  __syncthreads();

  float mean[4], rstd[4];
  #pragma unroll
  for (int r = 0; r < 4; ++r) {
    float S = 0.f, S2 = 0.f;
    #pragma unroll
    for (int w2 = 0; w2 < 4; ++w2) {
      S  += stat1[w2][4 * g + r][0];
      S2 += stat1[w2][4 * g + r][1];
    }
    mean[r] = S * (1.f / 128.f);
    rstd[r] = rsqrtf(S2 * (1.f / 128.f) - mean[r] * mean[r] + 1e-5f);
  }

  #pragma unroll
  for (int jj = 0; jj < 2; ++jj) {
    const int col = 16 * (2 * wid + jj) + l15;
    const float g1 = ln1_g[col], bv1 = ln1_b[col];
    #pragma unroll
    for (int r = 0; r < 4; ++r) {
      const float vv = (zres[jj][r] - mean[r]) * rstd[r] * g1 + bv1;
      zres[jj][r] = vv;
      zl[4 * g + r][col] = f2b(vv);
    }
  }
  __syncthreads();

  short8v zA[4];
  #pragma unroll
  for (int c = 0; c < 4; ++c)
    zA[c] = *(const short8v*)&zl[l15][32 * c + 8 * g];
  #pragma unroll
  for (int jj = 0; jj < 4; ++jj) {
    const int j = 4 * wid + jj;
    f32x4 d = {0.f, 0.f, 0.f, 0.f};
    #pragma unroll
    for (int c = 0; c < 4; ++c) {
      const short8v wf = *(const short8v*)(w1k + (((c * 16 + j) * 64 + lane) << 3));
      d = __builtin_amdgcn_mfma_f32_16x16x32_bf16(zA[c], wf, d, 0, 0, 0);
    }
    const int col = 16 * j + l15;
    const float bv = b1[col];
    #pragma unroll
    for (int r = 0; r < 4; ++r) {
      const float x = d[r] + bv;
      hl[4 * g + r][col] = f2b(0.5f * x * (1.f + erff(x * 0.70710678118654752f)));
    }
  }
  __syncthreads();

  short8v hA[8];
  #pragma unroll
  for (int c = 0; c < 8; ++c)
    hA[c] = *(const short8v*)&hl[l15][32 * c + 8 * g];
  #pragma unroll
  for (int jj = 0; jj < 2; ++jj) {
    const int j = 2 * wid + jj;
    f32x4 d = {0.f, 0.f, 0.f, 0.f};
    #pragma unroll
    for (int c = 0; c < 8; ++c) {
      const short8v wf = *(const short8v*)(w2k + (((c * 8 + j) * 64 + lane) << 3));
      d = __builtin_amdgcn_mfma_f32_16x16x32_bf16(hA[c], wf, d, 0, 0, 0);
    }
    const int col = 16 * j + l15;
    const float bv = b2[col];
    #pragma unroll
    for (int r = 0; r < 4; ++r) zres[jj][r] += d[r] + bv;
  }

  {
    float sum[4], sq[4];
    #pragma unroll
    for (int r = 0; r < 4; ++r) {
      sum[r] = zres[0][r] + zres[1][r];
      sq[r]  = zres[0][r] * zres[0][r] + zres[1][r] * zres[1][r];
    }
    #pragma unroll
    for (int r = 0; r < 4; ++r) {
      #pragma unroll
      for (int off = 1; off < 16; off <<= 1) {
        sum[r] += __shfl_xor(sum[r], off);
        sq[r]  += __shfl_xor(sq[r], off);
      }
    }
    if (l15 == 0) {
      float4 s0 = {sum[0], sq[0], sum[1], sq[1]};
      float4 s1 = {sum[2], sq[2], sum[3], sq[3]};
      *(float4*)&stat2[wid][4 * g][0]     = s0;
      *(float4*)&stat2[wid][4 * g + 2][0] = s1;
    }
  }
  __syncthreads();

  float mean2[4], rstd2[4];
  #pragma unroll
  for (int r = 0; r < 4; ++r) {
    float S = 0.f, S2 = 0.f;
    #pragma unroll
    for (int w2 = 0; w2 < 4; ++w2) {
      S  += stat2[w2][4 * g + r][0];
      S2 += stat2[w2][4 * g + r][1];
    }
    mean2[r] = S * (1.f / 128.f);
    rstd2[r] = rsqrtf(S2 * (1.f / 128.f) - mean2[r] * mean2[r] + 1e-5f);
  }

  if (grow0 + 3 <= 4999) {
    const int bb = grow0 / 2500, q0 = grow0 - bb * 2500;
    #pragma unroll
    for (int jj = 0; jj < 2; ++jj) {
      const int col = 16 * (2 * wid + jj) + l15;
      const float g2 = ln2_g[col], bv2 = ln2_b[col];
      float4 o;
      o.x = (zres[jj][0] - mean2[0]) * rstd2[0] * g2 + bv2;
      o.y = (zres[jj][1] - mean2[1]) * rstd2[1] * g2 + bv2;
      o.z = (zres[jj][2] - mean2[2]) * rstd2[2] * g2 + bv2;
      o.w = (zres[jj][3] - mean2[3]) * rstd2[3] * g2 + bv2;
      *(float4*)(out + ((size_t)(bb * 128 + col)) * 2500 + q0) = o;
    }
  }
}

extern "C" void kernel_launch(void* const* d_in, const int* in_sizes, int n_in,
                              void* d_out, int out_size, void* d_ws, size_t ws_size,
                              hipStream_t stream)
{
  const float* q     = (const float*)d_in[0];
  const float* k     = (const float*)d_in[1];
  const float* v     = (const float*)d_in[2];
  const float* skip  = (const float*)d_in[3];
  const float* lnq_g = (const float*)d_in[4];
  const float* lnq_b = (const float*)d_in[5];
  const float* wq    = (const float*)d_in[6];
  const float* bq    = (const float*)d_in[7];
  const float* lnk_g = (const float*)d_in[8];
  const float* lnk_b = (const float*)d_in[9];
  const float* wk    = (const float*)d_in[10];
  const float* bk    = (const float*)d_in[11];
  const float* lnv_g = (const float*)d_in[12];
  const float* lnv_b = (const float*)d_in[13];
  const float* wv    = (const float*)d_in[14];
  const float* bv    = (const float*)d_in[15];
  const float* wp    = (const float*)d_in[16];
  const float* bp    = (const float*)d_in[17];
  const float* ln1_g = (const float*)d_in[18];
  const float* ln1_b = (const float*)d_in[19];
  const float* w1    = (const float*)d_in[20];
  const float* b1    = (const float*)d_in[21];
  const float* w2    = (const float*)d_in[22];
  const float* b2    = (const float*)d_in[23];
  const float* ln2_g = (const float*)d_in[24];
  const float* ln2_b = (const float*)d_in[25];

  unsigned short* kpb = (unsigned short*)d_ws;         // 655360
  unsigned short* vtb = kpb + 655360;                  // 655360
  unsigned short* qsb = vtb + 655360;                  // 640000
  unsigned short* wpk = qsb + 640000;                  // 16384
  unsigned short* w1k = wpk + 16384;                   // 32768
  unsigned short* w2k = w1k + 32768;                   // 32768
  unsigned short* wqk = w2k + 32768;                   // 16384
  unsigned short* wkk = wqk + 16384;                   // 16384
  unsigned short* wvk = wkk + 16384;                   // 16384
  float* pl   = (float*)(wvk + 16384);                 // 8*4*2500 = 80000
  float* pacc = pl + 80000;                            // *32 = 2560000

  setup_kernel<<<dim3(130), dim3(256), 0, stream>>>(wp, w1, w2, wq, wk, wv,
                                                    wpk, w1k, w2k, wqk, wkk, wvk,
                                                    kpb, vtb);
  proj_kernel<<<dim3(237), dim3(256), 0, stream>>>(
      k, v, lnk_g, lnk_b, wkk, bk, lnv_g, lnv_b, wvk, bv, kpb, vtb,
      q, lnq_g, lnq_b, wqk, bq, qsb);
  attn_kernel<<<dim3(1280), dim3(256), 0, stream>>>(qsb, kpb, vtb, pl, pacc);
  tail_kernel<<<dim3(313), dim3(256), 0, stream>>>(
      pl, pacc, skip, wpk, bp, ln1_g, ln1_b, w1k, b1, w2k, b2, ln2_g, ln2_b, (float*)d_out);
}

// Round 10
// 66.231 us; speedup vs baseline: 8.2964x; 1.1254x over previous
//
#include <hip/hip_runtime.h>
#include <hip/hip_bf16.h>
#include <math.h>

#define B_  2
#define N_  6
#define D_  128
#define Q_  2500
#define HK  420
#define NK  2520
#define NKP 2560      // padded keys (40 zero-pads)
#define M_  4
#define DH  32
#define SPLIT 8
#define KPSP 320      // NKP/SPLIT
#define CHUNKS 10     // KPSP/32
#define SCALE 0.25503487775f   // 32^-0.5 * log2(e); attn uses exp2

typedef __attribute__((ext_vector_type(8))) short short8v;
typedef __attribute__((ext_vector_type(4))) float f32x4;

__device__ __forceinline__ unsigned short f2b(float x) {
  unsigned u = __float_as_uint(x);
  return (unsigned short)((u + 0x7FFFu + ((u >> 16) & 1u)) >> 16);
}

__device__ __forceinline__ unsigned pk2(float lo, float hi) {
  return (unsigned)f2b(lo) | ((unsigned)f2b(hi) << 16);
}

// K-chunk storage permutation: actual key a (0..31) -> buffer position p so that
// the QK^T D-layout lands P[8g+e] directly in lane (q16,g)'s PV B-frag slots.
__device__ __forceinline__ int kperm(int a) {
  const int h = a & 7;
  return ((h >= 4) ? 16 : 0) + 4 * (a >> 3) + (h & 3);
}

// ---------------- Kernel 1: prepack weights to MFMA B-frag order + zero pad chunks ----------------
__global__ __launch_bounds__(256)
void setup_kernel(const float* __restrict__ wp, const float* __restrict__ w1,
                  const float* __restrict__ w2, const float* __restrict__ wq,
                  const float* __restrict__ wk, const float* __restrict__ wv,
                  unsigned short* __restrict__ wpk, unsigned short* __restrict__ w1k,
                  unsigned short* __restrict__ w2k, unsigned short* __restrict__ wqk,
                  unsigned short* __restrict__ wkk, unsigned short* __restrict__ wvk,
                  unsigned short* __restrict__ kpb, unsigned short* __restrict__ vtb)
{
  if (blockIdx.x < 128) {
    const int base = blockIdx.x * 1024 + threadIdx.x * 4;
    #pragma unroll
    for (int i = 0; i < 4; ++i) {
      const int tid = base + i;                       // < 131072
      if (tid < 16384) {                              // wp: [128][128]
        const int e = tid & 7, l = (tid >> 3) & 63, j = (tid >> 9) & 7, c = tid >> 12;
        wpk[tid] = f2b(wp[(32*c + 8*(l>>4) + e) * 128 + 16*j + (l & 15)]);
      } else if (tid < 49152) {                       // w1: [128][256]
        const int t2 = tid - 16384;
        const int e = t2 & 7, l = (t2 >> 3) & 63, j = (t2 >> 9) & 15, c = t2 >> 13;
        w1k[t2] = f2b(w1[(32*c + 8*(l>>4) + e) * 256 + 16*j + (l & 15)]);
      } else if (tid < 81920) {                       // w2: [256][128]
        const int t2 = tid - 49152;
        const int e = t2 & 7, l = (t2 >> 3) & 63, j = (t2 >> 9) & 7, c = t2 >> 12;
        w2k[t2] = f2b(w2[(32*c + 8*(l>>4) + e) * 128 + 16*j + (l & 15)]);
      } else {                                        // wq/wk/wv: [128][128]
        const int t2 = (tid - 81920) & 16383;
        const int which = (tid - 81920) >> 14;
        const float* src = which == 0 ? wq : which == 1 ? wk : wv;
        unsigned short* dst = which == 0 ? wqk : which == 1 ? wkk : wvk;
        const int e = t2 & 7, l = (t2 >> 3) & 63, j = (t2 >> 9) & 7, c = t2 >> 12;
        dst[t2] = f2b(src[(32*c + 8*(l>>4) + e) * 128 + 16*j + (l & 15)]);
      }
    }
  } else {
    // zero kpb buffer positions 2496..2559 (proj rewrites real keys 2496..2519 after)
    const int base = (blockIdx.x - 128) * 256 + threadIdx.x;   // 0..511
    for (int i = base; i < 16384; i += 512) {
      const int bm = i >> 11, rem = i & 2047;
      kpb[((size_t)bm * NKP + 2496 + (rem >> 5)) * DH + (rem & 31)] = 0;
      vtb[((size_t)(i >> 6)) * NKP + 2496 + (i & 63)] = 0;
    }
  }
}

// ---------------- Kernel 2: fused MFMA LN+project for K, V and Q ----------------
__global__ __launch_bounds__(256)
void proj_kernel(const float* __restrict__ kin, const float* __restrict__ vin,
                 const float* __restrict__ lnk_g, const float* __restrict__ lnk_b,
                 const unsigned short* __restrict__ wkk, const float* __restrict__ bk,
                 const float* __restrict__ lnv_g, const float* __restrict__ lnv_b,
                 const unsigned short* __restrict__ wvk, const float* __restrict__ bv,
                 unsigned short* __restrict__ kpb, unsigned short* __restrict__ vtb,
                 const float* __restrict__ qin,
                 const float* __restrict__ lnq_g, const float* __restrict__ lnq_b,
                 const unsigned short* __restrict__ wqk, const float* __restrict__ bq,
                 unsigned short* __restrict__ qsb)
{
  const int wid = threadIdx.x >> 6, lane = threadIdx.x & 63;
  const int l15 = lane & 15, g = lane >> 4;

  if (blockIdx.x < 158) {
    const int T = blockIdx.x * 4 + wid;
    if (T >= 630) return;
    const int ph = T >= 315 ? 1 : 0;
    const int t = ph ? T - 315 : T;

    const float* in = ph ? vin : kin;
    const float* gg = ph ? lnv_g : lnk_g;
    const float* bb = ph ? lnv_b : lnk_b;
    const unsigned short* wf = ph ? wvk : wkk;
    const float* bs = ph ? bv : bk;

    const int myrow = 16 * t + l15;
    const int cam = myrow / HK, kk = myrow - cam * HK;

    float x[4][8];
    float s = 0.f, s2 = 0.f;
    #pragma unroll
    for (int c = 0; c < 4; ++c)
      #pragma unroll
      for (int e = 0; e < 8; ++e) {
        const float xv = in[((size_t)(cam * D_ + 32 * c + 8 * g + e)) * HK + kk];
        x[c][e] = xv; s += xv; s2 += xv * xv;
      }
    s  += __shfl_xor(s, 16);  s2 += __shfl_xor(s2, 16);
    s  += __shfl_xor(s, 32);  s2 += __shfl_xor(s2, 32);
    const float mean = s * (1.f / 128.f);
    const float rstd = rsqrtf(s2 * (1.f / 128.f) - mean * mean + 1e-5f);

    short8v aA[4];
    #pragma unroll
    for (int c = 0; c < 4; ++c)
      #pragma unroll
      for (int e = 0; e < 8; ++e) {
        const int col = 32 * c + 8 * g + e;
        aA[c][e] = (short)f2b((x[c][e] - mean) * rstd * gg[col] + bb[col]);
      }

    f32x4 z[8];
    #pragma unroll
    for (int j = 0; j < 8; ++j) {
      f32x4 d = {0.f, 0.f, 0.f, 0.f};
      #pragma unroll
      for (int c = 0; c < 4; ++c) {
        const short8v w8 = *(const short8v*)(wf + (((c * 8 + j) * 64 + lane) << 3));
        d = __builtin_amdgcn_mfma_f32_16x16x32_bf16(aA[c], w8, d, 0, 0, 0);
      }
      z[j] = d;
    }

    const int key0 = 16 * t + 4 * g;
    #pragma unroll
    for (int j = 0; j < 8; ++j) {
      const int col = 16 * j + l15;
      const float bsv = bs[col];
      if (ph == 0) {
        const int m = col >> 5, dh = col & 31;
        #pragma unroll
        for (int r = 0; r < 4; ++r) {
          const int key = key0 + r;
          const int bbx = key / NK, kb = key - bbx * NK;
          const int kbp = (kb & ~31) | kperm(kb & 31);        // permuted chunk position
          kpb[((size_t)(bbx * M_ + m) * NKP + kbp) * DH + dh] = f2b(z[j][r] + bsv);
        }
      } else {
        #pragma unroll
        for (int r = 0; r < 4; ++r) {
          const int key = key0 + r;
          const int bbx = key / NK, kb = key - bbx * NK;
          vtb[((size_t)(bbx * 128 + col)) * NKP + kb] = f2b(z[j][r] + bsv);
        }
      }
    }
  } else {
    const int t = (blockIdx.x - 158) * 4 + wid;
    if (t >= 313) return;
    int myrow = 16 * t + l15; if (myrow > 4999) myrow = 4999;
    const int b = myrow / Q_, qpos = myrow - b * Q_;

    float xs[4][8];
    #pragma unroll
    for (int c = 0; c < 4; ++c)
      #pragma unroll
      for (int e = 0; e < 8; ++e) xs[c][e] = 0.f;

    #pragma unroll
    for (int n = 0; n < 2; ++n) {
      float x[4][8];
      float s = 0.f, s2 = 0.f;
      #pragma unroll
      for (int c = 0; c < 4; ++c)
        #pragma unroll
        for (int e = 0; e < 8; ++e) {
          const float xv = qin[((size_t)((b * N_ + n) * D_ + 32 * c + 8 * g + e)) * Q_ + qpos];
          x[c][e] = xv; s += xv; s2 += xv * xv;
        }
      s  += __shfl_xor(s, 16);  s2 += __shfl_xor(s2, 16);
      s  += __shfl_xor(s, 32);  s2 += __shfl_xor(s2, 32);
      const float mean = s * (1.f / 128.f);
      const float rstd = rsqrtf(s2 * (1.f / 128.f) - mean * mean + 1e-5f);
      #pragma unroll
      for (int c = 0; c < 4; ++c)
        #pragma unroll
        for (int e = 0; e < 8; ++e) xs[c][e] += (x[c][e] - mean) * rstd;
    }

    short8v aA[4];
    #pragma unroll
    for (int c = 0; c < 4; ++c) {
      #pragma unroll
      for (int e = 0; e < 8; ++e) {
        const int col = 32 * c + 8 * g + e;
        aA[c][e] = (short)f2b(SCALE * (xs[c][e] * lnq_g[col] + 2.f * lnq_b[col]));
      }
    }

    f32x4 z[8];
    #pragma unroll
    for (int j = 0; j < 8; ++j) {
      f32x4 d = {0.f, 0.f, 0.f, 0.f};
      #pragma unroll
      for (int c = 0; c < 4; ++c) {
        const short8v w8 = *(const short8v*)(wqk + (((c * 8 + j) * 64 + lane) << 3));
        d = __builtin_amdgcn_mfma_f32_16x16x32_bf16(aA[c], w8, d, 0, 0, 0);
      }
      z[j] = d;
    }

    const int row0 = 16 * t + 4 * g;
    #pragma unroll
    for (int j = 0; j < 8; ++j) {
      const int col = 16 * j + l15;
      const float bsv = 2.f * SCALE * bq[col];
      #pragma unroll
      for (int r = 0; r < 4; ++r) {
        const int row = row0 + r;
        if (row < 5000) qsb[((size_t)row) * 128 + col] = f2b(z[j][r] + bsv);
      }
    }
  }
}

// ---------------- Kernel 3: MFMA flash attention — 2 q-tiles per wave share K/V stream ----------------
__global__ __launch_bounds__(256)
void attn_kernel(const unsigned short* __restrict__ qsb,
                 const unsigned short* __restrict__ kpb,
                 const unsigned short* __restrict__ vtb,
                 float* __restrict__ pl, float* __restrict__ pacc)
{
  const int wid  = threadIdx.x >> 6;
  const int lane = threadIdx.x & 63;
  const int bi = blockIdx.x;
  const int sp = bi & 7;
  const int tmp = bi >> 3;
  const int qg = tmp % 20;
  const int bm = tmp / 20;               // b*4+m
  const int qp = qg * 4 + wid;           // q-tile pair 0..79 -> tiles 2qp, 2qp+1

  const int q16 = lane & 15, g = lane >> 4;
  const int qa = (2 * qp) * 16 + q16;
  const int qb = (2 * qp + 1) * 16 + q16;
  const int qca = qa < Q_ ? qa : Q_ - 1;
  const int qcb = qb < Q_ ? qb : Q_ - 1;
  const int b = bm >> 2;

  const short8v qf0 = *(const short8v*)(qsb + ((size_t)(b * Q_ + qca)) * 128 + (bm & 3) * DH + g * 8);
  const short8v qf1 = *(const short8v*)(qsb + ((size_t)(b * Q_ + qcb)) * 128 + (bm & 3) * DH + g * 8);

  const unsigned short* kbase = kpb + ((size_t)bm * NKP + sp * KPSP) * DH + q16 * DH + g * 8;
  const unsigned short* vbase = vtb + ((size_t)(bm * DH + q16)) * NKP + sp * KPSP + g * 8;

  f32x4 o0a = {0,0,0,0}, o1a = {0,0,0,0}, o0b = {0,0,0,0}, o1b = {0,0,0,0};
  float la = 0.f, lb = 0.f;

  const int c0 = qp % CHUNKS;
  int c1 = c0 + 1; if (c1 >= CHUNKS) c1 -= CHUNKS;
  int cn = c0 + 2; if (cn >= CHUNKS) cn -= CHUNKS;

  short8v kA1 = *(const short8v*)(kbase + c0 * 1024);
  short8v kA2 = *(const short8v*)(kbase + c0 * 1024 + 512);
  short8v vA1 = *(const short8v*)(vbase + c0 * 32);
  short8v vA2 = *(const short8v*)(vbase + c0 * 32 + 16 * NKP);
  short8v kB1 = *(const short8v*)(kbase + c1 * 1024);
  short8v kB2 = *(const short8v*)(kbase + c1 * 1024 + 512);
  short8v vB1 = *(const short8v*)(vbase + c1 * 32);
  short8v vB2 = *(const short8v*)(vbase + c1 * 32 + 16 * NKP);

  auto step = [&](short8v& K1r, short8v& K2r, short8v& V1r, short8v& V2r, int cnx) {
    // Permuted K: lane (q16,g) gets S for keys 8g+r (s0*) and 8g+4+r (s1*)
    f32x4 s0a = __builtin_amdgcn_mfma_f32_16x16x32_bf16(K1r, qf0, (f32x4){0.f,0.f,0.f,0.f}, 0, 0, 0);
    f32x4 s1a = __builtin_amdgcn_mfma_f32_16x16x32_bf16(K2r, qf0, (f32x4){0.f,0.f,0.f,0.f}, 0, 0, 0);
    f32x4 s0b = __builtin_amdgcn_mfma_f32_16x16x32_bf16(K1r, qf1, (f32x4){0.f,0.f,0.f,0.f}, 0, 0, 0);
    f32x4 s1b = __builtin_amdgcn_mfma_f32_16x16x32_bf16(K2r, qf1, (f32x4){0.f,0.f,0.f,0.f}, 0, 0, 0);

    float pa[8], pb_[8];
    #pragma unroll
    for (int r = 0; r < 4; ++r) {
      pa[r] = __builtin_amdgcn_exp2f(s0a[r]);  pa[4 + r] = __builtin_amdgcn_exp2f(s1a[r]);
      pb_[r] = __builtin_amdgcn_exp2f(s0b[r]); pb_[4 + r] = __builtin_amdgcn_exp2f(s1b[r]);
    }
    #pragma unroll
    for (int i = 0; i < 8; ++i) { la += pa[i]; lb += pb_[i]; }

    short8v fa, fb;
    #pragma unroll
    for (int i = 0; i < 8; ++i) { fa[i] = (short)f2b(pa[i]); fb[i] = (short)f2b(pb_[i]); }

    o0a = __builtin_amdgcn_mfma_f32_16x16x32_bf16(V1r, fa, o0a, 0, 0, 0);
    o1a = __builtin_amdgcn_mfma_f32_16x16x32_bf16(V2r, fa, o1a, 0, 0, 0);
    o0b = __builtin_amdgcn_mfma_f32_16x16x32_bf16(V1r, fb, o0b, 0, 0, 0);
    o1b = __builtin_amdgcn_mfma_f32_16x16x32_bf16(V2r, fb, o1b, 0, 0, 0);

    K1r = *(const short8v*)(kbase + cnx * 1024);
    K2r = *(const short8v*)(kbase + cnx * 1024 + 512);
    V1r = *(const short8v*)(vbase + cnx * 32);
    V2r = *(const short8v*)(vbase + cnx * 32 + 16 * NKP);
  };

  #pragma unroll 1
  for (int it = 0; it < CHUNKS / 2; ++it) {
    step(kA1, kA2, vA1, vA2, cn);
    cn = cn + 1 >= CHUNKS ? cn + 1 - CHUNKS : cn + 1;
    step(kB1, kB2, vB1, vB2, cn);
    cn = cn + 1 >= CHUNKS ? cn + 1 - CHUNKS : cn + 1;
  }

  la += __shfl_xor(la, 16);  la += __shfl_xor(la, 32);
  lb += __shfl_xor(lb, 16);  lb += __shfl_xor(lb, 32);

  if (qa < Q_) {
    const size_t row = (size_t)(bm * SPLIT + sp) * Q_ + qa;
    if (lane < 16) pl[row] = la;
    *(f32x4*)(pacc + row * DH + 4 * g)      = o0a;
    *(f32x4*)(pacc + row * DH + 16 + 4 * g) = o1a;
  }
  if (qb < Q_) {
    const size_t row = (size_t)(bm * SPLIT + sp) * Q_ + qb;
    if (lane < 16) pl[row] = lb;
    *(f32x4*)(pacc + row * DH + 4 * g)      = o0b;
    *(f32x4*)(pacc + row * DH + 16 + 4 * g) = o1b;
  }
}

// ---------------- Kernel 4: fused combine + MFMA tail, 4 waves cooperate on one 16-row tile ----------------
__global__ __launch_bounds__(256)
void tail_kernel(const float* __restrict__ pl, const float* __restrict__ pacc,
                 const float* __restrict__ skip,
                 const unsigned short* __restrict__ wpk, const float* __restrict__ bp,
                 const float* __restrict__ ln1_g, const float* __restrict__ ln1_b,
                 const unsigned short* __restrict__ w1k, const float* __restrict__ b1,
                 const unsigned short* __restrict__ w2k, const float* __restrict__ b2,
                 const float* __restrict__ ln2_g, const float* __restrict__ ln2_b,
                 float* __restrict__ out)
{
  __shared__ __align__(16) unsigned short aL[16][136];
  __shared__ __align__(16) unsigned short zl[16][136];
  __shared__ __align__(16) unsigned short hl[16][264];
  __shared__ __align__(16) float stat1[4][16][2];
  __shared__ __align__(16) float stat2[4][16][2];

  const int wid = threadIdx.x >> 6, lane = threadIdx.x & 63;
  const int l15 = lane & 15, g = lane >> 4;
  const int row0 = blockIdx.x * 16;
  const int grow0 = row0 + 4 * g;

  {
    int arow = row0 + l15; if (arow > 4999) arow = 4999;
    const int bb = arow / Q_, qq = arow - bb * Q_;
    float ls = -40.0f;                   // exact correction for 40 zero-pad keys
    float4 a0 = {0,0,0,0}, a1 = {0,0,0,0};
    #pragma unroll
    for (int sp = 0; sp < SPLIT; ++sp) {
      const size_t row = (size_t)((bb * 4 + wid) * SPLIT + sp) * Q_ + qq;
      ls += pl[row];
      const float4 t0 = *(const float4*)(pacc + row * DH + 8 * g);
      const float4 t1 = *(const float4*)(pacc + row * DH + 8 * g + 4);
      a0.x += t0.x; a0.y += t0.y; a0.z += t0.z; a0.w += t0.w;
      a1.x += t1.x; a1.y += t1.y; a1.z += t1.z; a1.w += t1.w;
    }
    const float inv = 1.f / ls;
    uint4 w;
    w.x = pk2(a0.x * inv, a0.y * inv);
    w.y = pk2(a0.z * inv, a0.w * inv);
    w.z = pk2(a1.x * inv, a1.y * inv);
    w.w = pk2(a1.z * inv, a1.w * inv);
    *(uint4*)&aL[l15][32 * wid + 8 * g] = w;
  }
  __syncthreads();

  short8v aA[4];
  #pragma unroll
  for (int c = 0; c < 4; ++c)
    aA[c] = *(const short8v*)&aL[l15][32 * c + 8 * g];

  f32x4 zres[2];
  #pragma unroll
  for (int jj = 0; jj < 2; ++jj) {
    const int j = 2 * wid + jj;
    f32x4 d = {0.f, 0.f, 0.f, 0.f};
    #pragma unroll
    for (int c = 0; c < 4; ++c) {
      const short8v wf = *(const short8v*)(wpk + (((c * 8 + j) * 64 + lane) << 3));
      d = __builtin_amdgcn_mfma_f32_16x16x32_bf16(aA[c], wf, d, 0, 0, 0);
    }
    zres[jj] = d;
  }

  #pragma unroll
  for (int jj = 0; jj < 2; ++jj) {
    const int col = 16 * (2 * wid + jj) + l15;
    const float bpv = bp[col];
    #pragma unroll
    for (int r = 0; r < 4; ++r) {
      int rr = grow0 + r; if (rr > 4999) rr = 4999;
      const int bb = rr / 2500, q = rr - bb * 2500;
      zres[jj][r] += bpv + skip[((size_t)(bb * 128 + col)) * 2500 + q];
    }
  }

  {
    float sum[4], sq[4];
    #pragma unroll
    for (int r = 0; r < 4; ++r) {
      sum[r] = zres[0][r] + zres[1][r];
      sq[r]  = zres[0][r] * zres[0][r] + zres[1][r] * zres[1][r];
    }
    #pragma unroll
    for (int r = 0; r < 4; ++r) {
      #pragma unroll
      for (int off = 1; off < 16; off <<= 1) {
        sum[r] += __shfl_xor(sum[r], off);
        sq[r]  += __shfl_xor(sq[r], off);
      }
    }
    if (l15 == 0) {
      float4 s0 = {sum[0], sq[0], sum[1], sq[1]};
      float4 s1 = {sum[2], sq[2], sum[3], sq[3]};
      *(float4*)&stat1[wid][4 * g][0]     = s0;
      *(float4*)&stat1[wid][4 * g + 2][0] = s1;
    }
  }
  __syncthreads();

  float mean[4], rstd[4];
  #pragma unroll
  for (int r = 0; r < 4; ++r) {
    float S = 0.f, S2 = 0.f;
    #pragma unroll
    for (int w2 = 0; w2 < 4; ++w2) {
      S  += stat1[w2][4 * g + r][0];
      S2 += stat1[w2][4 * g + r][1];
    }
    mean[r] = S * (1.f / 128.f);
    rstd[r] = rsqrtf(S2 * (1.f / 128.f) - mean[r] * mean[r] + 1e-5f);
  }

  #pragma unroll
  for (int jj = 0; jj < 2; ++jj) {
    const int col = 16 * (2 * wid + jj) + l15;
    const float g1 = ln1_g[col], bv1 = ln1_b[col];
    #pragma unroll
    for (int r = 0; r < 4; ++r) {
      const float vv = (zres[jj][r] - mean[r]) * rstd[r] * g1 + bv1;
      zres[jj][r] = vv;
      zl[4 * g + r][col] = f2b(vv);
    }
  }
  __syncthreads();

  short8v zA[4];
  #pragma unroll
  for (int c = 0; c < 4; ++c)
    zA[c] = *(const short8v*)&zl[l15][32 * c + 8 * g];
  #pragma unroll
  for (int jj = 0; jj < 4; ++jj) {
    const int j = 4 * wid + jj;
    f32x4 d = {0.f, 0.f, 0.f, 0.f};
    #pragma unroll
    for (int c = 0; c < 4; ++c) {
      const short8v wf = *(const short8v*)(w1k + (((c * 16 + j) * 64 + lane) << 3));
      d = __builtin_amdgcn_mfma_f32_16x16x32_bf16(zA[c], wf, d, 0, 0, 0);
    }
    const int col = 16 * j + l15;
    const float bv = b1[col];
    #pragma unroll
    for (int r = 0; r < 4; ++r) {
      const float x = d[r] + bv;
      hl[4 * g + r][col] = f2b(0.5f * x * (1.f + erff(x * 0.70710678118654752f)));
    }
  }
  __syncthreads();

  short8v hA[8];
  #pragma unroll
  for (int c = 0; c < 8; ++c)
    hA[c] = *(const short8v*)&hl[l15][32 * c + 8 * g];
  #pragma unroll
  for (int jj = 0; jj < 2; ++jj) {
    const int j = 2 * wid + jj;
    f32x4 d = {0.f, 0.f, 0.f, 0.f};
    #pragma unroll
    for (int c = 0; c < 8; ++c) {
      const short8v wf = *(const short8v*)(w2k + (((c * 8 + j) * 64 + lane) << 3));
      d = __builtin_amdgcn_mfma_f32_16x16x32_bf16(hA[c], wf, d, 0, 0, 0);
    }
    const int col = 16 * j + l15;
    const float bv = b2[col];
    #pragma unroll
    for (int r = 0; r < 4; ++r) zres[jj][r] += d[r] + bv;
  }

  {
    float sum[4], sq[4];
    #pragma unroll
    for (int r = 0; r < 4; ++r) {
      sum[r] = zres[0][r] + zres[1][r];
      sq[r]  = zres[0][r] * zres[0][r] + zres[1][r] * zres[1][r];
    }
    #pragma unroll
    for (int r = 0; r < 4; ++r) {
      #pragma unroll
      for (int off = 1; off < 16; off <<= 1) {
        sum[r] += __shfl_xor(sum[r], off);
        sq[r]  += __shfl_xor(sq[r], off);
      }
    }
    if (l15 == 0) {
      float4 s0 = {sum[0], sq[0], sum[1], sq[1]};
      float4 s1 = {sum[2], sq[2], sum[3], sq[3]};
      *(float4*)&stat2[wid][4 * g][0]     = s0;
      *(float4*)&stat2[wid][4 * g + 2][0] = s1;
    }
  }
  __syncthreads();

  float mean2[4], rstd2[4];
  #pragma unroll
  for (int r = 0; r < 4; ++r) {
    float S = 0.f, S2 = 0.f;
    #pragma unroll
    for (int w2 = 0; w2 < 4; ++w2) {
      S  += stat2[w2][4 * g + r][0];
      S2 += stat2[w2][4 * g + r][1];
    }
    mean2[r] = S * (1.f / 128.f);
    rstd2[r] = rsqrtf(S2 * (1.f / 128.f) - mean2[r] * mean2[r] + 1e-5f);
  }

  if (grow0 + 3 <= 4999) {
    const int bb = grow0 / 2500, q0 = grow0 - bb * 2500;
    #pragma unroll
    for (int jj = 0; jj < 2; ++jj) {
      const int col = 16 * (2 * wid + jj) + l15;
      const float g2 = ln2_g[col], bv2 = ln2_b[col];
      float4 o;
      o.x = (zres[jj][0] - mean2[0]) * rstd2[0] * g2 + bv2;
      o.y = (zres[jj][1] - mean2[1]) * rstd2[1] * g2 + bv2;
      o.z = (zres[jj][2] - mean2[2]) * rstd2[2] * g2 + bv2;
      o.w = (zres[jj][3] - mean2[3]) * rstd2[3] * g2 + bv2;
      *(float4*)(out + ((size_t)(bb * 128 + col)) * 2500 + q0) = o;
    }
  }
}

extern "C" void kernel_launch(void* const* d_in, const int* in_sizes, int n_in,
                              void* d_out, int out_size, void* d_ws, size_t ws_size,
                              hipStream_t stream)
{
  const float* q     = (const float*)d_in[0];
  const float* k     = (const float*)d_in[1];
  const float* v     = (const float*)d_in[2];
  const float* skip  = (const float*)d_in[3];
  const float* lnq_g = (const float*)d_in[4];
  const float* lnq_b = (const float*)d_in[5];
  const float* wq    = (const float*)d_in[6];
  const float* bq    = (const float*)d_in[7];
  const float* lnk_g = (const float*)d_in[8];
  const float* lnk_b = (const float*)d_in[9];
  const float* wk    = (const float*)d_in[10];
  const float* bk    = (const float*)d_in[11];
  const float* lnv_g = (const float*)d_in[12];
  const float* lnv_b = (const float*)d_in[13];
  const float* wv    = (const float*)d_in[14];
  const float* bv    = (const float*)d_in[15];
  const float* wp    = (const float*)d_in[16];
  const float* bp    = (const float*)d_in[17];
  const float* ln1_g = (const float*)d_in[18];
  const float* ln1_b = (const float*)d_in[19];
  const float* w1    = (const float*)d_in[20];
  const float* b1    = (const float*)d_in[21];
  const float* w2    = (const float*)d_in[22];
  const float* b2    = (const float*)d_in[23];
  const float* ln2_g = (const float*)d_in[24];
  const float* ln2_b = (const float*)d_in[25];

  unsigned short* kpb = (unsigned short*)d_ws;         // 655360
  unsigned short* vtb = kpb + 655360;                  // 655360
  unsigned short* qsb = vtb + 655360;                  // 640000
  unsigned short* wpk = qsb + 640000;                  // 16384
  unsigned short* w1k = wpk + 16384;                   // 32768
  unsigned short* w2k = w1k + 32768;                   // 32768
  unsigned short* wqk = w2k + 32768;                   // 16384
  unsigned short* wkk = wqk + 16384;                   // 16384
  unsigned short* wvk = wkk + 16384;                   // 16384
  float* pl   = (float*)(wvk + 16384);                 // 8*8*2500 = 160000
  float* pacc = pl + 160000;                           // *32 = 5120000

  setup_kernel<<<dim3(130), dim3(256), 0, stream>>>(wp, w1, w2, wq, wk, wv,
                                                    wpk, w1k, w2k, wqk, wkk, wvk,
                                                    kpb, vtb);
  proj_kernel<<<dim3(237), dim3(256), 0, stream>>>(
      k, v, lnk_g, lnk_b, wkk, bk, lnv_g, lnv_b, wvk, bv, kpb, vtb,
      q, lnq_g, lnq_b, wqk, bq, qsb);
  attn_kernel<<<dim3(1280), dim3(256), 0, stream>>>(qsb, kpb, vtb, pl, pacc);
  tail_kernel<<<dim3(313), dim3(256), 0, stream>>>(
      pl, pacc, skip, wpk, bp, ln1_g, ln1_b, w1k, b1, w2k, b2, ln2_g, ln2_b, (float*)d_out);
}

// Round 12
// 63.209 us; speedup vs baseline: 8.6930x; 1.0478x over previous
//
#include <hip/hip_runtime.h>
#include <hip/hip_bf16.h>
#include <math.h>

#define B_  2
#define N_  6
#define D_  128
#define Q_  2500
#define HK  420
#define NK  2520
#define NKP 2560      // padded keys (40 zero-pads)
#define M_  4
#define DH  32
#define SPLIT 8
#define KPSP 320      // NKP/SPLIT
#define CHUNKS 10     // KPSP/32
#define SCALE 0.25503487775f   // 32^-0.5 * log2(e); attn uses exp2

typedef __attribute__((ext_vector_type(8))) short short8v;
typedef __attribute__((ext_vector_type(4))) float f32x4;
typedef __attribute__((ext_vector_type(2))) unsigned u32x2;
typedef __attribute__((ext_vector_type(4))) unsigned u32x4;

__device__ __forceinline__ unsigned short f2b(float x) {
  unsigned u = __float_as_uint(x);
  return (unsigned short)((u + 0x7FFFu + ((u >> 16) & 1u)) >> 16);
}

__device__ __forceinline__ unsigned pk2(float lo, float hi) {
  return (unsigned)f2b(lo) | ((unsigned)f2b(hi) << 16);
}

__device__ __forceinline__ float bl(unsigned u) { return __uint_as_float(u << 16); }
__device__ __forceinline__ float bh(unsigned u) { return __uint_as_float(u & 0xffff0000u); }

// K-chunk storage permutation: actual key a (0..31) -> buffer position p so that
// the QK^T D-layout lands P[8g+e] directly in lane (q16,g)'s PV B-frag slots.
__device__ __forceinline__ int kperm(int a) {
  const int h = a & 7;
  return ((h >= 4) ? 16 : 0) + 4 * (a >> 3) + (h & 3);
}

// ---------------- Kernel 1: prepack weights to MFMA B-frag order + zero pad chunks ----------------
__global__ __launch_bounds__(256)
void setup_kernel(const float* __restrict__ wp, const float* __restrict__ w1,
                  const float* __restrict__ w2, const float* __restrict__ wq,
                  const float* __restrict__ wk, const float* __restrict__ wv,
                  unsigned short* __restrict__ wpk, unsigned short* __restrict__ w1k,
                  unsigned short* __restrict__ w2k, unsigned short* __restrict__ wqk,
                  unsigned short* __restrict__ wkk, unsigned short* __restrict__ wvk,
                  unsigned short* __restrict__ kpb, unsigned short* __restrict__ vtb)
{
  if (blockIdx.x < 128) {
    const int base = blockIdx.x * 1024 + threadIdx.x * 4;
    #pragma unroll
    for (int i = 0; i < 4; ++i) {
      const int tid = base + i;                       // < 131072
      if (tid < 16384) {                              // wp: [128][128]
        const int e = tid & 7, l = (tid >> 3) & 63, j = (tid >> 9) & 7, c = tid >> 12;
        wpk[tid] = f2b(wp[(32*c + 8*(l>>4) + e) * 128 + 16*j + (l & 15)]);
      } else if (tid < 49152) {                       // w1: [128][256]
        const int t2 = tid - 16384;
        const int e = t2 & 7, l = (t2 >> 3) & 63, j = (t2 >> 9) & 15, c = t2 >> 13;
        w1k[t2] = f2b(w1[(32*c + 8*(l>>4) + e) * 256 + 16*j + (l & 15)]);
      } else if (tid < 81920) {                       // w2: [256][128]
        const int t2 = tid - 49152;
        const int e = t2 & 7, l = (t2 >> 3) & 63, j = (t2 >> 9) & 7, c = t2 >> 12;
        w2k[t2] = f2b(w2[(32*c + 8*(l>>4) + e) * 128 + 16*j + (l & 15)]);
      } else {                                        // wq/wk/wv: [128][128]
        const int t2 = (tid - 81920) & 16383;
        const int which = (tid - 81920) >> 14;
        const float* src = which == 0 ? wq : which == 1 ? wk : wv;
        unsigned short* dst = which == 0 ? wqk : which == 1 ? wkk : wvk;
        const int e = t2 & 7, l = (t2 >> 3) & 63, j = (t2 >> 9) & 7, c = t2 >> 12;
        dst[t2] = f2b(src[(32*c + 8*(l>>4) + e) * 128 + 16*j + (l & 15)]);
      }
    }
  } else {
    // zero kpb buffer positions 2496..2559 (proj rewrites real keys 2496..2519 after)
    const int base = (blockIdx.x - 128) * 256 + threadIdx.x;   // 0..511
    for (int i = base; i < 16384; i += 512) {
      const int bm = i >> 11, rem = i & 2047;
      kpb[((size_t)bm * NKP + 2496 + (rem >> 5)) * DH + (rem & 31)] = 0;
      vtb[((size_t)(i >> 6)) * NKP + 2496 + (i & 63)] = 0;
    }
  }
}

// ---------------- Kernel 2: fused MFMA LN+project for K, V and Q ----------------
__global__ __launch_bounds__(256)
void proj_kernel(const float* __restrict__ kin, const float* __restrict__ vin,
                 const float* __restrict__ lnk_g, const float* __restrict__ lnk_b,
                 const unsigned short* __restrict__ wkk, const float* __restrict__ bk,
                 const float* __restrict__ lnv_g, const float* __restrict__ lnv_b,
                 const unsigned short* __restrict__ wvk, const float* __restrict__ bv,
                 unsigned short* __restrict__ kpb, unsigned short* __restrict__ vtb,
                 const float* __restrict__ qin,
                 const float* __restrict__ lnq_g, const float* __restrict__ lnq_b,
                 const unsigned short* __restrict__ wqk, const float* __restrict__ bq,
                 unsigned short* __restrict__ qsb)
{
  const int wid = threadIdx.x >> 6, lane = threadIdx.x & 63;
  const int l15 = lane & 15, g = lane >> 4;

  if (blockIdx.x < 158) {
    const int T = blockIdx.x * 4 + wid;
    if (T >= 630) return;
    const int ph = T >= 315 ? 1 : 0;
    const int t = ph ? T - 315 : T;

    const float* in = ph ? vin : kin;
    const float* gg = ph ? lnv_g : lnk_g;
    const float* bb = ph ? lnv_b : lnk_b;
    const unsigned short* wf = ph ? wvk : wkk;
    const float* bs = ph ? bv : bk;

    const int myrow = 16 * t + l15;
    const int cam = myrow / HK, kk = myrow - cam * HK;

    float x[4][8];
    float s = 0.f, s2 = 0.f;
    #pragma unroll
    for (int c = 0; c < 4; ++c)
      #pragma unroll
      for (int e = 0; e < 8; ++e) {
        const float xv = in[((size_t)(cam * D_ + 32 * c + 8 * g + e)) * HK + kk];
        x[c][e] = xv; s += xv; s2 += xv * xv;
      }
    s  += __shfl_xor(s, 16);  s2 += __shfl_xor(s2, 16);
    s  += __shfl_xor(s, 32);  s2 += __shfl_xor(s2, 32);
    const float mean = s * (1.f / 128.f);
    const float rstd = rsqrtf(s2 * (1.f / 128.f) - mean * mean + 1e-5f);

    short8v aA[4];
    #pragma unroll
    for (int c = 0; c < 4; ++c)
      #pragma unroll
      for (int e = 0; e < 8; ++e) {
        const int col = 32 * c + 8 * g + e;
        aA[c][e] = (short)f2b((x[c][e] - mean) * rstd * gg[col] + bb[col]);
      }

    f32x4 z[8];
    #pragma unroll
    for (int j = 0; j < 8; ++j) {
      f32x4 d = {0.f, 0.f, 0.f, 0.f};
      #pragma unroll
      for (int c = 0; c < 4; ++c) {
        const short8v w8 = *(const short8v*)(wf + (((c * 8 + j) * 64 + lane) << 3));
        d = __builtin_amdgcn_mfma_f32_16x16x32_bf16(aA[c], w8, d, 0, 0, 0);
      }
      z[j] = d;
    }

    const int key0 = 16 * t + 4 * g;
    #pragma unroll
    for (int j = 0; j < 8; ++j) {
      const int col = 16 * j + l15;
      const float bsv = bs[col];
      if (ph == 0) {
        const int m = col >> 5, dh = col & 31;
        #pragma unroll
        for (int r = 0; r < 4; ++r) {
          const int key = key0 + r;
          const int bbx = key / NK, kb = key - bbx * NK;
          const int kbp = (kb & ~31) | kperm(kb & 31);        // permuted chunk position
          kpb[((size_t)(bbx * M_ + m) * NKP + kbp) * DH + dh] = f2b(z[j][r] + bsv);
        }
      } else {
        #pragma unroll
        for (int r = 0; r < 4; ++r) {
          const int key = key0 + r;
          const int bbx = key / NK, kb = key - bbx * NK;
          vtb[((size_t)(bbx * 128 + col)) * NKP + kb] = f2b(z[j][r] + bsv);
        }
      }
    }
  } else {
    const int t = (blockIdx.x - 158) * 4 + wid;
    if (t >= 313) return;
    int myrow = 16 * t + l15; if (myrow > 4999) myrow = 4999;
    const int b = myrow / Q_, qpos = myrow - b * Q_;

    float xs[4][8];
    #pragma unroll
    for (int c = 0; c < 4; ++c)
      #pragma unroll
      for (int e = 0; e < 8; ++e) xs[c][e] = 0.f;

    #pragma unroll
    for (int n = 0; n < 2; ++n) {
      float x[4][8];
      float s = 0.f, s2 = 0.f;
      #pragma unroll
      for (int c = 0; c < 4; ++c)
        #pragma unroll
        for (int e = 0; e < 8; ++e) {
          const float xv = qin[((size_t)((b * N_ + n) * D_ + 32 * c + 8 * g + e)) * Q_ + qpos];
          x[c][e] = xv; s += xv; s2 += xv * xv;
        }
      s  += __shfl_xor(s, 16);  s2 += __shfl_xor(s2, 16);
      s  += __shfl_xor(s, 32);  s2 += __shfl_xor(s2, 32);
      const float mean = s * (1.f / 128.f);
      const float rstd = rsqrtf(s2 * (1.f / 128.f) - mean * mean + 1e-5f);
      #pragma unroll
      for (int c = 0; c < 4; ++c)
        #pragma unroll
        for (int e = 0; e < 8; ++e) xs[c][e] += (x[c][e] - mean) * rstd;
    }

    short8v aA[4];
    #pragma unroll
    for (int c = 0; c < 4; ++c) {
      #pragma unroll
      for (int e = 0; e < 8; ++e) {
        const int col = 32 * c + 8 * g + e;
        aA[c][e] = (short)f2b(SCALE * (xs[c][e] * lnq_g[col] + 2.f * lnq_b[col]));
      }
    }

    f32x4 z[8];
    #pragma unroll
    for (int j = 0; j < 8; ++j) {
      f32x4 d = {0.f, 0.f, 0.f, 0.f};
      #pragma unroll
      for (int c = 0; c < 4; ++c) {
        const short8v w8 = *(const short8v*)(wqk + (((c * 8 + j) * 64 + lane) << 3));
        d = __builtin_amdgcn_mfma_f32_16x16x32_bf16(aA[c], w8, d, 0, 0, 0);
      }
      z[j] = d;
    }

    const int row0 = 16 * t + 4 * g;
    #pragma unroll
    for (int j = 0; j < 8; ++j) {
      const int col = 16 * j + l15;
      const float bsv = 2.f * SCALE * bq[col];
      #pragma unroll
      for (int r = 0; r < 4; ++r) {
        const int row = row0 + r;
        if (row < 5000) qsb[((size_t)row) * 128 + col] = f2b(z[j][r] + bsv);
      }
    }
  }
}

// ---------------- Kernel 3: MFMA flash attention — 2 q-tiles per wave; bf16 nontemporal partials ----------------
__global__ __launch_bounds__(256)
void attn_kernel(const unsigned short* __restrict__ qsb,
                 const unsigned short* __restrict__ kpb,
                 const unsigned short* __restrict__ vtb,
                 float* __restrict__ pl, unsigned short* __restrict__ pacc)
{
  const int wid  = threadIdx.x >> 6;
  const int lane = threadIdx.x & 63;
  const int bi = blockIdx.x;
  const int sp = bi & 7;
  const int tmp = bi >> 3;
  const int qg = tmp % 20;
  const int bm = tmp / 20;               // b*4+m
  const int qp = qg * 4 + wid;           // q-tile pair 0..79 -> tiles 2qp, 2qp+1

  const int q16 = lane & 15, g = lane >> 4;
  const int qa = (2 * qp) * 16 + q16;
  const int qb = (2 * qp + 1) * 16 + q16;
  const int qca = qa < Q_ ? qa : Q_ - 1;
  const int qcb = qb < Q_ ? qb : Q_ - 1;
  const int b = bm >> 2;

  const short8v qf0 = *(const short8v*)(qsb + ((size_t)(b * Q_ + qca)) * 128 + (bm & 3) * DH + g * 8);
  const short8v qf1 = *(const short8v*)(qsb + ((size_t)(b * Q_ + qcb)) * 128 + (bm & 3) * DH + g * 8);

  const unsigned short* kbase = kpb + ((size_t)bm * NKP + sp * KPSP) * DH + q16 * DH + g * 8;
  const unsigned short* vbase = vtb + ((size_t)(bm * DH + q16)) * NKP + sp * KPSP + g * 8;

  f32x4 o0a = {0,0,0,0}, o1a = {0,0,0,0}, o0b = {0,0,0,0}, o1b = {0,0,0,0};
  float la = 0.f, lb = 0.f;

  const int c0 = qp % CHUNKS;
  int c1 = c0 + 1; if (c1 >= CHUNKS) c1 -= CHUNKS;
  int cn = c0 + 2; if (cn >= CHUNKS) cn -= CHUNKS;

  short8v kA1 = *(const short8v*)(kbase + c0 * 1024);
  short8v kA2 = *(const short8v*)(kbase + c0 * 1024 + 512);
  short8v vA1 = *(const short8v*)(vbase + c0 * 32);
  short8v vA2 = *(const short8v*)(vbase + c0 * 32 + 16 * NKP);
  short8v kB1 = *(const short8v*)(kbase + c1 * 1024);
  short8v kB2 = *(const short8v*)(kbase + c1 * 1024 + 512);
  short8v vB1 = *(const short8v*)(vbase + c1 * 32);
  short8v vB2 = *(const short8v*)(vbase + c1 * 32 + 16 * NKP);

  auto step = [&](short8v& K1r, short8v& K2r, short8v& V1r, short8v& V2r, int cnx) {
    // Permuted K: lane (q16,g) gets S for keys 8g+r (s0*) and 8g+4+r (s1*)
    f32x4 s0a = __builtin_amdgcn_mfma_f32_16x16x32_bf16(K1r, qf0, (f32x4){0.f,0.f,0.f,0.f}, 0, 0, 0);
    f32x4 s1a = __builtin_amdgcn_mfma_f32_16x16x32_bf16(K2r, qf0, (f32x4){0.f,0.f,0.f,0.f}, 0, 0, 0);
    f32x4 s0b = __builtin_amdgcn_mfma_f32_16x16x32_bf16(K1r, qf1, (f32x4){0.f,0.f,0.f,0.f}, 0, 0, 0);
    f32x4 s1b = __builtin_amdgcn_mfma_f32_16x16x32_bf16(K2r, qf1, (f32x4){0.f,0.f,0.f,0.f}, 0, 0, 0);

    float pa[8], pb_[8];
    #pragma unroll
    for (int r = 0; r < 4; ++r) {
      pa[r] = __builtin_amdgcn_exp2f(s0a[r]);  pa[4 + r] = __builtin_amdgcn_exp2f(s1a[r]);
      pb_[r] = __builtin_amdgcn_exp2f(s0b[r]); pb_[4 + r] = __builtin_amdgcn_exp2f(s1b[r]);
    }
    #pragma unroll
    for (int i = 0; i < 8; ++i) { la += pa[i]; lb += pb_[i]; }

    short8v fa, fb;
    #pragma unroll
    for (int i = 0; i < 8; ++i) { fa[i] = (short)f2b(pa[i]); fb[i] = (short)f2b(pb_[i]); }

    o0a = __builtin_amdgcn_mfma_f32_16x16x32_bf16(V1r, fa, o0a, 0, 0, 0);
    o1a = __builtin_amdgcn_mfma_f32_16x16x32_bf16(V2r, fa, o1a, 0, 0, 0);
    o0b = __builtin_amdgcn_mfma_f32_16x16x32_bf16(V1r, fb, o0b, 0, 0, 0);
    o1b = __builtin_amdgcn_mfma_f32_16x16x32_bf16(V2r, fb, o1b, 0, 0, 0);

    K1r = *(const short8v*)(kbase + cnx * 1024);
    K2r = *(const short8v*)(kbase + cnx * 1024 + 512);
    V1r = *(const short8v*)(vbase + cnx * 32);
    V2r = *(const short8v*)(vbase + cnx * 32 + 16 * NKP);
  };

  #pragma unroll 1
  for (int it = 0; it < CHUNKS / 2; ++it) {
    step(kA1, kA2, vA1, vA2, cn);
    cn = cn + 1 >= CHUNKS ? cn + 1 - CHUNKS : cn + 1;
    step(kB1, kB2, vB1, vB2, cn);
    cn = cn + 1 >= CHUNKS ? cn + 1 - CHUNKS : cn + 1;
  }

  la += __shfl_xor(la, 16);  la += __shfl_xor(la, 32);
  lb += __shfl_xor(lb, 16);  lb += __shfl_xor(lb, 32);

  // nontemporal bf16 partials: keep the write stream out of L2 so K/V stay resident
  if (qa < Q_) {
    const size_t row = (size_t)(bm * SPLIT + sp) * Q_ + qa;
    if (lane < 16) __builtin_nontemporal_store(la, &pl[row]);
    u32x2 w0, w1;
    w0[0] = pk2(o0a[0], o0a[1]); w0[1] = pk2(o0a[2], o0a[3]);
    w1[0] = pk2(o1a[0], o1a[1]); w1[1] = pk2(o1a[2], o1a[3]);
    __builtin_nontemporal_store(w0, (u32x2*)(pacc + row * DH + 4 * g));
    __builtin_nontemporal_store(w1, (u32x2*)(pacc + row * DH + 16 + 4 * g));
  }
  if (qb < Q_) {
    const size_t row = (size_t)(bm * SPLIT + sp) * Q_ + qb;
    if (lane < 16) __builtin_nontemporal_store(lb, &pl[row]);
    u32x2 w0, w1;
    w0[0] = pk2(o0b[0], o0b[1]); w0[1] = pk2(o0b[2], o0b[3]);
    w1[0] = pk2(o1b[0], o1b[1]); w1[1] = pk2(o1b[2], o1b[3]);
    __builtin_nontemporal_store(w0, (u32x2*)(pacc + row * DH + 4 * g));
    __builtin_nontemporal_store(w1, (u32x2*)(pacc + row * DH + 16 + 4 * g));
  }
}

// ---------------- Kernel 4: fused combine + MFMA tail, 4 waves cooperate on one 16-row tile ----------------
__global__ __launch_bounds__(256)
void tail_kernel(const float* __restrict__ pl, const unsigned short* __restrict__ pacc,
                 const float* __restrict__ skip,
                 const unsigned short* __restrict__ wpk, const float* __restrict__ bp,
                 const float* __restrict__ ln1_g, const float* __restrict__ ln1_b,
                 const unsigned short* __restrict__ w1k, const float* __restrict__ b1,
                 const unsigned short* __restrict__ w2k, const float* __restrict__ b2,
                 const float* __restrict__ ln2_g, const float* __restrict__ ln2_b,
                 float* __restrict__ out)
{
  __shared__ __align__(16) unsigned short aL[16][136];
  __shared__ __align__(16) unsigned short zl[16][136];
  __shared__ __align__(16) unsigned short hl[16][264];
  __shared__ __align__(16) float stat1[4][16][2];
  __shared__ __align__(16) float stat2[4][16][2];

  const int wid = threadIdx.x >> 6, lane = threadIdx.x & 63;
  const int l15 = lane & 15, g = lane >> 4;
  const int row0 = blockIdx.x * 16;
  const int grow0 = row0 + 4 * g;

  {
    int arow = row0 + l15; if (arow > 4999) arow = 4999;
    const int bb = arow / Q_, qq = arow - bb * Q_;
    float ls = -40.0f;                   // exact correction for 40 zero-pad keys
    float4 a0 = {0,0,0,0}, a1 = {0,0,0,0};
    #pragma unroll
    for (int sp = 0; sp < SPLIT; ++sp) {
      const size_t row = (size_t)((bb * 4 + wid) * SPLIT + sp) * Q_ + qq;
      ls += __builtin_nontemporal_load(&pl[row]);
      const u32x4 t = __builtin_nontemporal_load((const u32x4*)(pacc + row * DH + 8 * g));
      a0.x += bl(t[0]); a0.y += bh(t[0]); a0.z += bl(t[1]); a0.w += bh(t[1]);
      a1.x += bl(t[2]); a1.y += bh(t[2]); a1.z += bl(t[3]); a1.w += bh(t[3]);
    }
    const float inv = 1.f / ls;
    u32x4 w;
    w[0] = pk2(a0.x * inv, a0.y * inv);
    w[1] = pk2(a0.z * inv, a0.w * inv);
    w[2] = pk2(a1.x * inv, a1.y * inv);
    w[3] = pk2(a1.z * inv, a1.w * inv);
    *(u32x4*)&aL[l15][32 * wid + 8 * g] = w;
  }
  __syncthreads();

  short8v aA[4];
  #pragma unroll
  for (int c = 0; c < 4; ++c)
    aA[c] = *(const short8v*)&aL[l15][32 * c + 8 * g];

  f32x4 zres[2];
  #pragma unroll
  for (int jj = 0; jj < 2; ++jj) {
    const int j = 2 * wid + jj;
    f32x4 d = {0.f, 0.f, 0.f, 0.f};
    #pragma unroll
    for (int c = 0; c < 4; ++c) {
      const short8v wf = *(const short8v*)(wpk + (((c * 8 + j) * 64 + lane) << 3));
      d = __builtin_amdgcn_mfma_f32_16x16x32_bf16(aA[c], wf, d, 0, 0, 0);
    }
    zres[jj] = d;
  }

  #pragma unroll
  for (int jj = 0; jj < 2; ++jj) {
    const int col = 16 * (2 * wid + jj) + l15;
    const float bpv = bp[col];
    #pragma unroll
    for (int r = 0; r < 4; ++r) {
      int rr = grow0 + r; if (rr > 4999) rr = 4999;
      const int bb = rr / 2500, q = rr - bb * 2500;
      zres[jj][r] += bpv + skip[((size_t)(bb * 128 + col)) * 2500 + q];
    }
  }

  {
    float sum[4], sq[4];
    #pragma unroll
    for (int r = 0; r < 4; ++r) {
      sum[r] = zres[0][r] + zres[1][r];
      sq[r]  = zres[0][r] * zres[0][r] + zres[1][r] * zres[1][r];
    }
    #pragma unroll
    for (int r = 0; r < 4; ++r) {
      #pragma unroll
      for (int off = 1; off < 16; off <<= 1) {
        sum[r] += __shfl_xor(sum[r], off);
        sq[r]  += __shfl_xor(sq[r], off);
      }
    }
    if (l15 == 0) {
      float4 s0 = {sum[0], sq[0], sum[1], sq[1]};
      float4 s1 = {sum[2], sq[2], sum[3], sq[3]};
      *(float4*)&stat1[wid][4 * g][0]     = s0;
      *(float4*)&stat1[wid][4 * g + 2][0] = s1;
    }
  }
  __syncthreads();

  float mean[4], rstd[4];
  #pragma unroll
  for (int r = 0; r < 4; ++r) {
    float S = 0.f, S2 = 0.f;
    #pragma unroll
    for (int w2 = 0; w2 < 4; ++w2) {
      S  += stat1[w2][4 * g + r][0];
      S2 += stat1[w2][4 * g + r][1];
    }
    mean[r] = S * (1.f / 128.f);
    rstd[r] = rsqrtf(S2 * (1.f / 128.f) - mean[r] * mean[r] + 1e-5f);
  }

  #pragma unroll
  for (int jj = 0; jj < 2; ++jj) {
    const int col = 16 * (2 * wid + jj) + l15;
    const float g1 = ln1_g[col], bv1 = ln1_b[col];
    #pragma unroll
    for (int r = 0; r < 4; ++r) {
      const float vv = (zres[jj][r] - mean[r]) * rstd[r] * g1 + bv1;
      zres[jj][r] = vv;
      zl[4 * g + r][col] = f2b(vv);
    }
  }
  __syncthreads();

  short8v zA[4];
  #pragma unroll
  for (int c = 0; c < 4; ++c)
    zA[c] = *(const short8v*)&zl[l15][32 * c + 8 * g];
  #pragma unroll
  for (int jj = 0; jj < 4; ++jj) {
    const int j = 4 * wid + jj;
    f32x4 d = {0.f, 0.f, 0.f, 0.f};
    #pragma unroll
    for (int c = 0; c < 4; ++c) {
      const short8v wf = *(const short8v*)(w1k + (((c * 16 + j) * 64 + lane) << 3));
      d = __builtin_amdgcn_mfma_f32_16x16x32_bf16(zA[c], wf, d, 0, 0, 0);
    }
    const int col = 16 * j + l15;
    const float bv = b1[col];
    #pragma unroll
    for (int r = 0; r < 4; ++r) {
      const float x = d[r] + bv;
      hl[4 * g + r][col] = f2b(0.5f * x * (1.f + erff(x * 0.70710678118654752f)));
    }
  }
  __syncthreads();

  short8v hA[8];
  #pragma unroll
  for (int c = 0; c < 8; ++c)
    hA[c] = *(const short8v*)&hl[l15][32 * c + 8 * g];
  #pragma unroll
  for (int jj = 0; jj < 2; ++jj) {
    const int j = 2 * wid + jj;
    f32x4 d = {0.f, 0.f, 0.f, 0.f};
    #pragma unroll
    for (int c = 0; c < 8; ++c) {
      const short8v wf = *(const short8v*)(w2k + (((c * 8 + j) * 64 + lane) << 3));
      d = __builtin_amdgcn_mfma_f32_16x16x32_bf16(hA[c], wf, d, 0, 0, 0);
    }
    const int col = 16 * j + l15;
    const float bv = b2[col];
    #pragma unroll
    for (int r = 0; r < 4; ++r) zres[jj][r] += d[r] + bv;
  }

  {
    float sum[4], sq[4];
    #pragma unroll
    for (int r = 0; r < 4; ++r) {
      sum[r] = zres[0][r] + zres[1][r];
      sq[r]  = zres[0][r] * zres[0][r] + zres[1][r] * zres[1][r];
    }
    #pragma unroll
    for (int r = 0; r < 4; ++r) {
      #pragma unroll
      for (int off = 1; off < 16; off <<= 1) {
        sum[r] += __shfl_xor(sum[r], off);
        sq[r]  += __shfl_xor(sq[r], off);
      }
    }
    if (l15 == 0) {
      float4 s0 = {sum[0], sq[0], sum[1], sq[1]};
      float4 s1 = {sum[2], sq[2], sum[3], sq[3]};
      *(float4*)&stat2[wid][4 * g][0]     = s0;
      *(float4*)&stat2[wid][4 * g + 2][0] = s1;
    }
  }
  __syncthreads();

  float mean2[4], rstd2[4];
  #pragma unroll
  for (int r = 0; r < 4; ++r) {
    float S = 0.f, S2 = 0.f;
    #pragma unroll
    for (int w2 = 0; w2 < 4; ++w2) {
      S  += stat2[w2][4 * g + r][0];
      S2 += stat2[w2][4 * g + r][1];
    }
    mean2[r] = S * (1.f / 128.f);
    rstd2[r] = rsqrtf(S2 * (1.f / 128.f) - mean2[r] * mean2[r] + 1e-5f);
  }

  if (grow0 + 3 <= 4999) {
    const int bb = grow0 / 2500, q0 = grow0 - bb * 2500;
    #pragma unroll
    for (int jj = 0; jj < 2; ++jj) {
      const int col = 16 * (2 * wid + jj) + l15;
      const float g2 = ln2_g[col], bv2 = ln2_b[col];
      float4 o;
      o.x = (zres[jj][0] - mean2[0]) * rstd2[0] * g2 + bv2;
      o.y = (zres[jj][1] - mean2[1]) * rstd2[1] * g2 + bv2;
      o.z = (zres[jj][2] - mean2[2]) * rstd2[2] * g2 + bv2;
      o.w = (zres[jj][3] - mean2[3]) * rstd2[3] * g2 + bv2;
      *(float4*)(out + ((size_t)(bb * 128 + col)) * 2500 + q0) = o;
    }
  }
}

extern "C" void kernel_launch(void* const* d_in, const int* in_sizes, int n_in,
                              void* d_out, int out_size, void* d_ws, size_t ws_size,
                              hipStream_t stream)
{
  const float* q     = (const float*)d_in[0];
  const float* k     = (const float*)d_in[1];
  const float* v     = (const float*)d_in[2];
  const float* skip  = (const float*)d_in[3];
  const float* lnq_g = (const float*)d_in[4];
  const float* lnq_b = (const float*)d_in[5];
  const float* wq    = (const float*)d_in[6];
  const float* bq    = (const float*)d_in[7];
  const float* lnk_g = (const float*)d_in[8];
  const float* lnk_b = (const float*)d_in[9];
  const float* wk    = (const float*)d_in[10];
  const float* bk    = (const float*)d_in[11];
  const float* lnv_g = (const float*)d_in[12];
  const float* lnv_b = (const float*)d_in[13];
  const float* wv    = (const float*)d_in[14];
  const float* bv    = (const float*)d_in[15];
  const float* wp    = (const float*)d_in[16];
  const float* bp    = (const float*)d_in[17];
  const float* ln1_g = (const float*)d_in[18];
  const float* ln1_b = (const float*)d_in[19];
  const float* w1    = (const float*)d_in[20];
  const float* b1    = (const float*)d_in[21];
  const float* w2    = (const float*)d_in[22];
  const float* b2    = (const float*)d_in[23];
  const float* ln2_g = (const float*)d_in[24];
  const float* ln2_b = (const float*)d_in[25];

  unsigned short* kpb = (unsigned short*)d_ws;         // 655360
  unsigned short* vtb = kpb + 655360;                  // 655360
  unsigned short* qsb = vtb + 655360;                  // 640000
  unsigned short* wpk = qsb + 640000;                  // 16384
  unsigned short* w1k = wpk + 16384;                   // 32768
  unsigned short* w2k = w1k + 32768;                   // 32768
  unsigned short* wqk = w2k + 32768;                   // 16384
  unsigned short* wkk = wqk + 16384;                   // 16384
  unsigned short* wvk = wkk + 16384;                   // 16384
  float* pl = (float*)(wvk + 16384);                   // 2*4*8*2500 = 160000 floats
  unsigned short* pacc = (unsigned short*)(pl + 160000); // 160000*32 bf16 = 5.12M shorts

  setup_kernel<<<dim3(130), dim3(256), 0, stream>>>(wp, w1, w2, wq, wk, wv,
                                                    wpk, w1k, w2k, wqk, wkk, wvk,
                                                    kpb, vtb);
  proj_kernel<<<dim3(237), dim3(256), 0, stream>>>(
      k, v, lnk_g, lnk_b, wkk, bk, lnv_g, lnv_b, wvk, bv, kpb, vtb,
      q, lnq_g, lnq_b, wqk, bq, qsb);
  attn_kernel<<<dim3(1280), dim3(256), 0, stream>>>(qsb, kpb, vtb, pl, pacc);
  tail_kernel<<<dim3(313), dim3(256), 0, stream>>>(
      pl, pacc, skip, wpk, bp, ln1_g, ln1_b, w1k, b1, w2k, b2, ln2_g, ln2_b, (float*)d_out);
}